// Round 4
// baseline (2105.191 us; speedup 1.0000x reference)
//
#include <hip/hip_runtime.h>

// ---------------- problem constants ----------------
#define NB 2048
#define ND 1024
#define NS 30720
#define K_MAIN 131072LL           // TOP_K * B
#define K_AUX  2097152LL          // TOP_K * AUX_K_MULT * B
#define BAND_CAP 16384
#define SEL_CAP  8192
#define CANDA_CAP 65536
#define EPS_BAND 1e-3f            // covers worst-case |approx - fp64| per element with big margin
#define KSPLIT 4

// ---------------- ws layout (bytes) ----------------
#define OFF_SCAL 0                // int[64]
#define OFF_ACC  256              // double[8]
#define OFF_H1M  512              // int[4096]
#define OFF_H1A  16896
#define OFF_H2M  33280
#define OFF_H2A  49664
#define OFF_ZERO_END 66048        // zeroed every launch
#define OFF_DEAD 66048            // 30720 bytes
#define OFF_SEL_IDX 98304         // int[SEL_CAP]
#define OFF_SEL_BITS 131072       // uint[SEL_CAP]
#define OFF_BANDI 163840          // int[BAND_CAP]
#define OFF_BANDV 229376          // double[BAND_CAP]
#define OFF_CAB  360448           // uint[CANDA_CAP]  (ends 622592)
// aux GEMM per-split output planes: fp32 [KSPLIT][NB][ND] = 32 MB
#define OFF_RAUX 1048576ULL
// split-bf16 planes for the encoder MFMA GEMM
#define OFF_AH   (OFF_RAUX + (unsigned long long)KSPLIT * NB * ND * 4)   // 34603008
#define OFF_AL   (OFF_AH + 2048ULL*1024*2)
#define OFF_WHT  (OFF_AL + 2048ULL*1024*2)          // [30720][1024] bf16 = 60 MB (transposed)
#define OFF_WLT  (OFF_WHT + 30720ULL*1024*2)
#define WS_NEED_ENC (OFF_WLT + 30720ULL*1024*2)     // ~161 MB
// aux planes reuse the encoder-plane region (encoder GEMM is complete before aux pack)
#define OFF_AXB  OFF_AH                              // bf16 [NB][NS] = 126 MB
#define OFF_WDT  (OFF_AXB + 2048ULL*30720*2)         // bf16 [ND][NS] = 63 MB
#define WS_NEED_AUX (OFF_WDT + 1024ULL*30720*2)      // ~213 MB

// scal indices
#define S_NDEAD 0
#define S_B1M 1
#define S_REM1M 2
#define S_B1A 3
#define S_REM1A 4
#define S_T24M 5
#define S_BLO 6
#define S_BHI 7
#define S_T24A 8
#define S_JA 9
#define S_NHI 10
#define S_BANDC 11
#define S_CCA 12
#define S_SELCNT 13
#define S_L0 14
#define S_MINBITS 15

// acc indices
#define A_L2_0 0
#define A_L1 4
#define A_AUX 5

typedef __attribute__((ext_vector_type(8))) short bf16x8;
typedef __attribute__((ext_vector_type(4))) float f32x4;

// ---------------- helpers ----------------
__device__ __forceinline__ float blk_reduce(float v, float* sred) {
    int t = threadIdx.x;
    #pragma unroll
    for (int o = 32; o > 0; o >>= 1) v += __shfl_down(v, o, 64);
    __syncthreads();
    if ((t & 63) == 0) sred[t >> 6] = v;
    __syncthreads();
    return sred[0] + sred[1] + sred[2] + sred[3];
}

__device__ __forceinline__ unsigned short f2bf(float f) {
    unsigned u = __float_as_uint(f);
    unsigned r = (u + 0x7FFFu + ((u >> 16) & 1u)) >> 16;   // RNE
    return (unsigned short)r;
}
__device__ __forceinline__ float bf2f(unsigned short h) {
    return __uint_as_float(((unsigned)h) << 16);
}

#define GLD16(gp, lp) __builtin_amdgcn_global_load_lds( \
    (const __attribute__((address_space(1))) unsigned int*)(gp), \
    (__attribute__((address_space(3))) unsigned int*)(lp), 16, 0, 0)

// ---------------- kernels ----------------
__global__ void k_init(int* w) {
    int n = OFF_ZERO_END / 4;
    for (int i = blockIdx.x * blockDim.x + threadIdx.x; i < n; i += gridDim.x * blockDim.x)
        w[i] = 0;
}

__global__ void k_dead(const int* __restrict__ nbna, unsigned char* __restrict__ dead, int* scal) {
    int stride = gridDim.x * blockDim.x;
    int cnt = 0;
    for (int i = blockIdx.x * blockDim.x + threadIdx.x; i < NS; i += stride) {
        bool d = nbna[i] >= 20;
        dead[i] = d ? 1 : 0;
        cnt += d ? 1 : 0;
    }
    #pragma unroll
    for (int o = 32; o > 0; o >>= 1) cnt += __shfl_down(cnt, o, 64);
    if ((threadIdx.x & 63) == 0 && cnt) atomicAdd(&scal[S_NDEAD], cnt);
}

// split (x - b_dec) into bf16 hi/lo planes, [M][K]
__global__ void k_prep_a(const float* __restrict__ x, const float* __restrict__ b_dec,
                         unsigned short* __restrict__ Ahg, unsigned short* __restrict__ Alg) {
    int stride = gridDim.x * blockDim.x;
    for (int i = blockIdx.x * blockDim.x + threadIdx.x; i < NB * ND; i += stride) {
        float v = x[i] - b_dec[i & (ND - 1)];
        unsigned short h = f2bf(v);
        unsigned short l = f2bf(v - bf2f(h));
        Ahg[i] = h; Alg[i] = l;
    }
}

// transpose + split W_enc [K][N] fp32 -> WhT/WlT [N][K] bf16 (32x32 tiles via LDS)
__global__ __launch_bounds__(256) void k_prep_w(const float* __restrict__ W,
        unsigned short* __restrict__ WhT, unsigned short* __restrict__ WlT) {
    __shared__ float tile[32][33];
    int n0 = blockIdx.x * 32, k0 = blockIdx.y * 32;
    int t = threadIdx.x;
    int c = t & 31, r = t >> 5;          // r in 0..7
    #pragma unroll
    for (int it = 0; it < 4; it++)
        tile[r + it * 8][c] = W[(size_t)(k0 + r + it * 8) * NS + n0 + c];
    __syncthreads();
    int kl = t & 31, nl = t >> 5;
    #pragma unroll
    for (int it = 0; it < 4; it++) {
        float v = tile[kl][nl + it * 8];
        unsigned short h = f2bf(v);
        unsigned short l = f2bf(v - bf2f(h));
        size_t o = (size_t)(n0 + nl + it * 8) * ND + k0 + kl;
        WhT[o] = h; WlT[o] = l;
    }
}

// ============================================================================
// split-bf16 MFMA encoder GEMM: acts = relu(A@W + b_enc), A=Ah+Al, W=Wh+Wl.
// 256x128 tile -> grid 8x240 = 1920 blocks (ALL 256 CUs; the 256x256 tile's
// 120-block grid left >half the chip idle — R3 diagnosis). BK=32, 8 waves in
// 4Mx2N grid (per-wave 64x64), double-buffered 96 KiB LDS.
// Canonical single-barrier-per-tile schedule (formally race-free):
//   vmcnt(0)                 <- own stage(kt) landed (issued ~1 tile ago; non-blocking)
//   s_barrier                <- ALL waves' stage(kt) visible; tile kt-1 reads done
//   stage(kt+1) x6           <- buf[nboff]: its readers finished before THIS barrier
//   ds_read ah,bh (8) | bl (4); lgkm(4) -> burst1 MFMA(ah*bh)
//   ds_read al (4);           lgkm(4) -> burst2 MFMA(ah*bl)
//                             lgkm(0) -> burst3 MFMA(al*bh)
// R3's bug: vmcnt AFTER the barrier only covers the issuing wave's loads ->
// cross-wave LDS race -> nondeterminism (tripwire). vmcnt must precede the
// barrier to propagate. lgkm counts are split-robust (LDS ops complete
// in-order; over-wait only). sched_barrier(0) after each wait stops MFMA
// hoisting past inline-asm waits (rule #18).
// 16B-chunk XOR swizzle (chunk ^= (row>>1)&3) on pre-swizzled global src +
// swizzled ds_read (linear gload_lds dest) -> 0 bank conflicts (verified R1);
// formulas are row-based and geometry-independent.
// Per-acc FLOP order unchanged (AhBh, AhBl, AlBh per fragment per K-tile,
// kt 0..31) -> bit-identical to the R1/R2 passing kernels.
// ============================================================================
#define ENC_BUF 24576                 // shorts per LDS buffer
#define ENC_PAH 0                     // Ah plane: 256x32 shorts
#define ENC_PAL 8192                  // Al plane: 256x32
#define ENC_PBH 16384                 // Bh plane: 128x32
#define ENC_PBL 20480                 // Bl plane: 128x32

#define ENC_STAGE_A(boff, plane, gptr, r, ktn) GLD16((gptr) + (size_t)(r) * 128 * ND + (size_t)(ktn) * 32, \
    smem + (boff) + (plane) + (r) * 4096 + ldsw)
#define ENC_STAGE_B(boff, plane, gptr, ktn) GLD16((gptr) + (size_t)(ktn) * 32, \
    smem + (boff) + (plane) + ldsw)

#define ENC_RD_AH(boff) { _Pragma("unroll") \
    for (int i = 0; i < 4; i++) ah[i] = *(const bf16x8*)&smem[(boff) + ENC_PAH + (arb + i * 16) * 32 + cph8]; }
#define ENC_RD_AL(boff) { _Pragma("unroll") \
    for (int i = 0; i < 4; i++) al[i] = *(const bf16x8*)&smem[(boff) + ENC_PAL + (arb + i * 16) * 32 + cph8]; }
#define ENC_RD_BH(boff) { _Pragma("unroll") \
    for (int j = 0; j < 4; j++) bh[j] = *(const bf16x8*)&smem[(boff) + ENC_PBH + (brb + j * 16) * 32 + cph8]; }
#define ENC_RD_BL(boff) { _Pragma("unroll") \
    for (int j = 0; j < 4; j++) bl[j] = *(const bf16x8*)&smem[(boff) + ENC_PBL + (brb + j * 16) * 32 + cph8]; }

#define ENC_MFMA_BURST(AF, BF) { \
    __builtin_amdgcn_s_setprio(1); \
    _Pragma("unroll") for (int i = 0; i < 4; i++) \
        _Pragma("unroll") for (int j = 0; j < 4; j++) \
            acc[i][j] = __builtin_amdgcn_mfma_f32_16x16x32_bf16(AF[i], BF[j], acc[i][j], 0, 0, 0); \
    __builtin_amdgcn_s_setprio(0); }

__global__ __launch_bounds__(512, 2) void k_enc_mfma(
        const unsigned short* __restrict__ Ahg, const unsigned short* __restrict__ Alg,
        const unsigned short* __restrict__ WhT, const unsigned short* __restrict__ WlT,
        const float* __restrict__ b_enc, float* __restrict__ acts) {
    // 2 bufs x (Ah[256x32] + Al[256x32] + Bh[128x32] + Bl[128x32]) = 96 KiB
    __shared__ unsigned short smem[49152];
    const int t = threadIdx.x;
    const int lane = t & 63, w = t >> 6;
    const int wm = w >> 1, wn = w & 1;                 // 4x2 wave grid; per-wave 64x64
    // bijective XCD-chunked swizzle: 1920 = 8 x 240; XCD x gets n-tiles [x*30, x*30+30)
    const int flat = blockIdx.x;
    const int wg = (flat & 7) * 240 + (flat >> 3);
    const int n0 = (wg >> 3) * 128;
    const int m0 = (wg & 7) * 256;
    const int ln15 = lane & 15, q = lane >> 4;
    // physical chunk offset (shorts) for fragment reads: (q ^ ((row>>1)&3)) * 8
    const int cph8 = ((q ^ ((lane >> 1) & 3)) << 3);

    // staging: wave w covers rows [w*16, w*16+16) (+r*128 for A); lane l -> row +(l>>2), phys chunk l&3
    const int srow = w * 16 + (lane >> 2);
    const int sq8 = (((lane & 3) ^ ((lane >> 3) & 3)) << 3);   // logical chunk for this phys slot
    const unsigned short* gA  = Ahg + (size_t)(m0 + srow) * ND + sq8;
    const unsigned short* gAl = Alg + (size_t)(m0 + srow) * ND + sq8;
    const unsigned short* gB  = WhT + (size_t)(n0 + srow) * ND + sq8;
    const unsigned short* gBl = WlT + (size_t)(n0 + srow) * ND + sq8;
    const int ldsw = w * 512;                                  // wave slot (16 rows x 32 shorts)

    f32x4 acc[4][4];
    #pragma unroll
    for (int i = 0; i < 4; i++)
        #pragma unroll
        for (int j = 0; j < 4; j++) acc[i][j] = (f32x4){0.f, 0.f, 0.f, 0.f};

    const int arb = wm * 64 + ln15;        // A frag row base (+ i*16), in [0,256)
    const int brb = wn * 64 + ln15;        // B frag row base (+ j*16), in [0,128)

    // prologue: stage tile 0 into buf 0
    ENC_STAGE_A(0, ENC_PAH, gA, 0, 0);  ENC_STAGE_A(0, ENC_PAH, gA, 1, 0);
    ENC_STAGE_A(0, ENC_PAL, gAl, 0, 0); ENC_STAGE_A(0, ENC_PAL, gAl, 1, 0);
    ENC_STAGE_B(0, ENC_PBH, gB, 0);     ENC_STAGE_B(0, ENC_PBL, gBl, 0);

    for (int kt = 0; kt < 32; ++kt) {
        const int cboff = (kt & 1) * ENC_BUF;
        const int nboff = cboff ^ ENC_BUF;
        bf16x8 ah[4], bh[4], bl[4], al[4];

        // own stage(kt) drained BEFORE barrier -> barrier propagates to all waves
        asm volatile("s_waitcnt vmcnt(0)" ::: "memory");
        __builtin_amdgcn_s_barrier();
        __builtin_amdgcn_sched_barrier(0);
        if (kt < 31) {
            const int kn = kt + 1;
            ENC_STAGE_A(nboff, ENC_PAH, gA, 0, kn);  ENC_STAGE_A(nboff, ENC_PAH, gA, 1, kn);
            ENC_STAGE_A(nboff, ENC_PAL, gAl, 0, kn); ENC_STAGE_A(nboff, ENC_PAL, gAl, 1, kn);
            ENC_STAGE_B(nboff, ENC_PBH, gB, kn);     ENC_STAGE_B(nboff, ENC_PBL, gBl, kn);
        }

        // read group 1: ah + bh (8x ds_read_b128)
        ENC_RD_AH(cboff) ENC_RD_BH(cboff)
        __builtin_amdgcn_sched_barrier(0);                     // group1 strictly before bl
        // read group 2: bl (4x)
        ENC_RD_BL(cboff)
        asm volatile("s_waitcnt lgkmcnt(4)" ::: "memory");     // ah+bh done; bl may fly
        __builtin_amdgcn_sched_barrier(0);
        ENC_MFMA_BURST(ah, bh)
        // read group 3 (issues overlap burst1): al (4x)
        ENC_RD_AL(cboff)
        asm volatile("s_waitcnt lgkmcnt(4)" ::: "memory");     // bl done; al may fly
        __builtin_amdgcn_sched_barrier(0);
        ENC_MFMA_BURST(ah, bl)
        asm volatile("s_waitcnt lgkmcnt(0)" ::: "memory");     // al done
        __builtin_amdgcn_sched_barrier(0);
        ENC_MFMA_BURST(al, bh)
    }

    #pragma unroll
    for (int j = 0; j < 4; j++) {
        int n = n0 + wn * 64 + j * 16 + ln15;
        float be = b_enc[n];
        #pragma unroll
        for (int i = 0; i < 4; i++) {
            int mrow = m0 + wm * 64 + i * 16 + q * 4;
            #pragma unroll
            for (int rg = 0; rg < 4; rg++)
                acts[(size_t)(mrow + rg) * NS + n] = fmaxf(acc[i][j][rg] + be, 0.f);
        }
    }
}

// fallback fp32 encoder GEMM (used when ws too small for bf16 planes)
#define GBM 128
#define GBN 128
#define GBK 8
__global__ __launch_bounds__(256) void k_enc_gemm(const float* __restrict__ x,
        const float* __restrict__ b_dec, const float* __restrict__ b_enc,
        const float* __restrict__ W, float* __restrict__ acts) {
    __shared__ float As[GBK][GBM];
    __shared__ float Bs[GBK][GBN];
    const int t = threadIdx.x;
    const int tx = t & 15, ty = t >> 4;
    const int m0 = blockIdx.y * GBM, n0 = blockIdx.x * GBN;
    const int am = t >> 1, ak = (t & 1) * 4;
    const int bk = t >> 5, bnq = (t & 31) * 4;
    float acc[8][8];
    #pragma unroll
    for (int i = 0; i < 8; i++)
        #pragma unroll
        for (int j = 0; j < 8; j++) acc[i][j] = 0.f;
    for (int k0 = 0; k0 < ND; k0 += GBK) {
        float4 av = *(const float4*)(x + (size_t)(m0 + am) * ND + k0 + ak);
        float4 bd = *(const float4*)(b_dec + k0 + ak);
        As[ak + 0][am] = av.x - bd.x;
        As[ak + 1][am] = av.y - bd.y;
        As[ak + 2][am] = av.z - bd.z;
        As[ak + 3][am] = av.w - bd.w;
        *(float4*)&Bs[bk][bnq] = *(const float4*)(W + (size_t)(k0 + bk) * NS + n0 + bnq);
        __syncthreads();
        #pragma unroll
        for (int kk = 0; kk < GBK; kk++) {
            float a[8], b[8];
            *(float4*)&a[0] = *(const float4*)&As[kk][ty * 4];
            *(float4*)&a[4] = *(const float4*)&As[kk][64 + ty * 4];
            *(float4*)&b[0] = *(const float4*)&Bs[kk][tx * 4];
            *(float4*)&b[4] = *(const float4*)&Bs[kk][64 + tx * 4];
            #pragma unroll
            for (int i = 0; i < 8; i++)
                #pragma unroll
                for (int j = 0; j < 8; j++)
                    acc[i][j] = fmaf(a[i], b[j], acc[i][j]);
        }
        __syncthreads();
    }
    float be[8];
    #pragma unroll
    for (int j = 0; j < 4; j++) {
        be[j]     = b_enc[n0 + tx * 4 + j];
        be[4 + j] = b_enc[n0 + 64 + tx * 4 + j];
    }
    #pragma unroll
    for (int i = 0; i < 8; i++) {
        int row = m0 + ((i < 4) ? (ty * 4 + i) : (64 + ty * 4 + i - 4));
        float* orow = acts + (size_t)row * NS + n0;
        #pragma unroll
        for (int j = 0; j < 4; j++) {
            orow[tx * 4 + j]      = fmaxf(acc[i][j] + be[j], 0.f);
            orow[64 + tx * 4 + j] = fmaxf(acc[i][4 + j] + be[4 + j], 0.f);
        }
    }
}

// fused coarse histograms: main (all) + aux (dead cols only); bins = bits >> 20
__global__ __launch_bounds__(256) void k_hist1(const float* __restrict__ acts,
        const unsigned char* __restrict__ dead, int* h1m, int* h1a) {
    __shared__ int hm[4096], ha[4096];
    int t = threadIdx.x;
    for (int i = t; i < 4096; i += 256) { hm[i] = 0; ha[i] = 0; }
    __syncthreads();
    for (int row = blockIdx.x; row < NB; row += gridDim.x) {
        const float* pr = acts + (size_t)row * NS;
        for (int c = t; c < NS; c += 256) {
            unsigned bits = __float_as_uint(pr[c]);
            bool isz = (bits == 0u);
            bool dd = dead[c] != 0;
            unsigned long long mz = __ballot(isz);
            unsigned long long mza = __ballot(isz && dd);
            if ((t & 63) == 0) {
                int nz = __popcll(mz);
                if (nz) atomicAdd(&hm[0], nz);
                int nza = __popcll(mza);
                if (nza) atomicAdd(&ha[0], nza);
            }
            if (!isz) {
                atomicAdd(&hm[bits >> 20], 1);
                if (dd) atomicAdd(&ha[bits >> 20], 1);
            }
        }
    }
    __syncthreads();
    for (int i = t; i < 4096; i += 256) {
        if (hm[i]) atomicAdd(&h1m[i], hm[i]);
        if (ha[i]) atomicAdd(&h1a[i], ha[i]);
    }
}

// suffix-scan over a 4096-bin histogram; finds bin containing rank k (from top)
__global__ void k_scan(const int* __restrict__ hist, int* scal, int mode) {
    __shared__ long long csum[256];
    __shared__ long long totsh;
    int t = threadIdx.x;
    int base = t * 16;
    int h[16];
    long long loc = 0;
    #pragma unroll
    for (int i = 0; i < 16; i++) { h[i] = hist[base + i]; loc += h[i]; }
    csum[t] = loc;
    __syncthreads();
    if (t == 0) {
        long long run = 0;
        for (int c = 255; c >= 0; c--) { long long tmp = csum[c]; csum[c] = run; run += tmp; }
        totsh = run;
    }
    __syncthreads();
    long long k;
    if (mode == 0) k = K_MAIN;
    else if (mode == 1) k = K_AUX;
    else if (mode == 2) k = (long long)scal[S_REM1M];
    else {
        if (scal[S_B1A] < 0) { if (t == 0) { scal[S_T24A] = -1; scal[S_MINBITS] = 0; } return; }
        k = (long long)scal[S_REM1A];
    }
    if (mode == 1 && k > totsh) { if (t == 0) scal[S_B1A] = -1; return; }
    long long cum = csum[t];
    int fb = -1; long long rem = 0;
    for (int i = 15; i >= 0; i--) {
        long long ca = cum;
        cum += h[i];
        if (ca < k && k <= cum) { fb = base + i; rem = k - ca; }
    }
    if (fb >= 0) {
        if (mode == 0)      { scal[S_B1M] = fb; scal[S_REM1M] = (int)rem; }
        else if (mode == 1) { scal[S_B1A] = fb; scal[S_REM1A] = (int)rem; }
        else if (mode == 2) {
            int t24 = (scal[S_B1M] << 12) | fb;
            scal[S_T24M] = t24;
            float center = __uint_as_float((((unsigned)t24) << 8) | 128u);
            float lo = center - EPS_BAND;
            if (lo < 0.f) lo = 0.f;
            scal[S_BLO] = (int)__float_as_uint(lo);
            scal[S_BHI] = (int)__float_as_uint(center + EPS_BAND);
        }
        else { scal[S_T24A] = (scal[S_B1A] << 12) | fb; scal[S_JA] = (int)rem; }
    }
}

// fine histograms inside the selected coarse bins
__global__ __launch_bounds__(256) void k_hist2(const float* __restrict__ acts,
        const unsigned char* __restrict__ dead, const int* scal, int* h2m, int* h2a) {
    int b1m = scal[S_B1M], b1a = scal[S_B1A];
    int row = blockIdx.x, t = threadIdx.x;
    const float* pr = acts + (size_t)row * NS;
    for (int c = t; c < NS; c += 256) {
        unsigned bits = __float_as_uint(pr[c]);
        int hi = (int)(bits >> 20);
        if (hi == b1m) atomicAdd(&h2m[(bits >> 8) & 0xFFF], 1);
        if (b1a >= 0 && hi == b1a && dead[c]) atomicAdd(&h2a[(bits >> 8) & 0xFFF], 1);
    }
}

// single pass: exact count above band (n_hi), band-member collection, aux candidates
__global__ __launch_bounds__(256) void k_collect(const float* __restrict__ acts,
        const unsigned char* __restrict__ dead, int* scal,
        int* bandi, unsigned* cab) {
    int row = blockIdx.x, t = threadIdx.x;
    unsigned blo = (unsigned)scal[S_BLO], bhi = (unsigned)scal[S_BHI];
    int t24a = scal[S_T24A];
    const float* pr = acts + (size_t)row * NS;
    int cnt = 0;
    for (int c = t; c < NS; c += 256) {
        unsigned bits = __float_as_uint(pr[c]);
        if (bits > bhi) cnt++;
        else if (bits >= blo) {
            int p = atomicAdd(&scal[S_BANDC], 1);
            if (p < BAND_CAP) bandi[p] = row * NS + c;
        }
        if (t24a >= 0 && (bits >> 8) == (unsigned)t24a && dead[c]) {
            int p = atomicAdd(&scal[S_CCA], 1);
            if (p < CANDA_CAP) cab[p] = bits;
        }
    }
    #pragma unroll
    for (int o = 32; o > 0; o >>= 1) cnt += __shfl_down(cnt, o, 64);
    __shared__ int s2[4];
    if ((t & 63) == 0) s2[t >> 6] = cnt;
    __syncthreads();
    if (t == 0) {
        int tot = s2[0] + s2[1] + s2[2] + s2[3];
        if (tot) atomicAdd(&scal[S_NHI], tot);
    }
}

// aux threshold value from boundary-fine-bin candidates
__global__ __launch_bounds__(256) void k_resolve(const unsigned* __restrict__ cab, int* scal) {
    __shared__ int h[256];
    int t = threadIdx.x;
    h[t] = 0;
    __syncthreads();
    int t24a = scal[S_T24A];
    if (t24a < 0) { if (t == 0) scal[S_MINBITS] = 0; return; }
    int cnt = min(scal[S_CCA], CANDA_CAP);
    int ja = scal[S_JA];
    for (int e = t; e < cnt; e += 256) atomicAdd(&h[cab[e] & 0xFF], 1);
    __syncthreads();
    if (t == 0) {
        long long cum = 0; int L = 0;
        for (int b = 255; b >= 0; b--) {
            long long ca = cum; cum += h[b];
            if (ca < ja && ja <= cum) { L = b; break; }
        }
        scal[S_MINBITS] = (int)((((unsigned)t24a) << 8) | (unsigned)L);
    }
}

// fp64 recompute of band elements (exact vs reference)
__global__ __launch_bounds__(256) void k_band_re(const float* __restrict__ x,
        const float* __restrict__ b_dec, const float* __restrict__ b_enc,
        const float* __restrict__ W, const int* scal,
        const int* __restrict__ bandi, double* __restrict__ bandv) {
    int n = min(scal[S_BANDC], BAND_CAP);
    int t = threadIdx.x;
    __shared__ double sd[4];
    for (int e = blockIdx.x; e < n; e += gridDim.x) {
        int idx = bandi[e];
        int r = idx / NS, c = idx - r * NS;
        double s = 0.0;
        #pragma unroll
        for (int j = 0; j < 4; j++) {
            int d = t + j * 256;
            s += ((double)x[(size_t)r * ND + d] - (double)b_dec[d]) * (double)W[(size_t)d * NS + c];
        }
        #pragma unroll
        for (int o = 32; o > 0; o >>= 1) s += __shfl_down(s, o, 64);
        if ((t & 63) == 0) sd[t >> 6] = s;
        __syncthreads();
        if (t == 0) {
            double v = sd[0] + sd[1] + sd[2] + sd[3] + (double)b_enc[c];
            bandv[e] = fmax(v, 0.0);
        }
        __syncthreads();
    }
}

// exact selection within band: rank by (v64 desc, idx asc); keep rank < need = K - n_hi
__global__ __launch_bounds__(256) void k_band_sel(int* scal,
        const int* __restrict__ bandi, const double* __restrict__ bandv,
        int* sel_idx, unsigned* sel_bits) {
    int n = min(scal[S_BANDC], BAND_CAP);
    int need = (int)(K_MAIN - (long long)scal[S_NHI]);
    if (need < 0) need = 0;
    if (need > n) need = n;
    int t = threadIdx.x;
    for (int e = t; e < n; e += 256) {
        double v = bandv[e];
        int idx = bandi[e];
        int rank = 0;
        for (int j = 0; j < n; j++) {
            double vj = bandv[j];
            rank += (vj > v || (vj == v && bandi[j] < idx)) ? 1 : 0;
        }
        if (rank < need) {
            int p = atomicAdd(&scal[S_SELCNT], 1);
            if (p < SEL_CAP) { sel_idx[p] = idx; sel_bits[p] = __float_as_uint((float)v); }
        }
    }
}

// hierarchical sparse decode: one block per row; membership = bits > bhi OR selected band element
__global__ __launch_bounds__(256) void k_decode(const float* __restrict__ acts,
        const float* __restrict__ x, const float* __restrict__ b_dec, const float* __restrict__ Wd,
        float* __restrict__ recon, const int* scal,
        const int* __restrict__ sel_idx, double* acc) {
    int row = blockIdx.x, t = threadIdx.x;
    unsigned blo = (unsigned)scal[S_BLO], bhi = (unsigned)scal[S_BHI];
    int selcnt = min(scal[S_SELCNT], SEL_CAP);
    __shared__ int lj[2048];
    __shared__ float lv[2048];
    __shared__ int lcnt;
    __shared__ float sred[4];
    const int d0 = t * 4;
    float4 r;
    r.x = b_dec[d0]; r.y = b_dec[d0 + 1]; r.z = b_dec[d0 + 2]; r.w = b_dec[d0 + 3];
    float4 xv = *(const float4*)(x + (size_t)row * ND + d0);
    const float* arow = acts + (size_t)row * NS;
    const int bnds[5] = {0, 2048, 6144, 14336, NS};
    for (int g = 0; g < 4; g++) {
        for (int c0 = bnds[g]; c0 < bnds[g + 1]; c0 += 2048) {
            __syncthreads();
            if (t == 0) lcnt = 0;
            __syncthreads();
            #pragma unroll
            for (int u = 0; u < 8; u++) {
                int c = c0 + u * 256 + t;
                float v = arow[c];
                unsigned bits = __float_as_uint(v);
                bool keep = bits > bhi;
                if (!keep && bits >= blo) {
                    int flat = row * NS + c;
                    for (int e = 0; e < selcnt; e++)
                        if (sel_idx[e] == flat) { keep = true; break; }
                }
                if (keep) { int p = atomicAdd(&lcnt, 1); lj[p] = c; lv[p] = v; }
            }
            __syncthreads();
            int n = lcnt;
            for (int e = 0; e < n; e++) {
                float a_ = lv[e];
                float4 w = *(const float4*)(Wd + (size_t)lj[e] * ND + d0);
                r.x = fmaf(a_, w.x, r.x);
                r.y = fmaf(a_, w.y, r.y);
                r.z = fmaf(a_, w.z, r.z);
                r.w = fmaf(a_, w.w, r.w);
            }
        }
        float dx = r.x - xv.x, dy = r.y - xv.y, dz = r.z - xv.z, dw = r.w - xv.w;
        float ss = dx * dx + dy * dy + dz * dz + dw * dw;
        float tot = blk_reduce(ss, sred);
        if (t == 0) atomicAdd(&acc[A_L2_0 + g], (double)tot);
    }
    float* orow = recon + (size_t)row * ND + d0;   // region misaligned -> scalar stores
    orow[0] = r.x; orow[1] = r.y; orow[2] = r.z; orow[3] = r.w;
}

// ---- aux via dense masked GEMM ----
// pack acts_aux = relu(acts - minval) * dead into bf16 plane [NB][NS]
__global__ __launch_bounds__(256) void k_aux_pack(const float* __restrict__ acts,
        const unsigned char* __restrict__ dead, const int* scal,
        unsigned short* __restrict__ axb) {
    int row = blockIdx.x, t = threadIdx.x;
    float minval = __uint_as_float((unsigned)scal[S_MINBITS]);
    const float* arow = acts + (size_t)row * NS;
    unsigned short* orow = axb + (size_t)row * NS;
    for (int c = t; c < NS; c += 256) {
        float v = arow[c];
        float o = (dead[c] && v > minval) ? (v - minval) : 0.f;
        orow[c] = f2bf(o);
    }
}

// transpose W_dec [S][D] fp32 -> WdT [D][S] bf16
__global__ __launch_bounds__(256) void k_prep_wd(const float* __restrict__ Wd,
        unsigned short* __restrict__ WdT) {
    __shared__ float tile[32][33];
    int s0 = blockIdx.x * 32, d0 = blockIdx.y * 32;
    int t = threadIdx.x;
    int c = t & 31, r = t >> 5;
    #pragma unroll
    for (int it = 0; it < 4; it++)
        tile[r + it * 8][c] = Wd[(size_t)(s0 + r + it * 8) * ND + d0 + c];
    __syncthreads();
    int sl = t & 31, dl = t >> 5;
    #pragma unroll
    for (int it = 0; it < 4; it++)
        WdT[(size_t)(d0 + dl + it * 8) * NS + s0 + sl] = f2bf(tile[sl][dl + it * 8]);
}

// bf16 MFMA aux GEMM: raux[z] = acts_aux @ W_dec (K-split over z), per-split fp32 planes
__global__ __launch_bounds__(256) void k_aux_mfma(
        const unsigned short* __restrict__ axb, const unsigned short* __restrict__ WdT,
        float* __restrict__ raux) {
    __shared__ unsigned short As[128 * 32], Bs[128 * 32];
    const int t = threadIdx.x;
    const int lane = t & 63, w = t >> 6;
    const int wm = w >> 1, wn = w & 1;
    const int m0 = blockIdx.y * 128, n0 = blockIdx.x * 128;
    const int kbase = blockIdx.z * (NS / KSPLIT);
    const int ln15 = lane & 15, q = lane >> 4;

    f32x4 acc[4][4];
    #pragma unroll
    for (int i = 0; i < 4; i++)
        #pragma unroll
        for (int j = 0; j < 4; j++) acc[i][j] = (f32x4){0.f, 0.f, 0.f, 0.f};

    // waves 0,1 stage A halves; waves 2,3 stage B halves (64 rows x 32 cols each)
    const unsigned short* gbase;
    unsigned short* lbase;
    if (w < 2) { gbase = axb + (size_t)(m0 + w * 64) * NS; lbase = As + w * 64 * 32; }
    else       { gbase = WdT + (size_t)(n0 + (w - 2) * 64) * NS; lbase = Bs + (w - 2) * 64 * 32; }
    const unsigned short* glane = gbase + (size_t)(lane >> 2) * NS + (lane & 3) * 8 + kbase;

    for (int k0 = 0; k0 < NS / KSPLIT; k0 += 32) {
        __syncthreads();
        #pragma unroll
        for (int ch = 0; ch < 4; ch++)
            GLD16(glane + (size_t)ch * 16 * NS + k0, lbase + ch * 512);
        __syncthreads();

        bf16x8 af[4];
        #pragma unroll
        for (int i = 0; i < 4; i++)
            af[i] = *(const bf16x8*)&As[(wm * 64 + i * 16 + ln15) * 32 + q * 8];
        #pragma unroll
        for (int j = 0; j < 4; j++) {
            bf16x8 bf = *(const bf16x8*)&Bs[(wn * 64 + j * 16 + ln15) * 32 + q * 8];
            #pragma unroll
            for (int i = 0; i < 4; i++)
                acc[i][j] = __builtin_amdgcn_mfma_f32_16x16x32_bf16(af[i], bf, acc[i][j], 0, 0, 0);
        }
    }
    float* rz = raux + (size_t)blockIdx.z * NB * ND;
    #pragma unroll
    for (int j = 0; j < 4; j++) {
        int n = n0 + wn * 64 + j * 16 + ln15;
        #pragma unroll
        for (int i = 0; i < 4; i++) {
            int mrow = m0 + wm * 64 + i * 16 + q * 4;
            #pragma unroll
            for (int rg = 0; rg < 4; rg++)
                rz[(size_t)(mrow + rg) * ND + n] = acc[i][j][rg];
        }
    }
}

// aux loss: sum over B*D of (sum_z raux[z] - (x - recon))^2
__global__ __launch_bounds__(256) void k_aux_diff(const float* __restrict__ raux,
        const float* __restrict__ x, const float* __restrict__ recon, double* acc) {
    __shared__ float sred[4];
    float ss = 0.f;
    int stride = gridDim.x * blockDim.x;
    for (int i = blockIdx.x * blockDim.x + threadIdx.x; i < NB * ND; i += stride) {
        float ra = raux[i];
        #pragma unroll
        for (int z = 1; z < KSPLIT; z++) ra += raux[(size_t)z * NB * ND + i];
        float d = ra - (x[i] - recon[i]);
        ss += d * d;
    }
    float tot = blk_reduce(ss, sred);
    if (threadIdx.x == 0) atomicAdd(&acc[A_AUX], (double)tot);
}

// fallback aux: sparse gather per row
__global__ __launch_bounds__(256) void k_aux(const float* __restrict__ acts,
        const unsigned char* __restrict__ dead, const float* __restrict__ x,
        const float* __restrict__ recon, const float* __restrict__ Wd,
        const int* scal, double* acc) {
    int row = blockIdx.x, t = threadIdx.x;
    float minval = __uint_as_float((unsigned)scal[S_MINBITS]);
    __shared__ int lj[2048];
    __shared__ float lv[2048];
    __shared__ int lcnt;
    __shared__ float sred[4];
    float4 r = {0.f, 0.f, 0.f, 0.f};
    const float* arow = acts + (size_t)row * NS;
    const int d0 = t * 4;
    for (int c0 = 0; c0 < NS; c0 += 2048) {
        __syncthreads();
        if (t == 0) lcnt = 0;
        __syncthreads();
        #pragma unroll
        for (int u = 0; u < 8; u++) {
            int c = c0 + u * 256 + t;
            float v = arow[c];
            if (dead[c] && v > minval) {
                int p = atomicAdd(&lcnt, 1);
                lj[p] = c; lv[p] = v - minval;
            }
        }
        __syncthreads();
        int n = lcnt;
        for (int e = 0; e < n; e++) {
            float a_ = lv[e];
            float4 w = *(const float4*)(Wd + (size_t)lj[e] * ND + d0);
            r.x = fmaf(a_, w.x, r.x);
            r.y = fmaf(a_, w.y, r.y);
            r.z = fmaf(a_, w.z, r.z);
            r.w = fmaf(a_, w.w, r.w);
        }
    }
    const float* xr = x + (size_t)row * ND + d0;
    const float* rr = recon + (size_t)row * ND + d0;
    float dx = r.x - (xr[0] - rr[0]);
    float dy = r.y - (xr[1] - rr[1]);
    float dz = r.z - (xr[2] - rr[2]);
    float dw = r.w - (xr[3] - rr[3]);
    float ss = dx * dx + dy * dy + dz * dz + dw * dw;
    float tot = blk_reduce(ss, sred);
    if (t == 0) atomicAdd(&acc[A_AUX], (double)tot);
}

// in-place top-k zeroing over d_out acts region (strict bits > bhi) + L1/L0 for definite members
__global__ __launch_bounds__(256) void k_topk_write(float* __restrict__ out, const int* scal, double* acc, int* scalw) {
    unsigned bhi = (unsigned)scal[S_BHI];
    float l1 = 0.f;
    int cnt = 0;
    const long long vstart = 8, nvec = 15728639;   // [8, 62914564) as float4
    long long stride = (long long)gridDim.x * blockDim.x;
    for (long long i = (long long)blockIdx.x * blockDim.x + threadIdx.x; i < nvec; i += stride) {
        float4* p = (float4*)(out + vstart) + i;
        float4 v = *p;
        #define PROC(F) { unsigned b = __float_as_uint(v.F); if (b > bhi) { l1 += v.F; cnt++; } else v.F = 0.f; }
        PROC(x) PROC(y) PROC(z) PROC(w)
        #undef PROC
        *p = v;
    }
    if (blockIdx.x == 0 && threadIdx.x == 0) {
        const long long head[4] = {5, 6, 7, 62914564LL};
        for (int q = 0; q < 4; q++) {
            float v = out[head[q]];
            unsigned b = __float_as_uint(v);
            if (b > bhi) { l1 += v; cnt++; } else out[head[q]] = 0.f;
        }
    }
    int t = threadIdx.x;
    #pragma unroll
    for (int o = 32; o > 0; o >>= 1) { l1 += __shfl_down(l1, o, 64); cnt += __shfl_down(cnt, o, 64); }
    __shared__ float s1[4];
    __shared__ int s2[4];
    if ((t & 63) == 0) { s1[t >> 6] = l1; s2[t >> 6] = cnt; }
    __syncthreads();
    if (t == 0) {
        atomicAdd(&acc[A_L1], (double)(s1[0] + s1[1] + s1[2] + s1[3]));
        atomicAdd(&scalw[S_L0], s2[0] + s2[1] + s2[2] + s2[3]);
    }
}

// rewrite the selected band entries (zeroed by k_topk_write) + their L1/L0 contribution
__global__ __launch_bounds__(256) void k_selwrite(float* __restrict__ acts, const int* __restrict__ sel_idx,
        const unsigned* __restrict__ sel_bits, int* scal, double* acc) {
    int t = threadIdx.x;
    int n = min(scal[S_SELCNT], SEL_CAP);
    float l1 = 0.f;
    for (int e = t; e < n; e += 256) {
        float v = __uint_as_float(sel_bits[e]);
        acts[sel_idx[e]] = v;
        l1 += v;
    }
    #pragma unroll
    for (int o = 32; o > 0; o >>= 1) l1 += __shfl_down(l1, o, 64);
    __shared__ float s1[4];
    if ((t & 63) == 0) s1[t >> 6] = l1;
    __syncthreads();
    if (t == 0) {
        atomicAdd(&acc[A_L1], (double)(s1[0] + s1[1] + s1[2] + s1[3]));
        atomicAdd(&scal[S_L0], n);
    }
}

__global__ void k_final(float* out, const int* scal, const double* acc) {
    if (threadIdx.x == 0 && blockIdx.x == 0) {
        double ml2 = (acc[0] + acc[1] + acc[2] + acc[3]) * 0.25 / ((double)NB * ND);
        double l1 = 1e-3 * acc[A_L1] / (double)NB;
        double aux = (scal[S_NDEAD] > 0) ? (1e-2 * acc[A_AUX] / ((double)NB * ND)) : 0.0;
        out[0] = (float)(ml2 + l1 + aux);
        out[1] = (float)ml2;
        out[2] = (float)l1;
        out[3] = (float)aux;
        out[4] = (float)scal[S_L0] / (float)NB;
    }
}

// ---------------- launch ----------------
extern "C" void kernel_launch(void* const* d_in, const int* in_sizes, int n_in,
                              void* d_out, int out_size, void* d_ws, size_t ws_size,
                              hipStream_t stream) {
    const float* x     = (const float*)d_in[0];
    const float* b_dec = (const float*)d_in[1];
    const float* b_enc = (const float*)d_in[2];
    const float* W_enc = (const float*)d_in[3];
    const float* W_dec = (const float*)d_in[4];
    const int*   nbna  = (const int*)d_in[5];

    float* out = (float*)d_out;
    float* acts  = out + 5;                         // [NB, NS] (misaligned region)
    float* recon = out + 5 + (size_t)NB * NS;       // [NB, ND]

    char* ws = (char*)d_ws;
    int*    scal = (int*)(ws + OFF_SCAL);
    double* acc  = (double*)(ws + OFF_ACC);
    int*    h1m  = (int*)(ws + OFF_H1M);
    int*    h1a  = (int*)(ws + OFF_H1A);
    int*    h2m  = (int*)(ws + OFF_H2M);
    int*    h2a  = (int*)(ws + OFF_H2A);
    unsigned char* dead = (unsigned char*)(ws + OFF_DEAD);
    int*      sel_idx  = (int*)(ws + OFF_SEL_IDX);
    unsigned* sel_bits = (unsigned*)(ws + OFF_SEL_BITS);
    int*      bandi = (int*)(ws + OFF_BANDI);
    double*   bandv = (double*)(ws + OFF_BANDV);
    unsigned* cab   = (unsigned*)(ws + OFF_CAB);
    float*    raux  = (float*)(ws + OFF_RAUX);
    unsigned short* Ahg = (unsigned short*)(ws + OFF_AH);
    unsigned short* Alg = (unsigned short*)(ws + OFF_AL);
    unsigned short* WhT = (unsigned short*)(ws + OFF_WHT);
    unsigned short* WlT = (unsigned short*)(ws + OFF_WLT);
    unsigned short* axb = (unsigned short*)(ws + OFF_AXB);
    unsigned short* WdT = (unsigned short*)(ws + OFF_WDT);

    const bool use_mfma     = (ws_size >= WS_NEED_ENC);   // constant per process -> graph-stable
    const bool use_aux_gemm = (ws_size >= WS_NEED_AUX);

    k_init<<<64, 256, 0, stream>>>((int*)d_ws);
    k_dead<<<60, 256, 0, stream>>>(nbna, dead, scal);
    if (use_mfma) {
        k_prep_a<<<512, 256, 0, stream>>>(x, b_dec, Ahg, Alg);
        k_prep_w<<<dim3(NS / 32, ND / 32), 256, 0, stream>>>(W_enc, WhT, WlT);
        k_enc_mfma<<<(NB / 256) * (NS / 128), 512, 0, stream>>>(Ahg, Alg, WhT, WlT, b_enc, acts);
    } else {
        k_enc_gemm<<<dim3(NS / GBN, NB / GBM), 256, 0, stream>>>(x, b_dec, b_enc, W_enc, acts);
    }
    k_hist1<<<1024, 256, 0, stream>>>(acts, dead, h1m, h1a);
    k_scan<<<1, 256, 0, stream>>>(h1m, scal, 0);
    k_scan<<<1, 256, 0, stream>>>(h1a, scal, 1);
    k_hist2<<<NB, 256, 0, stream>>>(acts, dead, scal, h2m, h2a);
    k_scan<<<1, 256, 0, stream>>>(h2m, scal, 2);
    k_scan<<<1, 256, 0, stream>>>(h2a, scal, 3);
    k_collect<<<NB, 256, 0, stream>>>(acts, dead, scal, bandi, cab);
    k_resolve<<<1, 256, 0, stream>>>(cab, scal);
    k_band_re<<<512, 256, 0, stream>>>(x, b_dec, b_enc, W_enc, scal, bandi, bandv);
    k_band_sel<<<1, 256, 0, stream>>>(scal, bandi, bandv, sel_idx, sel_bits);
    k_decode<<<NB, 256, 0, stream>>>(acts, x, b_dec, W_dec, recon, scal, sel_idx, acc);
    if (use_aux_gemm) {
        k_aux_pack<<<NB, 256, 0, stream>>>(acts, dead, scal, axb);
        k_prep_wd<<<dim3(NS / 32, ND / 32), 256, 0, stream>>>(W_dec, WdT);
        k_aux_mfma<<<dim3(ND / 128, NB / 128, KSPLIT), 256, 0, stream>>>(axb, WdT, raux);
        k_aux_diff<<<512, 256, 0, stream>>>(raux, x, recon, acc);
    } else {
        k_aux<<<NB, 256, 0, stream>>>(acts, dead, x, recon, W_dec, scal, acc);
    }
    k_topk_write<<<4096, 256, 0, stream>>>(out, scal, acc, scal);
    k_selwrite<<<1, 256, 0, stream>>>(acts, sel_idx, sel_bits, scal, acc);
    k_final<<<1, 64, 0, stream>>>(out, scal, acc);
}

// Round 5
// 2069.919 us; speedup vs baseline: 1.0170x; 1.0170x over previous
//
#include <hip/hip_runtime.h>

// ---------------- problem constants ----------------
#define NB 2048
#define ND 1024
#define NS 30720
#define K_MAIN 131072LL           // TOP_K * B
#define K_AUX  2097152LL          // TOP_K * AUX_K_MULT * B
#define BAND_CAP 16384
#define SEL_CAP  8192
#define CANDA_CAP 65536
#define EPS_BAND 1e-3f            // covers worst-case |approx - fp64| per element with big margin
#define KSPLIT 4

// ---------------- ws layout (bytes) ----------------
#define OFF_SCAL 0                // int[64]
#define OFF_ACC  256              // double[8]
#define OFF_H1M  512              // int[4096]
#define OFF_H1A  16896
#define OFF_H2M  33280
#define OFF_H2A  49664
#define OFF_ZERO_END 66048        // zeroed every launch
#define OFF_DEAD 66048            // 30720 bytes
#define OFF_SEL_IDX 98304         // int[SEL_CAP]
#define OFF_SEL_BITS 131072       // uint[SEL_CAP]
#define OFF_BANDI 163840          // int[BAND_CAP]
#define OFF_BANDV 229376          // double[BAND_CAP]
#define OFF_CAB  360448           // uint[CANDA_CAP]  (ends 622592)
// aux GEMM per-split output planes: fp32 [KSPLIT][NB][ND] = 32 MB
#define OFF_RAUX 1048576ULL
// split-bf16 planes for the encoder MFMA GEMM
#define OFF_AH   (OFF_RAUX + (unsigned long long)KSPLIT * NB * ND * 4)   // 34603008
#define OFF_AL   (OFF_AH + 2048ULL*1024*2)
#define OFF_WHT  (OFF_AL + 2048ULL*1024*2)          // [30720][1024] bf16 = 60 MB (transposed)
#define OFF_WLT  (OFF_WHT + 30720ULL*1024*2)
#define WS_NEED_ENC (OFF_WLT + 30720ULL*1024*2)     // ~161 MB
// aux planes reuse the encoder-plane region (encoder GEMM is complete before aux pack)
#define OFF_AXB  OFF_AH                              // bf16 [NB][NS] = 126 MB
#define OFF_WDT  (OFF_AXB + 2048ULL*30720*2)         // bf16 [ND][NS] = 63 MB
#define WS_NEED_AUX (OFF_WDT + 1024ULL*30720*2)      // ~213 MB

// scal indices
#define S_NDEAD 0
#define S_B1M 1
#define S_REM1M 2
#define S_B1A 3
#define S_REM1A 4
#define S_T24M 5
#define S_BLO 6
#define S_BHI 7
#define S_T24A 8
#define S_JA 9
#define S_NHI 10
#define S_BANDC 11
#define S_CCA 12
#define S_SELCNT 13
#define S_L0 14
#define S_MINBITS 15

// acc indices
#define A_L2_0 0
#define A_L1 4
#define A_AUX 5

typedef __attribute__((ext_vector_type(8))) short bf16x8;
typedef __attribute__((ext_vector_type(4))) float f32x4;

// ---------------- helpers ----------------
__device__ __forceinline__ float blk_reduce(float v, float* sred) {
    int t = threadIdx.x;
    #pragma unroll
    for (int o = 32; o > 0; o >>= 1) v += __shfl_down(v, o, 64);
    __syncthreads();
    if ((t & 63) == 0) sred[t >> 6] = v;
    __syncthreads();
    return sred[0] + sred[1] + sred[2] + sred[3];
}

__device__ __forceinline__ unsigned short f2bf(float f) {
    unsigned u = __float_as_uint(f);
    unsigned r = (u + 0x7FFFu + ((u >> 16) & 1u)) >> 16;   // RNE
    return (unsigned short)r;
}
__device__ __forceinline__ float bf2f(unsigned short h) {
    return __uint_as_float(((unsigned)h) << 16);
}

#define GLD16(gp, lp) __builtin_amdgcn_global_load_lds( \
    (const __attribute__((address_space(1))) unsigned int*)(gp), \
    (__attribute__((address_space(3))) unsigned int*)(lp), 16, 0, 0)

// ---------------- kernels ----------------
__global__ void k_init(int* w) {
    int n = OFF_ZERO_END / 4;
    for (int i = blockIdx.x * blockDim.x + threadIdx.x; i < n; i += gridDim.x * blockDim.x)
        w[i] = 0;
}

__global__ void k_dead(const int* __restrict__ nbna, unsigned char* __restrict__ dead, int* scal) {
    int stride = gridDim.x * blockDim.x;
    int cnt = 0;
    for (int i = blockIdx.x * blockDim.x + threadIdx.x; i < NS; i += stride) {
        bool d = nbna[i] >= 20;
        dead[i] = d ? 1 : 0;
        cnt += d ? 1 : 0;
    }
    #pragma unroll
    for (int o = 32; o > 0; o >>= 1) cnt += __shfl_down(cnt, o, 64);
    if ((threadIdx.x & 63) == 0 && cnt) atomicAdd(&scal[S_NDEAD], cnt);
}

// split (x - b_dec) into bf16 hi/lo planes, [M][K]
__global__ void k_prep_a(const float* __restrict__ x, const float* __restrict__ b_dec,
                         unsigned short* __restrict__ Ahg, unsigned short* __restrict__ Alg) {
    int stride = gridDim.x * blockDim.x;
    for (int i = blockIdx.x * blockDim.x + threadIdx.x; i < NB * ND; i += stride) {
        float v = x[i] - b_dec[i & (ND - 1)];
        unsigned short h = f2bf(v);
        unsigned short l = f2bf(v - bf2f(h));
        Ahg[i] = h; Alg[i] = l;
    }
}

// transpose + split W_enc [K][N] fp32 -> WhT/WlT [N][K] bf16 (32x32 tiles via LDS)
__global__ __launch_bounds__(256) void k_prep_w(const float* __restrict__ W,
        unsigned short* __restrict__ WhT, unsigned short* __restrict__ WlT) {
    __shared__ float tile[32][33];
    int n0 = blockIdx.x * 32, k0 = blockIdx.y * 32;
    int t = threadIdx.x;
    int c = t & 31, r = t >> 5;          // r in 0..7
    #pragma unroll
    for (int it = 0; it < 4; it++)
        tile[r + it * 8][c] = W[(size_t)(k0 + r + it * 8) * NS + n0 + c];
    __syncthreads();
    int kl = t & 31, nl = t >> 5;
    #pragma unroll
    for (int it = 0; it < 4; it++) {
        float v = tile[kl][nl + it * 8];
        unsigned short h = f2bf(v);
        unsigned short l = f2bf(v - bf2f(h));
        size_t o = (size_t)(n0 + nl + it * 8) * ND + k0 + kl;
        WhT[o] = h; WlT[o] = l;
    }
}

// ============================================================================
// split-bf16 MFMA encoder GEMM: acts = relu(A@W + b_enc), A=Ah+Al, W=Wh+Wl.
// R2 geometry (best measured: 349 us): 256x256 tile, grid 960 (3.75 rounds of
// 256 CUs), BK=32, 8 waves 2Mx4N (per-wave 128x64), double-buffered 128 KiB
// LDS. R4's tile shrink REGRESSED (LDS bytes/FLOP up 33% -> LDS-bound); this
// round grafts R4's proven race-free counted-lgkm single-barrier schedule
// onto the R2 geometry:
//   vmcnt(0); s_barrier        <- own stage(kt) drained BEFORE barrier (cross-
//                                 wave visibility; R3's race was the inverse)
//   stage(kt+1) x8             <- buf[nboff]: its tile-(kt-1) readers finished
//                                 before this barrier (their lgkm(0) at burst3)
//   ds_read ah,bh (12) | bl (4); lgkm(4) -> burst1 MFMA(ah*bh)   bl in flight
//   ds_read al (8);              lgkm(8) -> burst2 MFMA(ah*bl)   al in flight
//                                lgkm(0) -> burst3 MFMA(al*bh)
// One barrier per tile; 12 of 24 reads hidden under MFMA. lgkm counts are
// over-wait-safe (LDS ops complete in order). sched_barrier(0) after each
// inline-asm wait stops MFMA hoisting (rule #18).
// 16B-chunk XOR swizzle (chunk ^= (row>>1)&3) on pre-swizzled global src +
// swizzled ds_read (linear gload_lds dest) -> 0 bank conflicts (verified R1).
// Per-acc FLOP order unchanged (AhBh, AhBl, AlBh per fragment, kt 0..31) ->
// bit-identical to the R1/R2/R4 passing kernels.
// ============================================================================
#define ENC_STAGE(bufoff, p, gptr, r, ktn) GLD16((gptr) + (size_t)(r) * 128 * ND + (size_t)(ktn) * 32, \
    smem + (bufoff) + (p) * 8192 + (r) * 4096 + ldsw)

#define ENC_RD_AH(boff) { _Pragma("unroll") \
    for (int i = 0; i < 8; i++) ah[i] = *(const bf16x8*)&smem[(boff) + (arb + i * 16) * 32 + cph8]; }
#define ENC_RD_AL(boff) { _Pragma("unroll") \
    for (int i = 0; i < 8; i++) al[i] = *(const bf16x8*)&smem[(boff) + 8192 + (arb + i * 16) * 32 + cph8]; }
#define ENC_RD_BH(boff) { _Pragma("unroll") \
    for (int j = 0; j < 4; j++) bh[j] = *(const bf16x8*)&smem[(boff) + 2 * 8192 + (brb + j * 16) * 32 + cph8]; }
#define ENC_RD_BL(boff) { _Pragma("unroll") \
    for (int j = 0; j < 4; j++) bl[j] = *(const bf16x8*)&smem[(boff) + 3 * 8192 + (brb + j * 16) * 32 + cph8]; }

#define ENC_MFMA_BURST(AF, BF) { \
    __builtin_amdgcn_s_setprio(1); \
    _Pragma("unroll") for (int i = 0; i < 8; i++) \
        _Pragma("unroll") for (int j = 0; j < 4; j++) \
            acc[i][j] = __builtin_amdgcn_mfma_f32_16x16x32_bf16(AF[i], BF[j], acc[i][j], 0, 0, 0); \
    __builtin_amdgcn_s_setprio(0); }

__global__ __launch_bounds__(512, 2) void k_enc_mfma(
        const unsigned short* __restrict__ Ahg, const unsigned short* __restrict__ Alg,
        const unsigned short* __restrict__ WhT, const unsigned short* __restrict__ WlT,
        const float* __restrict__ b_enc, float* __restrict__ acts) {
    // 2 bufs x 4 planes (Ah,Al,Bh,Bl) x [256][32] bf16 = 128 KiB
    __shared__ unsigned short smem[65536];
    const int t = threadIdx.x;
    const int lane = t & 63, w = t >> 6;
    const int wm = w >> 2, wn = w & 3;                 // 2x4 wave grid; wave out = 128x64
    // bijective XCD-chunked swizzle: 960 = 8 x 120; XCD x gets n-tiles [x*15, x*15+15)
    const int flat = blockIdx.x;
    const int wg = (flat & 7) * 120 + (flat >> 3);
    const int n0 = (wg >> 3) * 256;
    const int m0 = (wg & 7) * 256;
    const int ln15 = lane & 15, q = lane >> 4;
    // physical chunk offset (shorts) for fragment reads: (q ^ ((row>>1)&3)) * 8
    const int cph8 = ((q ^ ((lane >> 1) & 3)) << 3);

    // staging: wave w covers rows [r*128 + w*16, +16); lane l -> row +(l>>2), phys chunk l&3
    const int srow = w * 16 + (lane >> 2);
    const int sq8 = (((lane & 3) ^ ((lane >> 3) & 3)) << 3);   // logical chunk for this phys slot
    const unsigned short* gA  = Ahg + (size_t)(m0 + srow) * ND + sq8;
    const unsigned short* gAl = Alg + (size_t)(m0 + srow) * ND + sq8;
    const unsigned short* gB  = WhT + (size_t)(n0 + srow) * ND + sq8;
    const unsigned short* gBl = WlT + (size_t)(n0 + srow) * ND + sq8;
    const int ldsw = w * 512;                                  // wave slot in half-plane (shorts)

    f32x4 acc[8][4];
    #pragma unroll
    for (int i = 0; i < 8; i++)
        #pragma unroll
        for (int j = 0; j < 4; j++) acc[i][j] = (f32x4){0.f, 0.f, 0.f, 0.f};

    const int arb = wm * 128 + ln15;       // A frag row base (+ i*16)
    const int brb = wn * 64 + ln15;        // B frag row base (+ j*16)

    // prologue: stage tile 0 into buf 0
    ENC_STAGE(0, 0, gA, 0, 0);  ENC_STAGE(0, 0, gA, 1, 0);
    ENC_STAGE(0, 2, gB, 0, 0);  ENC_STAGE(0, 2, gB, 1, 0);
    ENC_STAGE(0, 3, gBl, 0, 0); ENC_STAGE(0, 3, gBl, 1, 0);
    ENC_STAGE(0, 1, gAl, 0, 0); ENC_STAGE(0, 1, gAl, 1, 0);

    for (int kt = 0; kt < 32; ++kt) {
        const int cboff = (kt & 1) * 32768;
        const int nboff = cboff ^ 32768;
        bf16x8 ah[8], bh[4], bl[4], al[8];

        // own stage(kt) drained BEFORE barrier -> all waves' staged data visible
        asm volatile("s_waitcnt vmcnt(0)" ::: "memory");
        __builtin_amdgcn_s_barrier();
        __builtin_amdgcn_sched_barrier(0);
        if (kt < 31) {
            const int kn = kt + 1;
            ENC_STAGE(nboff, 0, gA, 0, kn);  ENC_STAGE(nboff, 0, gA, 1, kn);
            ENC_STAGE(nboff, 2, gB, 0, kn);  ENC_STAGE(nboff, 2, gB, 1, kn);
            ENC_STAGE(nboff, 3, gBl, 0, kn); ENC_STAGE(nboff, 3, gBl, 1, kn);
            ENC_STAGE(nboff, 1, gAl, 0, kn); ENC_STAGE(nboff, 1, gAl, 1, kn);
        }

        // read group 1: ah + bh (12x ds_read_b128)
        ENC_RD_AH(cboff) ENC_RD_BH(cboff)
        __builtin_amdgcn_sched_barrier(0);                     // group1 strictly before bl
        // read group 2: bl (4x)
        ENC_RD_BL(cboff)
        asm volatile("s_waitcnt lgkmcnt(4)" ::: "memory");     // ah+bh done; bl may fly
        __builtin_amdgcn_sched_barrier(0);
        ENC_MFMA_BURST(ah, bh)
        // read group 3 (issues overlap burst1): al (8x)
        ENC_RD_AL(cboff)
        asm volatile("s_waitcnt lgkmcnt(8)" ::: "memory");     // bl done; al may fly
        __builtin_amdgcn_sched_barrier(0);
        ENC_MFMA_BURST(ah, bl)
        asm volatile("s_waitcnt lgkmcnt(0)" ::: "memory");     // al done
        __builtin_amdgcn_sched_barrier(0);
        ENC_MFMA_BURST(al, bh)
    }

    #pragma unroll
    for (int j = 0; j < 4; j++) {
        int n = n0 + wn * 64 + j * 16 + ln15;
        float be = b_enc[n];
        #pragma unroll
        for (int i = 0; i < 8; i++) {
            int mrow = m0 + wm * 128 + i * 16 + q * 4;
            #pragma unroll
            for (int rg = 0; rg < 4; rg++)
                acts[(size_t)(mrow + rg) * NS + n] = fmaxf(acc[i][j][rg] + be, 0.f);
        }
    }
}

// fallback fp32 encoder GEMM (used when ws too small for bf16 planes)
#define GBM 128
#define GBN 128
#define GBK 8
__global__ __launch_bounds__(256) void k_enc_gemm(const float* __restrict__ x,
        const float* __restrict__ b_dec, const float* __restrict__ b_enc,
        const float* __restrict__ W, float* __restrict__ acts) {
    __shared__ float As[GBK][GBM];
    __shared__ float Bs[GBK][GBN];
    const int t = threadIdx.x;
    const int tx = t & 15, ty = t >> 4;
    const int m0 = blockIdx.y * GBM, n0 = blockIdx.x * GBN;
    const int am = t >> 1, ak = (t & 1) * 4;
    const int bk = t >> 5, bnq = (t & 31) * 4;
    float acc[8][8];
    #pragma unroll
    for (int i = 0; i < 8; i++)
        #pragma unroll
        for (int j = 0; j < 8; j++) acc[i][j] = 0.f;
    for (int k0 = 0; k0 < ND; k0 += GBK) {
        float4 av = *(const float4*)(x + (size_t)(m0 + am) * ND + k0 + ak);
        float4 bd = *(const float4*)(b_dec + k0 + ak);
        As[ak + 0][am] = av.x - bd.x;
        As[ak + 1][am] = av.y - bd.y;
        As[ak + 2][am] = av.z - bd.z;
        As[ak + 3][am] = av.w - bd.w;
        *(float4*)&Bs[bk][bnq] = *(const float4*)(W + (size_t)(k0 + bk) * NS + n0 + bnq);
        __syncthreads();
        #pragma unroll
        for (int kk = 0; kk < GBK; kk++) {
            float a[8], b[8];
            *(float4*)&a[0] = *(const float4*)&As[kk][ty * 4];
            *(float4*)&a[4] = *(const float4*)&As[kk][64 + ty * 4];
            *(float4*)&b[0] = *(const float4*)&Bs[kk][tx * 4];
            *(float4*)&b[4] = *(const float4*)&Bs[kk][64 + tx * 4];
            #pragma unroll
            for (int i = 0; i < 8; i++)
                #pragma unroll
                for (int j = 0; j < 8; j++)
                    acc[i][j] = fmaf(a[i], b[j], acc[i][j]);
        }
        __syncthreads();
    }
    float be[8];
    #pragma unroll
    for (int j = 0; j < 4; j++) {
        be[j]     = b_enc[n0 + tx * 4 + j];
        be[4 + j] = b_enc[n0 + 64 + tx * 4 + j];
    }
    #pragma unroll
    for (int i = 0; i < 8; i++) {
        int row = m0 + ((i < 4) ? (ty * 4 + i) : (64 + ty * 4 + i - 4));
        float* orow = acts + (size_t)row * NS + n0;
        #pragma unroll
        for (int j = 0; j < 4; j++) {
            orow[tx * 4 + j]      = fmaxf(acc[i][j] + be[j], 0.f);
            orow[64 + tx * 4 + j] = fmaxf(acc[i][4 + j] + be[4 + j], 0.f);
        }
    }
}

// fused coarse histograms: main (all) + aux (dead cols only); bins = bits >> 20
__global__ __launch_bounds__(256) void k_hist1(const float* __restrict__ acts,
        const unsigned char* __restrict__ dead, int* h1m, int* h1a) {
    __shared__ int hm[4096], ha[4096];
    int t = threadIdx.x;
    for (int i = t; i < 4096; i += 256) { hm[i] = 0; ha[i] = 0; }
    __syncthreads();
    for (int row = blockIdx.x; row < NB; row += gridDim.x) {
        const float* pr = acts + (size_t)row * NS;
        for (int c = t; c < NS; c += 256) {
            unsigned bits = __float_as_uint(pr[c]);
            bool isz = (bits == 0u);
            bool dd = dead[c] != 0;
            unsigned long long mz = __ballot(isz);
            unsigned long long mza = __ballot(isz && dd);
            if ((t & 63) == 0) {
                int nz = __popcll(mz);
                if (nz) atomicAdd(&hm[0], nz);
                int nza = __popcll(mza);
                if (nza) atomicAdd(&ha[0], nza);
            }
            if (!isz) {
                atomicAdd(&hm[bits >> 20], 1);
                if (dd) atomicAdd(&ha[bits >> 20], 1);
            }
        }
    }
    __syncthreads();
    for (int i = t; i < 4096; i += 256) {
        if (hm[i]) atomicAdd(&h1m[i], hm[i]);
        if (ha[i]) atomicAdd(&h1a[i], ha[i]);
    }
}

// suffix-scan over a 4096-bin histogram; finds bin containing rank k (from top)
__global__ void k_scan(const int* __restrict__ hist, int* scal, int mode) {
    __shared__ long long csum[256];
    __shared__ long long totsh;
    int t = threadIdx.x;
    int base = t * 16;
    int h[16];
    long long loc = 0;
    #pragma unroll
    for (int i = 0; i < 16; i++) { h[i] = hist[base + i]; loc += h[i]; }
    csum[t] = loc;
    __syncthreads();
    if (t == 0) {
        long long run = 0;
        for (int c = 255; c >= 0; c--) { long long tmp = csum[c]; csum[c] = run; run += tmp; }
        totsh = run;
    }
    __syncthreads();
    long long k;
    if (mode == 0) k = K_MAIN;
    else if (mode == 1) k = K_AUX;
    else if (mode == 2) k = (long long)scal[S_REM1M];
    else {
        if (scal[S_B1A] < 0) { if (t == 0) { scal[S_T24A] = -1; scal[S_MINBITS] = 0; } return; }
        k = (long long)scal[S_REM1A];
    }
    if (mode == 1 && k > totsh) { if (t == 0) scal[S_B1A] = -1; return; }
    long long cum = csum[t];
    int fb = -1; long long rem = 0;
    for (int i = 15; i >= 0; i--) {
        long long ca = cum;
        cum += h[i];
        if (ca < k && k <= cum) { fb = base + i; rem = k - ca; }
    }
    if (fb >= 0) {
        if (mode == 0)      { scal[S_B1M] = fb; scal[S_REM1M] = (int)rem; }
        else if (mode == 1) { scal[S_B1A] = fb; scal[S_REM1A] = (int)rem; }
        else if (mode == 2) {
            int t24 = (scal[S_B1M] << 12) | fb;
            scal[S_T24M] = t24;
            float center = __uint_as_float((((unsigned)t24) << 8) | 128u);
            float lo = center - EPS_BAND;
            if (lo < 0.f) lo = 0.f;
            scal[S_BLO] = (int)__float_as_uint(lo);
            scal[S_BHI] = (int)__float_as_uint(center + EPS_BAND);
        }
        else { scal[S_T24A] = (scal[S_B1A] << 12) | fb; scal[S_JA] = (int)rem; }
    }
}

// fine histograms inside the selected coarse bins
__global__ __launch_bounds__(256) void k_hist2(const float* __restrict__ acts,
        const unsigned char* __restrict__ dead, const int* scal, int* h2m, int* h2a) {
    int b1m = scal[S_B1M], b1a = scal[S_B1A];
    int row = blockIdx.x, t = threadIdx.x;
    const float* pr = acts + (size_t)row * NS;
    for (int c = t; c < NS; c += 256) {
        unsigned bits = __float_as_uint(pr[c]);
        int hi = (int)(bits >> 20);
        if (hi == b1m) atomicAdd(&h2m[(bits >> 8) & 0xFFF], 1);
        if (b1a >= 0 && hi == b1a && dead[c]) atomicAdd(&h2a[(bits >> 8) & 0xFFF], 1);
    }
}

// single pass: exact count above band (n_hi), band-member collection, aux candidates
__global__ __launch_bounds__(256) void k_collect(const float* __restrict__ acts,
        const unsigned char* __restrict__ dead, int* scal,
        int* bandi, unsigned* cab) {
    int row = blockIdx.x, t = threadIdx.x;
    unsigned blo = (unsigned)scal[S_BLO], bhi = (unsigned)scal[S_BHI];
    int t24a = scal[S_T24A];
    const float* pr = acts + (size_t)row * NS;
    int cnt = 0;
    for (int c = t; c < NS; c += 256) {
        unsigned bits = __float_as_uint(pr[c]);
        if (bits > bhi) cnt++;
        else if (bits >= blo) {
            int p = atomicAdd(&scal[S_BANDC], 1);
            if (p < BAND_CAP) bandi[p] = row * NS + c;
        }
        if (t24a >= 0 && (bits >> 8) == (unsigned)t24a && dead[c]) {
            int p = atomicAdd(&scal[S_CCA], 1);
            if (p < CANDA_CAP) cab[p] = bits;
        }
    }
    #pragma unroll
    for (int o = 32; o > 0; o >>= 1) cnt += __shfl_down(cnt, o, 64);
    __shared__ int s2[4];
    if ((t & 63) == 0) s2[t >> 6] = cnt;
    __syncthreads();
    if (t == 0) {
        int tot = s2[0] + s2[1] + s2[2] + s2[3];
        if (tot) atomicAdd(&scal[S_NHI], tot);
    }
}

// aux threshold value from boundary-fine-bin candidates
__global__ __launch_bounds__(256) void k_resolve(const unsigned* __restrict__ cab, int* scal) {
    __shared__ int h[256];
    int t = threadIdx.x;
    h[t] = 0;
    __syncthreads();
    int t24a = scal[S_T24A];
    if (t24a < 0) { if (t == 0) scal[S_MINBITS] = 0; return; }
    int cnt = min(scal[S_CCA], CANDA_CAP);
    int ja = scal[S_JA];
    for (int e = t; e < cnt; e += 256) atomicAdd(&h[cab[e] & 0xFF], 1);
    __syncthreads();
    if (t == 0) {
        long long cum = 0; int L = 0;
        for (int b = 255; b >= 0; b--) {
            long long ca = cum; cum += h[b];
            if (ca < ja && ja <= cum) { L = b; break; }
        }
        scal[S_MINBITS] = (int)((((unsigned)t24a) << 8) | (unsigned)L);
    }
}

// fp64 recompute of band elements (exact vs reference)
__global__ __launch_bounds__(256) void k_band_re(const float* __restrict__ x,
        const float* __restrict__ b_dec, const float* __restrict__ b_enc,
        const float* __restrict__ W, const int* scal,
        const int* __restrict__ bandi, double* __restrict__ bandv) {
    int n = min(scal[S_BANDC], BAND_CAP);
    int t = threadIdx.x;
    __shared__ double sd[4];
    for (int e = blockIdx.x; e < n; e += gridDim.x) {
        int idx = bandi[e];
        int r = idx / NS, c = idx - r * NS;
        double s = 0.0;
        #pragma unroll
        for (int j = 0; j < 4; j++) {
            int d = t + j * 256;
            s += ((double)x[(size_t)r * ND + d] - (double)b_dec[d]) * (double)W[(size_t)d * NS + c];
        }
        #pragma unroll
        for (int o = 32; o > 0; o >>= 1) s += __shfl_down(s, o, 64);
        if ((t & 63) == 0) sd[t >> 6] = s;
        __syncthreads();
        if (t == 0) {
            double v = sd[0] + sd[1] + sd[2] + sd[3] + (double)b_enc[c];
            bandv[e] = fmax(v, 0.0);
        }
        __syncthreads();
    }
}

// exact selection within band: rank by (v64 desc, idx asc); keep rank < need = K - n_hi
__global__ __launch_bounds__(256) void k_band_sel(int* scal,
        const int* __restrict__ bandi, const double* __restrict__ bandv,
        int* sel_idx, unsigned* sel_bits) {
    int n = min(scal[S_BANDC], BAND_CAP);
    int need = (int)(K_MAIN - (long long)scal[S_NHI]);
    if (need < 0) need = 0;
    if (need > n) need = n;
    int t = threadIdx.x;
    for (int e = t; e < n; e += 256) {
        double v = bandv[e];
        int idx = bandi[e];
        int rank = 0;
        for (int j = 0; j < n; j++) {
            double vj = bandv[j];
            rank += (vj > v || (vj == v && bandi[j] < idx)) ? 1 : 0;
        }
        if (rank < need) {
            int p = atomicAdd(&scal[S_SELCNT], 1);
            if (p < SEL_CAP) { sel_idx[p] = idx; sel_bits[p] = __float_as_uint((float)v); }
        }
    }
}

// hierarchical sparse decode: one block per row; membership = bits > bhi OR selected band element
__global__ __launch_bounds__(256) void k_decode(const float* __restrict__ acts,
        const float* __restrict__ x, const float* __restrict__ b_dec, const float* __restrict__ Wd,
        float* __restrict__ recon, const int* scal,
        const int* __restrict__ sel_idx, double* acc) {
    int row = blockIdx.x, t = threadIdx.x;
    unsigned blo = (unsigned)scal[S_BLO], bhi = (unsigned)scal[S_BHI];
    int selcnt = min(scal[S_SELCNT], SEL_CAP);
    __shared__ int lj[2048];
    __shared__ float lv[2048];
    __shared__ int lcnt;
    __shared__ float sred[4];
    const int d0 = t * 4;
    float4 r;
    r.x = b_dec[d0]; r.y = b_dec[d0 + 1]; r.z = b_dec[d0 + 2]; r.w = b_dec[d0 + 3];
    float4 xv = *(const float4*)(x + (size_t)row * ND + d0);
    const float* arow = acts + (size_t)row * NS;
    const int bnds[5] = {0, 2048, 6144, 14336, NS};
    for (int g = 0; g < 4; g++) {
        for (int c0 = bnds[g]; c0 < bnds[g + 1]; c0 += 2048) {
            __syncthreads();
            if (t == 0) lcnt = 0;
            __syncthreads();
            #pragma unroll
            for (int u = 0; u < 8; u++) {
                int c = c0 + u * 256 + t;
                float v = arow[c];
                unsigned bits = __float_as_uint(v);
                bool keep = bits > bhi;
                if (!keep && bits >= blo) {
                    int flat = row * NS + c;
                    for (int e = 0; e < selcnt; e++)
                        if (sel_idx[e] == flat) { keep = true; break; }
                }
                if (keep) { int p = atomicAdd(&lcnt, 1); lj[p] = c; lv[p] = v; }
            }
            __syncthreads();
            int n = lcnt;
            for (int e = 0; e < n; e++) {
                float a_ = lv[e];
                float4 w = *(const float4*)(Wd + (size_t)lj[e] * ND + d0);
                r.x = fmaf(a_, w.x, r.x);
                r.y = fmaf(a_, w.y, r.y);
                r.z = fmaf(a_, w.z, r.z);
                r.w = fmaf(a_, w.w, r.w);
            }
        }
        float dx = r.x - xv.x, dy = r.y - xv.y, dz = r.z - xv.z, dw = r.w - xv.w;
        float ss = dx * dx + dy * dy + dz * dz + dw * dw;
        float tot = blk_reduce(ss, sred);
        if (t == 0) atomicAdd(&acc[A_L2_0 + g], (double)tot);
    }
    float* orow = recon + (size_t)row * ND + d0;   // region misaligned -> scalar stores
    orow[0] = r.x; orow[1] = r.y; orow[2] = r.z; orow[3] = r.w;
}

// ---- aux via dense masked GEMM ----
// pack acts_aux = relu(acts - minval) * dead into bf16 plane [NB][NS]
__global__ __launch_bounds__(256) void k_aux_pack(const float* __restrict__ acts,
        const unsigned char* __restrict__ dead, const int* scal,
        unsigned short* __restrict__ axb) {
    int row = blockIdx.x, t = threadIdx.x;
    float minval = __uint_as_float((unsigned)scal[S_MINBITS]);
    const float* arow = acts + (size_t)row * NS;
    unsigned short* orow = axb + (size_t)row * NS;
    for (int c = t; c < NS; c += 256) {
        float v = arow[c];
        float o = (dead[c] && v > minval) ? (v - minval) : 0.f;
        orow[c] = f2bf(o);
    }
}

// transpose W_dec [S][D] fp32 -> WdT [D][S] bf16
__global__ __launch_bounds__(256) void k_prep_wd(const float* __restrict__ Wd,
        unsigned short* __restrict__ WdT) {
    __shared__ float tile[32][33];
    int s0 = blockIdx.x * 32, d0 = blockIdx.y * 32;
    int t = threadIdx.x;
    int c = t & 31, r = t >> 5;
    #pragma unroll
    for (int it = 0; it < 4; it++)
        tile[r + it * 8][c] = Wd[(size_t)(s0 + r + it * 8) * ND + d0 + c];
    __syncthreads();
    int sl = t & 31, dl = t >> 5;
    #pragma unroll
    for (int it = 0; it < 4; it++)
        WdT[(size_t)(d0 + dl + it * 8) * NS + s0 + sl] = f2bf(tile[sl][dl + it * 8]);
}

// bf16 MFMA aux GEMM: raux[z] = acts_aux @ W_dec (K-split over z), per-split fp32 planes
__global__ __launch_bounds__(256) void k_aux_mfma(
        const unsigned short* __restrict__ axb, const unsigned short* __restrict__ WdT,
        float* __restrict__ raux) {
    __shared__ unsigned short As[128 * 32], Bs[128 * 32];
    const int t = threadIdx.x;
    const int lane = t & 63, w = t >> 6;
    const int wm = w >> 1, wn = w & 1;
    const int m0 = blockIdx.y * 128, n0 = blockIdx.x * 128;
    const int kbase = blockIdx.z * (NS / KSPLIT);
    const int ln15 = lane & 15, q = lane >> 4;

    f32x4 acc[4][4];
    #pragma unroll
    for (int i = 0; i < 4; i++)
        #pragma unroll
        for (int j = 0; j < 4; j++) acc[i][j] = (f32x4){0.f, 0.f, 0.f, 0.f};

    // waves 0,1 stage A halves; waves 2,3 stage B halves (64 rows x 32 cols each)
    const unsigned short* gbase;
    unsigned short* lbase;
    if (w < 2) { gbase = axb + (size_t)(m0 + w * 64) * NS; lbase = As + w * 64 * 32; }
    else       { gbase = WdT + (size_t)(n0 + (w - 2) * 64) * NS; lbase = Bs + (w - 2) * 64 * 32; }
    const unsigned short* glane = gbase + (size_t)(lane >> 2) * NS + (lane & 3) * 8 + kbase;

    for (int k0 = 0; k0 < NS / KSPLIT; k0 += 32) {
        __syncthreads();
        #pragma unroll
        for (int ch = 0; ch < 4; ch++)
            GLD16(glane + (size_t)ch * 16 * NS + k0, lbase + ch * 512);
        __syncthreads();

        bf16x8 af[4];
        #pragma unroll
        for (int i = 0; i < 4; i++)
            af[i] = *(const bf16x8*)&As[(wm * 64 + i * 16 + ln15) * 32 + q * 8];
        #pragma unroll
        for (int j = 0; j < 4; j++) {
            bf16x8 bf = *(const bf16x8*)&Bs[(wn * 64 + j * 16 + ln15) * 32 + q * 8];
            #pragma unroll
            for (int i = 0; i < 4; i++)
                acc[i][j] = __builtin_amdgcn_mfma_f32_16x16x32_bf16(af[i], bf, acc[i][j], 0, 0, 0);
        }
    }
    float* rz = raux + (size_t)blockIdx.z * NB * ND;
    #pragma unroll
    for (int j = 0; j < 4; j++) {
        int n = n0 + wn * 64 + j * 16 + ln15;
        #pragma unroll
        for (int i = 0; i < 4; i++) {
            int mrow = m0 + wm * 64 + i * 16 + q * 4;
            #pragma unroll
            for (int rg = 0; rg < 4; rg++)
                rz[(size_t)(mrow + rg) * ND + n] = acc[i][j][rg];
        }
    }
}

// aux loss: sum over B*D of (sum_z raux[z] - (x - recon))^2
__global__ __launch_bounds__(256) void k_aux_diff(const float* __restrict__ raux,
        const float* __restrict__ x, const float* __restrict__ recon, double* acc) {
    __shared__ float sred[4];
    float ss = 0.f;
    int stride = gridDim.x * blockDim.x;
    for (int i = blockIdx.x * blockDim.x + threadIdx.x; i < NB * ND; i += stride) {
        float ra = raux[i];
        #pragma unroll
        for (int z = 1; z < KSPLIT; z++) ra += raux[(size_t)z * NB * ND + i];
        float d = ra - (x[i] - recon[i]);
        ss += d * d;
    }
    float tot = blk_reduce(ss, sred);
    if (threadIdx.x == 0) atomicAdd(&acc[A_AUX], (double)tot);
}

// fallback aux: sparse gather per row
__global__ __launch_bounds__(256) void k_aux(const float* __restrict__ acts,
        const unsigned char* __restrict__ dead, const float* __restrict__ x,
        const float* __restrict__ recon, const float* __restrict__ Wd,
        const int* scal, double* acc) {
    int row = blockIdx.x, t = threadIdx.x;
    float minval = __uint_as_float((unsigned)scal[S_MINBITS]);
    __shared__ int lj[2048];
    __shared__ float lv[2048];
    __shared__ int lcnt;
    __shared__ float sred[4];
    float4 r = {0.f, 0.f, 0.f, 0.f};
    const float* arow = acts + (size_t)row * NS;
    const int d0 = t * 4;
    for (int c0 = 0; c0 < NS; c0 += 2048) {
        __syncthreads();
        if (t == 0) lcnt = 0;
        __syncthreads();
        #pragma unroll
        for (int u = 0; u < 8; u++) {
            int c = c0 + u * 256 + t;
            float v = arow[c];
            if (dead[c] && v > minval) {
                int p = atomicAdd(&lcnt, 1);
                lj[p] = c; lv[p] = v - minval;
            }
        }
        __syncthreads();
        int n = lcnt;
        for (int e = 0; e < n; e++) {
            float a_ = lv[e];
            float4 w = *(const float4*)(Wd + (size_t)lj[e] * ND + d0);
            r.x = fmaf(a_, w.x, r.x);
            r.y = fmaf(a_, w.y, r.y);
            r.z = fmaf(a_, w.z, r.z);
            r.w = fmaf(a_, w.w, r.w);
        }
    }
    const float* xr = x + (size_t)row * ND + d0;
    const float* rr = recon + (size_t)row * ND + d0;
    float dx = r.x - (xr[0] - rr[0]);
    float dy = r.y - (xr[1] - rr[1]);
    float dz = r.z - (xr[2] - rr[2]);
    float dw = r.w - (xr[3] - rr[3]);
    float ss = dx * dx + dy * dy + dz * dz + dw * dw;
    float tot = blk_reduce(ss, sred);
    if (t == 0) atomicAdd(&acc[A_AUX], (double)tot);
}

// in-place top-k zeroing over d_out acts region (strict bits > bhi) + L1/L0 for definite members
__global__ __launch_bounds__(256) void k_topk_write(float* __restrict__ out, const int* scal, double* acc, int* scalw) {
    unsigned bhi = (unsigned)scal[S_BHI];
    float l1 = 0.f;
    int cnt = 0;
    const long long vstart = 8, nvec = 15728639;   // [8, 62914564) as float4
    long long stride = (long long)gridDim.x * blockDim.x;
    for (long long i = (long long)blockIdx.x * blockDim.x + threadIdx.x; i < nvec; i += stride) {
        float4* p = (float4*)(out + vstart) + i;
        float4 v = *p;
        #define PROC(F) { unsigned b = __float_as_uint(v.F); if (b > bhi) { l1 += v.F; cnt++; } else v.F = 0.f; }
        PROC(x) PROC(y) PROC(z) PROC(w)
        #undef PROC
        *p = v;
    }
    if (blockIdx.x == 0 && threadIdx.x == 0) {
        const long long head[4] = {5, 6, 7, 62914564LL};
        for (int q = 0; q < 4; q++) {
            float v = out[head[q]];
            unsigned b = __float_as_uint(v);
            if (b > bhi) { l1 += v; cnt++; } else out[head[q]] = 0.f;
        }
    }
    int t = threadIdx.x;
    #pragma unroll
    for (int o = 32; o > 0; o >>= 1) { l1 += __shfl_down(l1, o, 64); cnt += __shfl_down(cnt, o, 64); }
    __shared__ float s1[4];
    __shared__ int s2[4];
    if ((t & 63) == 0) { s1[t >> 6] = l1; s2[t >> 6] = cnt; }
    __syncthreads();
    if (t == 0) {
        atomicAdd(&acc[A_L1], (double)(s1[0] + s1[1] + s1[2] + s1[3]));
        atomicAdd(&scalw[S_L0], s2[0] + s2[1] + s2[2] + s2[3]);
    }
}

// rewrite the selected band entries (zeroed by k_topk_write) + their L1/L0 contribution
__global__ __launch_bounds__(256) void k_selwrite(float* __restrict__ acts, const int* __restrict__ sel_idx,
        const unsigned* __restrict__ sel_bits, int* scal, double* acc) {
    int t = threadIdx.x;
    int n = min(scal[S_SELCNT], SEL_CAP);
    float l1 = 0.f;
    for (int e = t; e < n; e += 256) {
        float v = __uint_as_float(sel_bits[e]);
        acts[sel_idx[e]] = v;
        l1 += v;
    }
    #pragma unroll
    for (int o = 32; o > 0; o >>= 1) l1 += __shfl_down(l1, o, 64);
    __shared__ float s1[4];
    if ((t & 63) == 0) s1[t >> 6] = l1;
    __syncthreads();
    if (t == 0) {
        atomicAdd(&acc[A_L1], (double)(s1[0] + s1[1] + s1[2] + s1[3]));
        atomicAdd(&scal[S_L0], n);
    }
}

__global__ void k_final(float* out, const int* scal, const double* acc) {
    if (threadIdx.x == 0 && blockIdx.x == 0) {
        double ml2 = (acc[0] + acc[1] + acc[2] + acc[3]) * 0.25 / ((double)NB * ND);
        double l1 = 1e-3 * acc[A_L1] / (double)NB;
        double aux = (scal[S_NDEAD] > 0) ? (1e-2 * acc[A_AUX] / ((double)NB * ND)) : 0.0;
        out[0] = (float)(ml2 + l1 + aux);
        out[1] = (float)ml2;
        out[2] = (float)l1;
        out[3] = (float)aux;
        out[4] = (float)scal[S_L0] / (float)NB;
    }
}

// ---------------- launch ----------------
extern "C" void kernel_launch(void* const* d_in, const int* in_sizes, int n_in,
                              void* d_out, int out_size, void* d_ws, size_t ws_size,
                              hipStream_t stream) {
    const float* x     = (const float*)d_in[0];
    const float* b_dec = (const float*)d_in[1];
    const float* b_enc = (const float*)d_in[2];
    const float* W_enc = (const float*)d_in[3];
    const float* W_dec = (const float*)d_in[4];
    const int*   nbna  = (const int*)d_in[5];

    float* out = (float*)d_out;
    float* acts  = out + 5;                         // [NB, NS] (misaligned region)
    float* recon = out + 5 + (size_t)NB * NS;       // [NB, ND]

    char* ws = (char*)d_ws;
    int*    scal = (int*)(ws + OFF_SCAL);
    double* acc  = (double*)(ws + OFF_ACC);
    int*    h1m  = (int*)(ws + OFF_H1M);
    int*    h1a  = (int*)(ws + OFF_H1A);
    int*    h2m  = (int*)(ws + OFF_H2M);
    int*    h2a  = (int*)(ws + OFF_H2A);
    unsigned char* dead = (unsigned char*)(ws + OFF_DEAD);
    int*      sel_idx  = (int*)(ws + OFF_SEL_IDX);
    unsigned* sel_bits = (unsigned*)(ws + OFF_SEL_BITS);
    int*      bandi = (int*)(ws + OFF_BANDI);
    double*   bandv = (double*)(ws + OFF_BANDV);
    unsigned* cab   = (unsigned*)(ws + OFF_CAB);
    float*    raux  = (float*)(ws + OFF_RAUX);
    unsigned short* Ahg = (unsigned short*)(ws + OFF_AH);
    unsigned short* Alg = (unsigned short*)(ws + OFF_AL);
    unsigned short* WhT = (unsigned short*)(ws + OFF_WHT);
    unsigned short* WlT = (unsigned short*)(ws + OFF_WLT);
    unsigned short* axb = (unsigned short*)(ws + OFF_AXB);
    unsigned short* WdT = (unsigned short*)(ws + OFF_WDT);

    const bool use_mfma     = (ws_size >= WS_NEED_ENC);   // constant per process -> graph-stable
    const bool use_aux_gemm = (ws_size >= WS_NEED_AUX);

    k_init<<<64, 256, 0, stream>>>((int*)d_ws);
    k_dead<<<60, 256, 0, stream>>>(nbna, dead, scal);
    if (use_mfma) {
        k_prep_a<<<512, 256, 0, stream>>>(x, b_dec, Ahg, Alg);
        k_prep_w<<<dim3(NS / 32, ND / 32), 256, 0, stream>>>(W_enc, WhT, WlT);
        k_enc_mfma<<<(NB / 256) * (NS / 256), 512, 0, stream>>>(Ahg, Alg, WhT, WlT, b_enc, acts);
    } else {
        k_enc_gemm<<<dim3(NS / GBN, NB / GBM), 256, 0, stream>>>(x, b_dec, b_enc, W_enc, acts);
    }
    k_hist1<<<1024, 256, 0, stream>>>(acts, dead, h1m, h1a);
    k_scan<<<1, 256, 0, stream>>>(h1m, scal, 0);
    k_scan<<<1, 256, 0, stream>>>(h1a, scal, 1);
    k_hist2<<<NB, 256, 0, stream>>>(acts, dead, scal, h2m, h2a);
    k_scan<<<1, 256, 0, stream>>>(h2m, scal, 2);
    k_scan<<<1, 256, 0, stream>>>(h2a, scal, 3);
    k_collect<<<NB, 256, 0, stream>>>(acts, dead, scal, bandi, cab);
    k_resolve<<<1, 256, 0, stream>>>(cab, scal);
    k_band_re<<<512, 256, 0, stream>>>(x, b_dec, b_enc, W_enc, scal, bandi, bandv);
    k_band_sel<<<1, 256, 0, stream>>>(scal, bandi, bandv, sel_idx, sel_bits);
    k_decode<<<NB, 256, 0, stream>>>(acts, x, b_dec, W_dec, recon, scal, sel_idx, acc);
    if (use_aux_gemm) {
        k_aux_pack<<<NB, 256, 0, stream>>>(acts, dead, scal, axb);
        k_prep_wd<<<dim3(NS / 32, ND / 32), 256, 0, stream>>>(W_dec, WdT);
        k_aux_mfma<<<dim3(ND / 128, NB / 128, KSPLIT), 256, 0, stream>>>(axb, WdT, raux);
        k_aux_diff<<<512, 256, 0, stream>>>(raux, x, recon, acc);
    } else {
        k_aux<<<NB, 256, 0, stream>>>(acts, dead, x, recon, W_dec, scal, acc);
    }
    k_topk_write<<<4096, 256, 0, stream>>>(out, scal, acc, scal);
    k_selwrite<<<1, 256, 0, stream>>>(acts, sel_idx, sel_bits, scal, acc);
    k_final<<<1, 64, 0, stream>>>(out, scal, acc);
}

// Round 6
// 1901.242 us; speedup vs baseline: 1.1073x; 1.0887x over previous
//
#include <hip/hip_runtime.h>

// ---------------- problem constants ----------------
#define NB 2048
#define ND 1024
#define NS 30720
#define K_MAIN 131072LL           // TOP_K * B
#define K_AUX  2097152LL          // TOP_K * AUX_K_MULT * B
#define BAND_CAP 16384
#define SEL_CAP  8192
#define CANDA_CAP 65536
#define EPS_BAND 1e-3f            // covers worst-case |approx - fp64| per element with big margin
#define KSPLIT 4

// ---------------- ws layout (bytes) ----------------
#define OFF_SCAL 0                // int[64]
#define OFF_ACC  256              // double[8]
#define OFF_H1M  512              // int[4096]
#define OFF_H1A  16896
#define OFF_H2M  33280
#define OFF_H2A  49664
#define OFF_ZERO_END 66048        // zeroed every launch
#define OFF_DEAD 66048            // 30720 bytes
#define OFF_SEL_IDX 98304         // int[SEL_CAP]
#define OFF_SEL_BITS 131072       // uint[SEL_CAP]
#define OFF_BANDI 163840          // int[BAND_CAP]
#define OFF_BANDV 229376          // double[BAND_CAP]
#define OFF_CAB  360448           // uint[CANDA_CAP]  (ends 622592)
// aux GEMM per-split output planes: fp32 [KSPLIT][NB][ND] = 32 MB
#define OFF_RAUX 1048576ULL
// split-bf16 planes for the encoder MFMA GEMM
#define OFF_AH   (OFF_RAUX + (unsigned long long)KSPLIT * NB * ND * 4)   // 34603008
#define OFF_AL   (OFF_AH + 2048ULL*1024*2)
#define OFF_WHT  (OFF_AL + 2048ULL*1024*2)          // [30720][1024] bf16 = 60 MB (transposed)
#define OFF_WLT  (OFF_WHT + 30720ULL*1024*2)
#define WS_NEED_ENC (OFF_WLT + 30720ULL*1024*2)     // ~161 MB
// aux planes reuse the encoder-plane region (encoder GEMM is complete before aux pack)
#define OFF_AXB  OFF_AH                              // bf16 [NB][NS] = 126 MB
#define OFF_WDT  (OFF_AXB + 2048ULL*30720*2)         // bf16 [ND][NS] = 63 MB
#define WS_NEED_AUX (OFF_WDT + 1024ULL*30720*2)      // ~213 MB

// scal indices
#define S_NDEAD 0
#define S_B1M 1
#define S_REM1M 2
#define S_B1A 3
#define S_REM1A 4
#define S_T24M 5
#define S_BLO 6
#define S_BHI 7
#define S_T24A 8
#define S_JA 9
#define S_NHI 10
#define S_BANDC 11
#define S_CCA 12
#define S_SELCNT 13
#define S_L0 14
#define S_MINBITS 15

// acc indices
#define A_L2_0 0
#define A_L1 4
#define A_AUX 5

typedef __attribute__((ext_vector_type(8))) short bf16x8;
typedef __attribute__((ext_vector_type(4))) float f32x4;

// ---------------- helpers ----------------
__device__ __forceinline__ float blk_reduce(float v, float* sred) {
    int t = threadIdx.x;
    #pragma unroll
    for (int o = 32; o > 0; o >>= 1) v += __shfl_down(v, o, 64);
    __syncthreads();
    if ((t & 63) == 0) sred[t >> 6] = v;
    __syncthreads();
    return sred[0] + sred[1] + sred[2] + sred[3];
}

__device__ __forceinline__ unsigned short f2bf(float f) {
    unsigned u = __float_as_uint(f);
    unsigned r = (u + 0x7FFFu + ((u >> 16) & 1u)) >> 16;   // RNE
    return (unsigned short)r;
}
__device__ __forceinline__ float bf2f(unsigned short h) {
    return __uint_as_float(((unsigned)h) << 16);
}

#define GLD16(gp, lp) __builtin_amdgcn_global_load_lds( \
    (const __attribute__((address_space(1))) unsigned int*)(gp), \
    (__attribute__((address_space(3))) unsigned int*)(lp), 16, 0, 0)

// ---------------- kernels ----------------
__global__ void k_init(int* w) {
    int n = OFF_ZERO_END / 4;
    for (int i = blockIdx.x * blockDim.x + threadIdx.x; i < n; i += gridDim.x * blockDim.x)
        w[i] = 0;
}

__global__ void k_dead(const int* __restrict__ nbna, unsigned char* __restrict__ dead, int* scal) {
    int stride = gridDim.x * blockDim.x;
    int cnt = 0;
    for (int i = blockIdx.x * blockDim.x + threadIdx.x; i < NS; i += stride) {
        bool d = nbna[i] >= 20;
        dead[i] = d ? 1 : 0;
        cnt += d ? 1 : 0;
    }
    #pragma unroll
    for (int o = 32; o > 0; o >>= 1) cnt += __shfl_down(cnt, o, 64);
    if ((threadIdx.x & 63) == 0 && cnt) atomicAdd(&scal[S_NDEAD], cnt);
}

// split (x - b_dec) into bf16 hi/lo planes, [M][K]
__global__ void k_prep_a(const float* __restrict__ x, const float* __restrict__ b_dec,
                         unsigned short* __restrict__ Ahg, unsigned short* __restrict__ Alg) {
    int stride = gridDim.x * blockDim.x;
    for (int i = blockIdx.x * blockDim.x + threadIdx.x; i < NB * ND; i += stride) {
        float v = x[i] - b_dec[i & (ND - 1)];
        unsigned short h = f2bf(v);
        unsigned short l = f2bf(v - bf2f(h));
        Ahg[i] = h; Alg[i] = l;
    }
}

// transpose + split W_enc [K][N] fp32 -> WhT/WlT [N][K] bf16 (32x32 tiles via LDS)
__global__ __launch_bounds__(256) void k_prep_w(const float* __restrict__ W,
        unsigned short* __restrict__ WhT, unsigned short* __restrict__ WlT) {
    __shared__ float tile[32][33];
    int n0 = blockIdx.x * 32, k0 = blockIdx.y * 32;
    int t = threadIdx.x;
    int c = t & 31, r = t >> 5;          // r in 0..7
    #pragma unroll
    for (int it = 0; it < 4; it++)
        tile[r + it * 8][c] = W[(size_t)(k0 + r + it * 8) * NS + n0 + c];
    __syncthreads();
    int kl = t & 31, nl = t >> 5;
    #pragma unroll
    for (int it = 0; it < 4; it++) {
        float v = tile[kl][nl + it * 8];
        unsigned short h = f2bf(v);
        unsigned short l = f2bf(v - bf2f(h));
        size_t o = (size_t)(n0 + nl + it * 8) * ND + k0 + kl;
        WhT[o] = h; WlT[o] = l;
    }
}

// ============================================================================
// split-bf16 MFMA encoder GEMM: acts = relu(A@W + b_enc), A=Ah+Al, W=Wh+Wl.
// EXACT R2 schedule (best measured: 349 us, passing): 256x256 tile, grid 960,
// BK=32, 8 waves 2Mx4N, double-buffered 128 KiB LDS, counted vmcnt(8)
// pipeline (AhBh(kt+1) issued at phase-0 top, BlAl(kt+1) at phase-1 top;
// vmcnt precedes s_barrier -> cross-wave LDS visibility OK).
// NEW: hist1 FUSED into the epilogue — each block histograms its tile from
// REGISTERS into LDS (buf0 region, provably idle after the tail barrier),
// then flushes nonzero bins with global atomics. Kills the separate 252 MB
// hist1 pass. Counts are bit-identical to k_hist1 (bin = bits>>20, zeros via
// counter into bin 0; dead-col subhistogram alongside).
// 16B-chunk XOR swizzle -> 0 bank conflicts (verified R1).
// Per-acc FLOP order unchanged -> acts bit-identical to R1/R2/R4/R5.
// ============================================================================
#define ENC_STAGE(bufoff, p, gptr, r, ktn) GLD16((gptr) + (size_t)(r) * 128 * ND + (size_t)(ktn) * 32, \
    smem + (bufoff) + (p) * 8192 + (r) * 4096 + ldsw)

#define ENC_RD_AH(boff) { _Pragma("unroll") \
    for (int i = 0; i < 8; i++) ah[i] = *(const bf16x8*)&smem[(boff) + (arb + i * 16) * 32 + cph8]; }
#define ENC_RD_AL(boff) { _Pragma("unroll") \
    for (int i = 0; i < 8; i++) al[i] = *(const bf16x8*)&smem[(boff) + 8192 + (arb + i * 16) * 32 + cph8]; }
#define ENC_RD_BH(boff) { _Pragma("unroll") \
    for (int j = 0; j < 4; j++) bh[j] = *(const bf16x8*)&smem[(boff) + 2 * 8192 + (brb + j * 16) * 32 + cph8]; }
#define ENC_RD_BL(boff) { _Pragma("unroll") \
    for (int j = 0; j < 4; j++) bl[j] = *(const bf16x8*)&smem[(boff) + 3 * 8192 + (brb + j * 16) * 32 + cph8]; }

#define ENC_MFMA(AF, BF) { \
    asm volatile("s_waitcnt lgkmcnt(0)" ::: "memory"); \
    __builtin_amdgcn_sched_barrier(0); \
    __builtin_amdgcn_s_setprio(1); \
    _Pragma("unroll") for (int i = 0; i < 8; i++) \
        _Pragma("unroll") for (int j = 0; j < 4; j++) \
            acc[i][j] = __builtin_amdgcn_mfma_f32_16x16x32_bf16(AF[i], BF[j], acc[i][j], 0, 0, 0); \
    __builtin_amdgcn_s_setprio(0); }

__global__ __launch_bounds__(512, 2) void k_enc_mfma(
        const unsigned short* __restrict__ Ahg, const unsigned short* __restrict__ Alg,
        const unsigned short* __restrict__ WhT, const unsigned short* __restrict__ WlT,
        const float* __restrict__ b_enc, const unsigned char* __restrict__ dead,
        float* __restrict__ acts, int* __restrict__ h1m, int* __restrict__ h1a) {
    // 2 bufs x 4 planes (Ah,Al,Bh,Bl) x [256][32] bf16 = 128 KiB
    __shared__ unsigned short smem[65536];
    const int t = threadIdx.x;
    const int lane = t & 63, w = t >> 6;
    const int wm = w >> 2, wn = w & 3;                 // 2x4 wave grid; wave out = 128x64
    // bijective XCD-chunked swizzle: 960 = 8 x 120; XCD x gets n-tiles [x*15, x*15+15)
    const int flat = blockIdx.x;
    const int wg = (flat & 7) * 120 + (flat >> 3);
    const int n0 = (wg >> 3) * 256;
    const int m0 = (wg & 7) * 256;
    const int ln15 = lane & 15, q = lane >> 4;
    // physical chunk offset (shorts) for fragment reads: (q ^ ((row>>1)&3)) * 8
    const int cph8 = ((q ^ ((lane >> 1) & 3)) << 3);

    // staging: wave w covers rows [r*128 + w*16, +16); lane l -> row +(l>>2), phys chunk l&3
    const int srow = w * 16 + (lane >> 2);
    const int sq8 = (((lane & 3) ^ ((lane >> 3) & 3)) << 3);   // logical chunk for this phys slot
    const unsigned short* gA  = Ahg + (size_t)(m0 + srow) * ND + sq8;
    const unsigned short* gAl = Alg + (size_t)(m0 + srow) * ND + sq8;
    const unsigned short* gB  = WhT + (size_t)(n0 + srow) * ND + sq8;
    const unsigned short* gBl = WlT + (size_t)(n0 + srow) * ND + sq8;
    const int ldsw = w * 512;                                  // wave slot in half-plane (shorts)

    f32x4 acc[8][4];
    #pragma unroll
    for (int i = 0; i < 8; i++)
        #pragma unroll
        for (int j = 0; j < 4; j++) acc[i][j] = (f32x4){0.f, 0.f, 0.f, 0.f};

    const int arb = wm * 128 + ln15;       // A frag row base (+ i*16)
    const int brb = wn * 64 + ln15;        // B frag row base (+ j*16)

    // prologue: issue AhBh(0) then BlAl(0) into buf 0 (issue ORDER = wait order)
    ENC_STAGE(0, 0, gA, 0, 0);  ENC_STAGE(0, 0, gA, 1, 0);
    ENC_STAGE(0, 2, gB, 0, 0);  ENC_STAGE(0, 2, gB, 1, 0);
    ENC_STAGE(0, 3, gBl, 0, 0); ENC_STAGE(0, 3, gBl, 1, 0);
    ENC_STAGE(0, 1, gAl, 0, 0); ENC_STAGE(0, 1, gAl, 1, 0);

    for (int kt = 0; kt < 31; ++kt) {
        const int cboff = (kt & 1) * 32768;
        const int nboff = cboff ^ 32768;
        const int kn = kt + 1;
        bf16x8 ah[8], bh[4], bl[4], al[8];

        // ---- phase 0: issue AhBh(kt+1); wait AhBh(kt); MFMA Ah*Bh ----
        ENC_STAGE(nboff, 0, gA, 0, kn);  ENC_STAGE(nboff, 0, gA, 1, kn);
        ENC_STAGE(nboff, 2, gB, 0, kn);  ENC_STAGE(nboff, 2, gB, 1, kn);
        asm volatile("s_waitcnt vmcnt(8)" ::: "memory");   // oldest 4 = AhBh(kt)
        __builtin_amdgcn_s_barrier();
        ENC_RD_AH(cboff) ENC_RD_BH(cboff)
        ENC_MFMA(ah, bh)

        // ---- phase 1: issue BlAl(kt+1); wait BlAl(kt); MFMA Ah*Bl ----
        ENC_STAGE(nboff, 3, gBl, 0, kn); ENC_STAGE(nboff, 3, gBl, 1, kn);
        ENC_STAGE(nboff, 1, gAl, 0, kn); ENC_STAGE(nboff, 1, gAl, 1, kn);
        asm volatile("s_waitcnt vmcnt(8)" ::: "memory");   // oldest 4 = BlAl(kt)
        __builtin_amdgcn_s_barrier();
        ENC_RD_BL(cboff)
        ENC_MFMA(ah, bl)

        // ---- phase 2: MFMA Al*Bh (Al visibility established at P1 barrier) ----
        ENC_RD_AL(cboff)
        ENC_MFMA(al, bh)
    }

    // ---- peeled tail kt=31 (no prefetch; counted waits drain naturally) ----
    {
        const int cboff = 32768;
        bf16x8 ah[8], bh[4], bl[4], al[8];
        asm volatile("s_waitcnt vmcnt(4)" ::: "memory");   // AhBh(31) landed
        __builtin_amdgcn_s_barrier();
        ENC_RD_AH(cboff) ENC_RD_BH(cboff)
        ENC_MFMA(ah, bh)
        asm volatile("s_waitcnt vmcnt(0)" ::: "memory");   // BlAl(31) landed
        __builtin_amdgcn_s_barrier();
        ENC_RD_BL(cboff)
        ENC_MFMA(ah, bl)
        ENC_RD_AL(cboff)
        ENC_MFMA(al, bh)
    }

    // ---- fused hist1 epilogue: histogram tile from registers ----
    // buf0 (shorts 0..16383) is idle: last buf0 reads (tile 30) completed
    // before each wave's lgkmcnt(0); all waves passed the tail barrier since.
    __syncthreads();
    int* hm = (int*)smem;            // 4096 ints (bytes 0..16383)
    int* ha = hm + 4096;             // 4096 ints (bytes 16384..32767)
    for (int i2 = t; i2 < 8192; i2 += 512) hm[i2] = 0;
    __syncthreads();

    int zc = 0, zca = 0;
    #pragma unroll
    for (int j = 0; j < 4; j++) {
        int n = n0 + wn * 64 + j * 16 + ln15;
        float be = b_enc[n];
        bool dd = dead[n] != 0;
        #pragma unroll
        for (int i = 0; i < 8; i++) {
            int mrow = m0 + wm * 128 + i * 16 + q * 4;
            #pragma unroll
            for (int rg = 0; rg < 4; rg++) {
                float v = fmaxf(acc[i][j][rg] + be, 0.f);
                acts[(size_t)(mrow + rg) * NS + n] = v;
                unsigned bits = __float_as_uint(v);
                if (bits == 0u) { zc++; zca += dd ? 1 : 0; }
                else {
                    atomicAdd(&hm[bits >> 20], 1);
                    if (dd) atomicAdd(&ha[bits >> 20], 1);
                }
            }
        }
    }
    #pragma unroll
    for (int o = 32; o > 0; o >>= 1) { zc += __shfl_down(zc, o, 64); zca += __shfl_down(zca, o, 64); }
    if ((t & 63) == 0) { if (zc) atomicAdd(&hm[0], zc); if (zca) atomicAdd(&ha[0], zca); }
    __syncthreads();
    for (int i2 = t; i2 < 4096; i2 += 512) {
        if (hm[i2]) atomicAdd(&h1m[i2], hm[i2]);
        if (ha[i2]) atomicAdd(&h1a[i2], ha[i2]);
    }
}

// fallback fp32 encoder GEMM (used when ws too small for bf16 planes)
#define GBM 128
#define GBN 128
#define GBK 8
__global__ __launch_bounds__(256) void k_enc_gemm(const float* __restrict__ x,
        const float* __restrict__ b_dec, const float* __restrict__ b_enc,
        const float* __restrict__ W, float* __restrict__ acts) {
    __shared__ float As[GBK][GBM];
    __shared__ float Bs[GBK][GBN];
    const int t = threadIdx.x;
    const int tx = t & 15, ty = t >> 4;
    const int m0 = blockIdx.y * GBM, n0 = blockIdx.x * GBN;
    const int am = t >> 1, ak = (t & 1) * 4;
    const int bk = t >> 5, bnq = (t & 31) * 4;
    float acc[8][8];
    #pragma unroll
    for (int i = 0; i < 8; i++)
        #pragma unroll
        for (int j = 0; j < 8; j++) acc[i][j] = 0.f;
    for (int k0 = 0; k0 < ND; k0 += GBK) {
        float4 av = *(const float4*)(x + (size_t)(m0 + am) * ND + k0 + ak);
        float4 bd = *(const float4*)(b_dec + k0 + ak);
        As[ak + 0][am] = av.x - bd.x;
        As[ak + 1][am] = av.y - bd.y;
        As[ak + 2][am] = av.z - bd.z;
        As[ak + 3][am] = av.w - bd.w;
        *(float4*)&Bs[bk][bnq] = *(const float4*)(W + (size_t)(k0 + bk) * NS + n0 + bnq);
        __syncthreads();
        #pragma unroll
        for (int kk = 0; kk < GBK; kk++) {
            float a[8], b[8];
            *(float4*)&a[0] = *(const float4*)&As[kk][ty * 4];
            *(float4*)&a[4] = *(const float4*)&As[kk][64 + ty * 4];
            *(float4*)&b[0] = *(const float4*)&Bs[kk][tx * 4];
            *(float4*)&b[4] = *(const float4*)&Bs[kk][64 + tx * 4];
            #pragma unroll
            for (int i = 0; i < 8; i++)
                #pragma unroll
                for (int j = 0; j < 8; j++)
                    acc[i][j] = fmaf(a[i], b[j], acc[i][j]);
        }
        __syncthreads();
    }
    float be[8];
    #pragma unroll
    for (int j = 0; j < 4; j++) {
        be[j]     = b_enc[n0 + tx * 4 + j];
        be[4 + j] = b_enc[n0 + 64 + tx * 4 + j];
    }
    #pragma unroll
    for (int i = 0; i < 8; i++) {
        int row = m0 + ((i < 4) ? (ty * 4 + i) : (64 + ty * 4 + i - 4));
        float* orow = acts + (size_t)row * NS + n0;
        #pragma unroll
        for (int j = 0; j < 4; j++) {
            orow[tx * 4 + j]      = fmaxf(acc[i][j] + be[j], 0.f);
            orow[64 + tx * 4 + j] = fmaxf(acc[i][4 + j] + be[4 + j], 0.f);
        }
    }
}

// standalone coarse histogram (fallback path only; fused into enc otherwise)
__global__ __launch_bounds__(256) void k_hist1(const float* __restrict__ acts,
        const unsigned char* __restrict__ dead, int* h1m, int* h1a) {
    __shared__ int hm[4096], ha[4096];
    int t = threadIdx.x;
    for (int i = t; i < 4096; i += 256) { hm[i] = 0; ha[i] = 0; }
    __syncthreads();
    for (int row = blockIdx.x; row < NB; row += gridDim.x) {
        const float* pr = acts + (size_t)row * NS;
        for (int c = t; c < NS; c += 256) {
            unsigned bits = __float_as_uint(pr[c]);
            bool isz = (bits == 0u);
            bool dd = dead[c] != 0;
            unsigned long long mz = __ballot(isz);
            unsigned long long mza = __ballot(isz && dd);
            if ((t & 63) == 0) {
                int nz = __popcll(mz);
                if (nz) atomicAdd(&hm[0], nz);
                int nza = __popcll(mza);
                if (nza) atomicAdd(&ha[0], nza);
            }
            if (!isz) {
                atomicAdd(&hm[bits >> 20], 1);
                if (dd) atomicAdd(&ha[bits >> 20], 1);
            }
        }
    }
    __syncthreads();
    for (int i = t; i < 4096; i += 256) {
        if (hm[i]) atomicAdd(&h1m[i], hm[i]);
        if (ha[i]) atomicAdd(&h1a[i], ha[i]);
    }
}

// suffix-scan over a 4096-bin histogram; finds bin containing rank k (from top)
__global__ void k_scan(const int* __restrict__ hist, int* scal, int mode) {
    __shared__ long long csum[256];
    __shared__ long long totsh;
    int t = threadIdx.x;
    int base = t * 16;
    int h[16];
    long long loc = 0;
    #pragma unroll
    for (int i = 0; i < 16; i++) { h[i] = hist[base + i]; loc += h[i]; }
    csum[t] = loc;
    __syncthreads();
    if (t == 0) {
        long long run = 0;
        for (int c = 255; c >= 0; c--) { long long tmp = csum[c]; csum[c] = run; run += tmp; }
        totsh = run;
    }
    __syncthreads();
    long long k;
    if (mode == 0) k = K_MAIN;
    else if (mode == 1) k = K_AUX;
    else if (mode == 2) k = (long long)scal[S_REM1M];
    else {
        if (scal[S_B1A] < 0) { if (t == 0) { scal[S_T24A] = -1; scal[S_MINBITS] = 0; } return; }
        k = (long long)scal[S_REM1A];
    }
    if (mode == 1 && k > totsh) { if (t == 0) scal[S_B1A] = -1; return; }
    long long cum = csum[t];
    int fb = -1; long long rem = 0;
    for (int i = 15; i >= 0; i--) {
        long long ca = cum;
        cum += h[i];
        if (ca < k && k <= cum) { fb = base + i; rem = k - ca; }
    }
    if (fb >= 0) {
        if (mode == 0)      { scal[S_B1M] = fb; scal[S_REM1M] = (int)rem; }
        else if (mode == 1) { scal[S_B1A] = fb; scal[S_REM1A] = (int)rem; }
        else if (mode == 2) {
            int t24 = (scal[S_B1M] << 12) | fb;
            scal[S_T24M] = t24;
            float center = __uint_as_float((((unsigned)t24) << 8) | 128u);
            float lo = center - EPS_BAND;
            if (lo < 0.f) lo = 0.f;
            scal[S_BLO] = (int)__float_as_uint(lo);
            scal[S_BHI] = (int)__float_as_uint(center + EPS_BAND);
        }
        else { scal[S_T24A] = (scal[S_B1A] << 12) | fb; scal[S_JA] = (int)rem; }
    }
}

// fine histograms inside the selected coarse bins
__global__ __launch_bounds__(256) void k_hist2(const float* __restrict__ acts,
        const unsigned char* __restrict__ dead, const int* scal, int* h2m, int* h2a) {
    int b1m = scal[S_B1M], b1a = scal[S_B1A];
    int row = blockIdx.x, t = threadIdx.x;
    const float* pr = acts + (size_t)row * NS;
    for (int c = t; c < NS; c += 256) {
        unsigned bits = __float_as_uint(pr[c]);
        int hi = (int)(bits >> 20);
        if (hi == b1m) atomicAdd(&h2m[(bits >> 8) & 0xFFF], 1);
        if (b1a >= 0 && hi == b1a && dead[c]) atomicAdd(&h2a[(bits >> 8) & 0xFFF], 1);
    }
}

// single pass: exact count above band (n_hi), band-member collection, aux candidates
__global__ __launch_bounds__(256) void k_collect(const float* __restrict__ acts,
        const unsigned char* __restrict__ dead, int* scal,
        int* bandi, unsigned* cab) {
    int row = blockIdx.x, t = threadIdx.x;
    unsigned blo = (unsigned)scal[S_BLO], bhi = (unsigned)scal[S_BHI];
    int t24a = scal[S_T24A];
    const float* pr = acts + (size_t)row * NS;
    int cnt = 0;
    for (int c = t; c < NS; c += 256) {
        unsigned bits = __float_as_uint(pr[c]);
        if (bits > bhi) cnt++;
        else if (bits >= blo) {
            int p = atomicAdd(&scal[S_BANDC], 1);
            if (p < BAND_CAP) bandi[p] = row * NS + c;
        }
        if (t24a >= 0 && (bits >> 8) == (unsigned)t24a && dead[c]) {
            int p = atomicAdd(&scal[S_CCA], 1);
            if (p < CANDA_CAP) cab[p] = bits;
        }
    }
    #pragma unroll
    for (int o = 32; o > 0; o >>= 1) cnt += __shfl_down(cnt, o, 64);
    __shared__ int s2[4];
    if ((t & 63) == 0) s2[t >> 6] = cnt;
    __syncthreads();
    if (t == 0) {
        int tot = s2[0] + s2[1] + s2[2] + s2[3];
        if (tot) atomicAdd(&scal[S_NHI], tot);
    }
}

// aux threshold value from boundary-fine-bin candidates
__global__ __launch_bounds__(256) void k_resolve(const unsigned* __restrict__ cab, int* scal) {
    __shared__ int h[256];
    int t = threadIdx.x;
    h[t] = 0;
    __syncthreads();
    int t24a = scal[S_T24A];
    if (t24a < 0) { if (t == 0) scal[S_MINBITS] = 0; return; }
    int cnt = min(scal[S_CCA], CANDA_CAP);
    int ja = scal[S_JA];
    for (int e = t; e < cnt; e += 256) atomicAdd(&h[cab[e] & 0xFF], 1);
    __syncthreads();
    if (t == 0) {
        long long cum = 0; int L = 0;
        for (int b = 255; b >= 0; b--) {
            long long ca = cum; cum += h[b];
            if (ca < ja && ja <= cum) { L = b; break; }
        }
        scal[S_MINBITS] = (int)((((unsigned)t24a) << 8) | (unsigned)L);
    }
}

// fp64 recompute of band elements (exact vs reference)
__global__ __launch_bounds__(256) void k_band_re(const float* __restrict__ x,
        const float* __restrict__ b_dec, const float* __restrict__ b_enc,
        const float* __restrict__ W, const int* scal,
        const int* __restrict__ bandi, double* __restrict__ bandv) {
    int n = min(scal[S_BANDC], BAND_CAP);
    int t = threadIdx.x;
    __shared__ double sd[4];
    for (int e = blockIdx.x; e < n; e += gridDim.x) {
        int idx = bandi[e];
        int r = idx / NS, c = idx - r * NS;
        double s = 0.0;
        #pragma unroll
        for (int j = 0; j < 4; j++) {
            int d = t + j * 256;
            s += ((double)x[(size_t)r * ND + d] - (double)b_dec[d]) * (double)W[(size_t)d * NS + c];
        }
        #pragma unroll
        for (int o = 32; o > 0; o >>= 1) s += __shfl_down(s, o, 64);
        if ((t & 63) == 0) sd[t >> 6] = s;
        __syncthreads();
        if (t == 0) {
            double v = sd[0] + sd[1] + sd[2] + sd[3] + (double)b_enc[c];
            bandv[e] = fmax(v, 0.0);
        }
        __syncthreads();
    }
}

// exact selection within band: rank by (v64 desc, idx asc); keep rank < need = K - n_hi
__global__ __launch_bounds__(256) void k_band_sel(int* scal,
        const int* __restrict__ bandi, const double* __restrict__ bandv,
        int* sel_idx, unsigned* sel_bits) {
    int n = min(scal[S_BANDC], BAND_CAP);
    int need = (int)(K_MAIN - (long long)scal[S_NHI]);
    if (need < 0) need = 0;
    if (need > n) need = n;
    int t = threadIdx.x;
    for (int e = t; e < n; e += 256) {
        double v = bandv[e];
        int idx = bandi[e];
        int rank = 0;
        for (int j = 0; j < n; j++) {
            double vj = bandv[j];
            rank += (vj > v || (vj == v && bandi[j] < idx)) ? 1 : 0;
        }
        if (rank < need) {
            int p = atomicAdd(&scal[S_SELCNT], 1);
            if (p < SEL_CAP) { sel_idx[p] = idx; sel_bits[p] = __float_as_uint((float)v); }
        }
    }
}

// hierarchical sparse decode; when fuse==1 additionally:
//  - writes masked acts in-place (v if bits>bhi else 0; band restored by selwrite)
//  - writes bf16 aux plane axb = relu(v - minval) * dead   (was k_aux_pack)
//  - accumulates L1/L0 of strict members                    (was k_topk_write)
// Row-private per block; each element read before written. Raw acts consumers
// (hist2/collect) run BEFORE this kernel.
__global__ __launch_bounds__(256) void k_decode(float* __restrict__ acts,
        const float* __restrict__ x, const float* __restrict__ b_dec, const float* __restrict__ Wd,
        float* __restrict__ recon, const unsigned char* __restrict__ dead,
        const int* __restrict__ sel_idx, unsigned short* __restrict__ axb,
        int* scal, double* acc, int fuse) {
    int row = blockIdx.x, t = threadIdx.x;
    unsigned blo = (unsigned)scal[S_BLO], bhi = (unsigned)scal[S_BHI];
    float minval = __uint_as_float((unsigned)scal[S_MINBITS]);
    int selcnt = min(scal[S_SELCNT], SEL_CAP);
    __shared__ int lj[2048];
    __shared__ float lv[2048];
    __shared__ int lcnt;
    __shared__ float sred[4];
    const int d0 = t * 4;
    float4 r;
    r.x = b_dec[d0]; r.y = b_dec[d0 + 1]; r.z = b_dec[d0 + 2]; r.w = b_dec[d0 + 3];
    float4 xv = *(const float4*)(x + (size_t)row * ND + d0);
    float* arow = acts + (size_t)row * NS;
    unsigned short* xrow = axb + (size_t)row * NS;
    float l1 = 0.f; int kcnt = 0;
    const int bnds[5] = {0, 2048, 6144, 14336, NS};
    for (int g = 0; g < 4; g++) {
        for (int c0 = bnds[g]; c0 < bnds[g + 1]; c0 += 2048) {
            __syncthreads();
            if (t == 0) lcnt = 0;
            __syncthreads();
            #pragma unroll
            for (int u = 0; u < 8; u++) {
                int c = c0 + u * 256 + t;
                float v = arow[c];
                unsigned bits = __float_as_uint(v);
                bool strict = bits > bhi;
                bool keep = strict;
                if (!keep && bits >= blo) {
                    int flat = row * NS + c;
                    for (int e = 0; e < selcnt; e++)
                        if (sel_idx[e] == flat) { keep = true; break; }
                }
                if (keep) { int p = atomicAdd(&lcnt, 1); lj[p] = c; lv[p] = v; }
                if (fuse) {
                    if (strict) { l1 += v; kcnt++; }
                    arow[c] = strict ? v : 0.f;
                    float o = (dead[c] && v > minval) ? (v - minval) : 0.f;
                    xrow[c] = f2bf(o);
                }
            }
            __syncthreads();
            int n = lcnt;
            for (int e = 0; e < n; e++) {
                float a_ = lv[e];
                float4 w = *(const float4*)(Wd + (size_t)lj[e] * ND + d0);
                r.x = fmaf(a_, w.x, r.x);
                r.y = fmaf(a_, w.y, r.y);
                r.z = fmaf(a_, w.z, r.z);
                r.w = fmaf(a_, w.w, r.w);
            }
        }
        float dx = r.x - xv.x, dy = r.y - xv.y, dz = r.z - xv.z, dw = r.w - xv.w;
        float ss = dx * dx + dy * dy + dz * dz + dw * dw;
        float tot = blk_reduce(ss, sred);
        if (t == 0) atomicAdd(&acc[A_L2_0 + g], (double)tot);
    }
    float* orow = recon + (size_t)row * ND + d0;   // region misaligned -> scalar stores
    orow[0] = r.x; orow[1] = r.y; orow[2] = r.z; orow[3] = r.w;
    if (fuse) {
        #pragma unroll
        for (int o = 32; o > 0; o >>= 1) { l1 += __shfl_down(l1, o, 64); kcnt += __shfl_down(kcnt, o, 64); }
        __shared__ float s1[4];
        __shared__ int s2[4];
        if ((t & 63) == 0) { s1[t >> 6] = l1; s2[t >> 6] = kcnt; }
        __syncthreads();
        if (t == 0) {
            atomicAdd(&acc[A_L1], (double)(s1[0] + s1[1] + s1[2] + s1[3]));
            atomicAdd(&scal[S_L0], s2[0] + s2[1] + s2[2] + s2[3]);
        }
    }
}

// ---- aux via dense masked GEMM ----
// pack acts_aux = relu(acts - minval) * dead into bf16 plane [NB][NS]
// (fallback path only; fused into k_decode otherwise)
__global__ __launch_bounds__(256) void k_aux_pack(const float* __restrict__ acts,
        const unsigned char* __restrict__ dead, const int* scal,
        unsigned short* __restrict__ axb) {
    int row = blockIdx.x, t = threadIdx.x;
    float minval = __uint_as_float((unsigned)scal[S_MINBITS]);
    const float* arow = acts + (size_t)row * NS;
    unsigned short* orow = axb + (size_t)row * NS;
    for (int c = t; c < NS; c += 256) {
        float v = arow[c];
        float o = (dead[c] && v > minval) ? (v - minval) : 0.f;
        orow[c] = f2bf(o);
    }
}

// transpose W_dec [S][D] fp32 -> WdT [D][S] bf16
__global__ __launch_bounds__(256) void k_prep_wd(const float* __restrict__ Wd,
        unsigned short* __restrict__ WdT) {
    __shared__ float tile[32][33];
    int s0 = blockIdx.x * 32, d0 = blockIdx.y * 32;
    int t = threadIdx.x;
    int c = t & 31, r = t >> 5;
    #pragma unroll
    for (int it = 0; it < 4; it++)
        tile[r + it * 8][c] = Wd[(size_t)(s0 + r + it * 8) * ND + d0 + c];
    __syncthreads();
    int sl = t & 31, dl = t >> 5;
    #pragma unroll
    for (int it = 0; it < 4; it++)
        WdT[(size_t)(d0 + dl + it * 8) * NS + s0 + sl] = f2bf(tile[sl][dl + it * 8]);
}

// bf16 MFMA aux GEMM: raux[z] = acts_aux @ W_dec (K-split over z), per-split fp32 planes
__global__ __launch_bounds__(256) void k_aux_mfma(
        const unsigned short* __restrict__ axb, const unsigned short* __restrict__ WdT,
        float* __restrict__ raux) {
    __shared__ unsigned short As[128 * 32], Bs[128 * 32];
    const int t = threadIdx.x;
    const int lane = t & 63, w = t >> 6;
    const int wm = w >> 1, wn = w & 1;
    const int m0 = blockIdx.y * 128, n0 = blockIdx.x * 128;
    const int kbase = blockIdx.z * (NS / KSPLIT);
    const int ln15 = lane & 15, q = lane >> 4;

    f32x4 acc[4][4];
    #pragma unroll
    for (int i = 0; i < 4; i++)
        #pragma unroll
        for (int j = 0; j < 4; j++) acc[i][j] = (f32x4){0.f, 0.f, 0.f, 0.f};

    // waves 0,1 stage A halves; waves 2,3 stage B halves (64 rows x 32 cols each)
    const unsigned short* gbase;
    unsigned short* lbase;
    if (w < 2) { gbase = axb + (size_t)(m0 + w * 64) * NS; lbase = As + w * 64 * 32; }
    else       { gbase = WdT + (size_t)(n0 + (w - 2) * 64) * NS; lbase = Bs + (w - 2) * 64 * 32; }
    const unsigned short* glane = gbase + (size_t)(lane >> 2) * NS + (lane & 3) * 8 + kbase;

    for (int k0 = 0; k0 < NS / KSPLIT; k0 += 32) {
        __syncthreads();
        #pragma unroll
        for (int ch = 0; ch < 4; ch++)
            GLD16(glane + (size_t)ch * 16 * NS + k0, lbase + ch * 512);
        __syncthreads();

        bf16x8 af[4];
        #pragma unroll
        for (int i = 0; i < 4; i++)
            af[i] = *(const bf16x8*)&As[(wm * 64 + i * 16 + ln15) * 32 + q * 8];
        #pragma unroll
        for (int j = 0; j < 4; j++) {
            bf16x8 bf = *(const bf16x8*)&Bs[(wn * 64 + j * 16 + ln15) * 32 + q * 8];
            #pragma unroll
            for (int i = 0; i < 4; i++)
                acc[i][j] = __builtin_amdgcn_mfma_f32_16x16x32_bf16(af[i], bf, acc[i][j], 0, 0, 0);
        }
    }
    float* rz = raux + (size_t)blockIdx.z * NB * ND;
    #pragma unroll
    for (int j = 0; j < 4; j++) {
        int n = n0 + wn * 64 + j * 16 + ln15;
        #pragma unroll
        for (int i = 0; i < 4; i++) {
            int mrow = m0 + wm * 64 + i * 16 + q * 4;
            #pragma unroll
            for (int rg = 0; rg < 4; rg++)
                rz[(size_t)(mrow + rg) * ND + n] = acc[i][j][rg];
        }
    }
}

// aux loss: sum over B*D of (sum_z raux[z] - (x - recon))^2
__global__ __launch_bounds__(256) void k_aux_diff(const float* __restrict__ raux,
        const float* __restrict__ x, const float* __restrict__ recon, double* acc) {
    __shared__ float sred[4];
    float ss = 0.f;
    int stride = gridDim.x * blockDim.x;
    for (int i = blockIdx.x * blockDim.x + threadIdx.x; i < NB * ND; i += stride) {
        float ra = raux[i];
        #pragma unroll
        for (int z = 1; z < KSPLIT; z++) ra += raux[(size_t)z * NB * ND + i];
        float d = ra - (x[i] - recon[i]);
        ss += d * d;
    }
    float tot = blk_reduce(ss, sred);
    if (threadIdx.x == 0) atomicAdd(&acc[A_AUX], (double)tot);
}

// fallback aux: sparse gather per row
__global__ __launch_bounds__(256) void k_aux(const float* __restrict__ acts,
        const unsigned char* __restrict__ dead, const float* __restrict__ x,
        const float* __restrict__ recon, const float* __restrict__ Wd,
        const int* scal, double* acc) {
    int row = blockIdx.x, t = threadIdx.x;
    float minval = __uint_as_float((unsigned)scal[S_MINBITS]);
    __shared__ int lj[2048];
    __shared__ float lv[2048];
    __shared__ int lcnt;
    __shared__ float sred[4];
    float4 r = {0.f, 0.f, 0.f, 0.f};
    const float* arow = acts + (size_t)row * NS;
    const int d0 = t * 4;
    for (int c0 = 0; c0 < NS; c0 += 2048) {
        __syncthreads();
        if (t == 0) lcnt = 0;
        __syncthreads();
        #pragma unroll
        for (int u = 0; u < 8; u++) {
            int c = c0 + u * 256 + t;
            float v = arow[c];
            if (dead[c] && v > minval) {
                int p = atomicAdd(&lcnt, 1);
                lj[p] = c; lv[p] = v - minval;
            }
        }
        __syncthreads();
        int n = lcnt;
        for (int e = 0; e < n; e++) {
            float a_ = lv[e];
            float4 w = *(const float4*)(Wd + (size_t)lj[e] * ND + d0);
            r.x = fmaf(a_, w.x, r.x);
            r.y = fmaf(a_, w.y, r.y);
            r.z = fmaf(a_, w.z, r.z);
            r.w = fmaf(a_, w.w, r.w);
        }
    }
    const float* xr = x + (size_t)row * ND + d0;
    const float* rr = recon + (size_t)row * ND + d0;
    float dx = r.x - (xr[0] - rr[0]);
    float dy = r.y - (xr[1] - rr[1]);
    float dz = r.z - (xr[2] - rr[2]);
    float dw = r.w - (xr[3] - rr[3]);
    float ss = dx * dx + dy * dy + dz * dz + dw * dw;
    float tot = blk_reduce(ss, sred);
    if (t == 0) atomicAdd(&acc[A_AUX], (double)tot);
}

// in-place top-k zeroing over d_out acts region (fallback path only; fused into k_decode otherwise)
__global__ __launch_bounds__(256) void k_topk_write(float* __restrict__ out, const int* scal, double* acc, int* scalw) {
    unsigned bhi = (unsigned)scal[S_BHI];
    float l1 = 0.f;
    int cnt = 0;
    const long long vstart = 8, nvec = 15728639;   // [8, 62914564) as float4
    long long stride = (long long)gridDim.x * blockDim.x;
    for (long long i = (long long)blockIdx.x * blockDim.x + threadIdx.x; i < nvec; i += stride) {
        float4* p = (float4*)(out + vstart) + i;
        float4 v = *p;
        #define PROC(F) { unsigned b = __float_as_uint(v.F); if (b > bhi) { l1 += v.F; cnt++; } else v.F = 0.f; }
        PROC(x) PROC(y) PROC(z) PROC(w)
        #undef PROC
        *p = v;
    }
    if (blockIdx.x == 0 && threadIdx.x == 0) {
        const long long head[4] = {5, 6, 7, 62914564LL};
        for (int q = 0; q < 4; q++) {
            float v = out[head[q]];
            unsigned b = __float_as_uint(v);
            if (b > bhi) { l1 += v; cnt++; } else out[head[q]] = 0.f;
        }
    }
    int t = threadIdx.x;
    #pragma unroll
    for (int o = 32; o > 0; o >>= 1) { l1 += __shfl_down(l1, o, 64); cnt += __shfl_down(cnt, o, 64); }
    __shared__ float s1[4];
    __shared__ int s2[4];
    if ((t & 63) == 0) { s1[t >> 6] = l1; s2[t >> 6] = cnt; }
    __syncthreads();
    if (t == 0) {
        atomicAdd(&acc[A_L1], (double)(s1[0] + s1[1] + s1[2] + s1[3]));
        atomicAdd(&scalw[S_L0], s2[0] + s2[1] + s2[2] + s2[3]);
    }
}

// rewrite the selected band entries (zeroed by the masking pass) + their L1/L0 contribution
__global__ __launch_bounds__(256) void k_selwrite(float* __restrict__ acts, const int* __restrict__ sel_idx,
        const unsigned* __restrict__ sel_bits, int* scal, double* acc) {
    int t = threadIdx.x;
    int n = min(scal[S_SELCNT], SEL_CAP);
    float l1 = 0.f;
    for (int e = t; e < n; e += 256) {
        float v = __uint_as_float(sel_bits[e]);
        acts[sel_idx[e]] = v;
        l1 += v;
    }
    #pragma unroll
    for (int o = 32; o > 0; o >>= 1) l1 += __shfl_down(l1, o, 64);
    __shared__ float s1[4];
    if ((t & 63) == 0) s1[t >> 6] = l1;
    __syncthreads();
    if (t == 0) {
        atomicAdd(&acc[A_L1], (double)(s1[0] + s1[1] + s1[2] + s1[3]));
        atomicAdd(&scal[S_L0], n);
    }
}

__global__ void k_final(float* out, const int* scal, const double* acc) {
    if (threadIdx.x == 0 && blockIdx.x == 0) {
        double ml2 = (acc[0] + acc[1] + acc[2] + acc[3]) * 0.25 / ((double)NB * ND);
        double l1 = 1e-3 * acc[A_L1] / (double)NB;
        double aux = (scal[S_NDEAD] > 0) ? (1e-2 * acc[A_AUX] / ((double)NB * ND)) : 0.0;
        out[0] = (float)(ml2 + l1 + aux);
        out[1] = (float)ml2;
        out[2] = (float)l1;
        out[3] = (float)aux;
        out[4] = (float)scal[S_L0] / (float)NB;
    }
}

// ---------------- launch ----------------
extern "C" void kernel_launch(void* const* d_in, const int* in_sizes, int n_in,
                              void* d_out, int out_size, void* d_ws, size_t ws_size,
                              hipStream_t stream) {
    const float* x     = (const float*)d_in[0];
    const float* b_dec = (const float*)d_in[1];
    const float* b_enc = (const float*)d_in[2];
    const float* W_enc = (const float*)d_in[3];
    const float* W_dec = (const float*)d_in[4];
    const int*   nbna  = (const int*)d_in[5];

    float* out = (float*)d_out;
    float* acts  = out + 5;                         // [NB, NS] (misaligned region)
    float* recon = out + 5 + (size_t)NB * NS;       // [NB, ND]

    char* ws = (char*)d_ws;
    int*    scal = (int*)(ws + OFF_SCAL);
    double* acc  = (double*)(ws + OFF_ACC);
    int*    h1m  = (int*)(ws + OFF_H1M);
    int*    h1a  = (int*)(ws + OFF_H1A);
    int*    h2m  = (int*)(ws + OFF_H2M);
    int*    h2a  = (int*)(ws + OFF_H2A);
    unsigned char* dead = (unsigned char*)(ws + OFF_DEAD);
    int*      sel_idx  = (int*)(ws + OFF_SEL_IDX);
    unsigned* sel_bits = (unsigned*)(ws + OFF_SEL_BITS);
    int*      bandi = (int*)(ws + OFF_BANDI);
    double*   bandv = (double*)(ws + OFF_BANDV);
    unsigned* cab   = (unsigned*)(ws + OFF_CAB);
    float*    raux  = (float*)(ws + OFF_RAUX);
    unsigned short* Ahg = (unsigned short*)(ws + OFF_AH);
    unsigned short* Alg = (unsigned short*)(ws + OFF_AL);
    unsigned short* WhT = (unsigned short*)(ws + OFF_WHT);
    unsigned short* WlT = (unsigned short*)(ws + OFF_WLT);
    unsigned short* axb = (unsigned short*)(ws + OFF_AXB);
    unsigned short* WdT = (unsigned short*)(ws + OFF_WDT);

    const bool use_mfma     = (ws_size >= WS_NEED_ENC);   // constant per process -> graph-stable
    const bool use_aux_gemm = (ws_size >= WS_NEED_AUX);   // implies use_mfma (AUX > ENC)

    k_init<<<64, 256, 0, stream>>>((int*)d_ws);
    k_dead<<<60, 256, 0, stream>>>(nbna, dead, scal);
    if (use_mfma) {
        k_prep_a<<<512, 256, 0, stream>>>(x, b_dec, Ahg, Alg);
        k_prep_w<<<dim3(NS / 32, ND / 32), 256, 0, stream>>>(W_enc, WhT, WlT);
        // hist1 fused into enc epilogue
        k_enc_mfma<<<(NB / 256) * (NS / 256), 512, 0, stream>>>(Ahg, Alg, WhT, WlT, b_enc, dead, acts, h1m, h1a);
    } else {
        k_enc_gemm<<<dim3(NS / GBN, NB / GBM), 256, 0, stream>>>(x, b_dec, b_enc, W_enc, acts);
        k_hist1<<<1024, 256, 0, stream>>>(acts, dead, h1m, h1a);
    }
    k_scan<<<1, 256, 0, stream>>>(h1m, scal, 0);
    k_scan<<<1, 256, 0, stream>>>(h1a, scal, 1);
    k_hist2<<<NB, 256, 0, stream>>>(acts, dead, scal, h2m, h2a);
    k_scan<<<1, 256, 0, stream>>>(h2m, scal, 2);
    k_scan<<<1, 256, 0, stream>>>(h2a, scal, 3);
    k_collect<<<NB, 256, 0, stream>>>(acts, dead, scal, bandi, cab);
    k_resolve<<<1, 256, 0, stream>>>(cab, scal);
    k_band_re<<<512, 256, 0, stream>>>(x, b_dec, b_enc, W_enc, scal, bandi, bandv);
    k_band_sel<<<1, 256, 0, stream>>>(scal, bandi, bandv, sel_idx, sel_bits);
    if (use_aux_gemm) {
        // fused decode: recon/L2 + masked-acts write + axb pack + L1/L0
        k_decode<<<NB, 256, 0, stream>>>(acts, x, b_dec, W_dec, recon, dead, sel_idx, axb, scal, acc, 1);
        k_prep_wd<<<dim3(NS / 32, ND / 32), 256, 0, stream>>>(W_dec, WdT);
        k_aux_mfma<<<dim3(ND / 128, NB / 128, KSPLIT), 256, 0, stream>>>(axb, WdT, raux);
        k_aux_diff<<<512, 256, 0, stream>>>(raux, x, recon, acc);
    } else {
        // legacy path: decode leaves acts raw; k_aux reads raw acts; topk masks after
        k_decode<<<NB, 256, 0, stream>>>(acts, x, b_dec, W_dec, recon, dead, sel_idx, axb, scal, acc, 0);
        k_aux<<<NB, 256, 0, stream>>>(acts, dead, x, recon, W_dec, scal, acc);
        k_topk_write<<<4096, 256, 0, stream>>>(out, scal, acc, scal);
    }
    k_selwrite<<<1, 256, 0, stream>>>(acts, sel_idx, sel_bits, scal, acc);
    k_final<<<1, 64, 0, stream>>>(out, scal, acc);
}

// Round 7
// 1884.458 us; speedup vs baseline: 1.1171x; 1.0089x over previous
//
#include <hip/hip_runtime.h>

// ---------------- problem constants ----------------
#define NB 2048
#define ND 1024
#define NS 30720
#define K_MAIN 131072LL           // TOP_K * B
#define K_AUX  2097152LL          // TOP_K * AUX_K_MULT * B
#define BAND_CAP 16384
#define SEL_CAP  8192
#define CANDA_CAP 65536
#define EPS_BAND 1e-3f            // covers worst-case |approx - fp64| per element with big margin
#define KSPLIT 4

// ---------------- ws layout (bytes) ----------------
#define OFF_SCAL 0                // int[64]
#define OFF_ACC  256              // double[8]
#define OFF_H1M  512              // int[4096]
#define OFF_H1A  16896
#define OFF_H2M  33280
#define OFF_H2A  49664
#define OFF_ZERO_END 66048        // zeroed every launch
#define OFF_DEAD 66048            // 30720 bytes
#define OFF_SEL_IDX 98304         // int[SEL_CAP]
#define OFF_SEL_BITS 131072       // uint[SEL_CAP]
#define OFF_BANDI 163840          // int[BAND_CAP]
#define OFF_BANDV 229376          // double[BAND_CAP]
#define OFF_CAB  360448           // uint[CANDA_CAP]  (ends 622592)
// aux GEMM per-split output planes: fp32 [KSPLIT][NB][ND] = 32 MB
#define OFF_RAUX 1048576ULL
// split-bf16 planes for the encoder MFMA GEMM
#define OFF_AH   (OFF_RAUX + (unsigned long long)KSPLIT * NB * ND * 4)   // 34603008
#define OFF_AL   (OFF_AH + 2048ULL*1024*2)
#define OFF_WHT  (OFF_AL + 2048ULL*1024*2)          // [30720][1024] bf16 = 60 MB (transposed)
#define OFF_WLT  (OFF_WHT + 30720ULL*1024*2)
#define WS_NEED_ENC (OFF_WLT + 30720ULL*1024*2)     // ~161 MB
// aux planes reuse the encoder-plane region (encoder GEMM is complete before aux pack)
#define OFF_AXB  OFF_AH                              // bf16 [NB][NS] = 126 MB
#define OFF_WDT  (OFF_AXB + 2048ULL*30720*2)         // bf16 [ND][NS] = 63 MB
#define WS_NEED_AUX (OFF_WDT + 1024ULL*30720*2)      // ~213 MB

// scal indices
#define S_NDEAD 0
#define S_B1M 1
#define S_REM1M 2
#define S_B1A 3
#define S_REM1A 4
#define S_T24M 5
#define S_BLO 6
#define S_BHI 7
#define S_T24A 8
#define S_JA 9
#define S_NHI 10
#define S_BANDC 11
#define S_CCA 12
#define S_SELCNT 13
#define S_L0 14
#define S_MINBITS 15

// acc indices
#define A_L2_0 0
#define A_L1 4
#define A_AUX 5

typedef __attribute__((ext_vector_type(8))) short bf16x8;
typedef __attribute__((ext_vector_type(4))) float f32x4;

// ---------------- helpers ----------------
__device__ __forceinline__ float blk_reduce(float v, float* sred) {
    int t = threadIdx.x;
    #pragma unroll
    for (int o = 32; o > 0; o >>= 1) v += __shfl_down(v, o, 64);
    __syncthreads();
    if ((t & 63) == 0) sred[t >> 6] = v;
    __syncthreads();
    return sred[0] + sred[1] + sred[2] + sred[3];
}

__device__ __forceinline__ unsigned short f2bf(float f) {
    unsigned u = __float_as_uint(f);
    unsigned r = (u + 0x7FFFu + ((u >> 16) & 1u)) >> 16;   // RNE
    return (unsigned short)r;
}
__device__ __forceinline__ float bf2f(unsigned short h) {
    return __uint_as_float(((unsigned)h) << 16);
}

#define GLD16(gp, lp) __builtin_amdgcn_global_load_lds( \
    (const __attribute__((address_space(1))) unsigned int*)(gp), \
    (__attribute__((address_space(3))) unsigned int*)(lp), 16, 0, 0)

// ---------------- kernels ----------------
__global__ void k_init(int* w) {
    int n = OFF_ZERO_END / 4;
    for (int i = blockIdx.x * blockDim.x + threadIdx.x; i < n; i += gridDim.x * blockDim.x)
        w[i] = 0;
}

__global__ void k_dead(const int* __restrict__ nbna, unsigned char* __restrict__ dead, int* scal) {
    int stride = gridDim.x * blockDim.x;
    int cnt = 0;
    for (int i = blockIdx.x * blockDim.x + threadIdx.x; i < NS; i += stride) {
        bool d = nbna[i] >= 20;
        dead[i] = d ? 1 : 0;
        cnt += d ? 1 : 0;
    }
    #pragma unroll
    for (int o = 32; o > 0; o >>= 1) cnt += __shfl_down(cnt, o, 64);
    if ((threadIdx.x & 63) == 0 && cnt) atomicAdd(&scal[S_NDEAD], cnt);
}

// split (x - b_dec) into bf16 hi/lo planes, [M][K]
__global__ void k_prep_a(const float* __restrict__ x, const float* __restrict__ b_dec,
                         unsigned short* __restrict__ Ahg, unsigned short* __restrict__ Alg) {
    int stride = gridDim.x * blockDim.x;
    for (int i = blockIdx.x * blockDim.x + threadIdx.x; i < NB * ND; i += stride) {
        float v = x[i] - b_dec[i & (ND - 1)];
        unsigned short h = f2bf(v);
        unsigned short l = f2bf(v - bf2f(h));
        Ahg[i] = h; Alg[i] = l;
    }
}

// transpose + split W_enc [K][N] fp32 -> WhT/WlT [N][K] bf16 (32x32 tiles via LDS)
__global__ __launch_bounds__(256) void k_prep_w(const float* __restrict__ W,
        unsigned short* __restrict__ WhT, unsigned short* __restrict__ WlT) {
    __shared__ float tile[32][33];
    int n0 = blockIdx.x * 32, k0 = blockIdx.y * 32;
    int t = threadIdx.x;
    int c = t & 31, r = t >> 5;          // r in 0..7
    #pragma unroll
    for (int it = 0; it < 4; it++)
        tile[r + it * 8][c] = W[(size_t)(k0 + r + it * 8) * NS + n0 + c];
    __syncthreads();
    int kl = t & 31, nl = t >> 5;
    #pragma unroll
    for (int it = 0; it < 4; it++) {
        float v = tile[kl][nl + it * 8];
        unsigned short h = f2bf(v);
        unsigned short l = f2bf(v - bf2f(h));
        size_t o = (size_t)(n0 + nl + it * 8) * ND + k0 + kl;
        WhT[o] = h; WlT[o] = l;
    }
}

// ============================================================================
// split-bf16 MFMA encoder GEMM: acts = relu(A@W + b_enc), A=Ah+Al, W=Wh+Wl.
// EXACT R2 schedule (best measured: 349 us, passing): 256x256 tile, grid 960,
// BK=32, 8 waves 2Mx4N, double-buffered 128 KiB LDS, counted vmcnt(8)
// pipeline. hist1 fused into the epilogue — R7 de-contention:
//  - 4-way lane-spread sub-bins: hh[bin*4 + (lane&3)] (same-bin lanes split
//    over 4 addresses/banks; worst-case serialization /4)
//  - main|aux packed in one atomic: +1 | (dead<<16). Overflow-safe: per copy
//    (128 threads x 128 vals) <= 16384 per 16-bit field; fields extracted
//    BEFORE summing at flush. Counts bit-identical to k_hist1.
// 16B-chunk XOR swizzle -> 0 bank conflicts in the GEMM body (verified R1).
// Per-acc FLOP order unchanged -> acts bit-identical to R1/R2/R4/R5/R6.
// ============================================================================
#define ENC_STAGE(bufoff, p, gptr, r, ktn) GLD16((gptr) + (size_t)(r) * 128 * ND + (size_t)(ktn) * 32, \
    smem + (bufoff) + (p) * 8192 + (r) * 4096 + ldsw)

#define ENC_RD_AH(boff) { _Pragma("unroll") \
    for (int i = 0; i < 8; i++) ah[i] = *(const bf16x8*)&smem[(boff) + (arb + i * 16) * 32 + cph8]; }
#define ENC_RD_AL(boff) { _Pragma("unroll") \
    for (int i = 0; i < 8; i++) al[i] = *(const bf16x8*)&smem[(boff) + 8192 + (arb + i * 16) * 32 + cph8]; }
#define ENC_RD_BH(boff) { _Pragma("unroll") \
    for (int j = 0; j < 4; j++) bh[j] = *(const bf16x8*)&smem[(boff) + 2 * 8192 + (brb + j * 16) * 32 + cph8]; }
#define ENC_RD_BL(boff) { _Pragma("unroll") \
    for (int j = 0; j < 4; j++) bl[j] = *(const bf16x8*)&smem[(boff) + 3 * 8192 + (brb + j * 16) * 32 + cph8]; }

#define ENC_MFMA(AF, BF) { \
    asm volatile("s_waitcnt lgkmcnt(0)" ::: "memory"); \
    __builtin_amdgcn_sched_barrier(0); \
    __builtin_amdgcn_s_setprio(1); \
    _Pragma("unroll") for (int i = 0; i < 8; i++) \
        _Pragma("unroll") for (int j = 0; j < 4; j++) \
            acc[i][j] = __builtin_amdgcn_mfma_f32_16x16x32_bf16(AF[i], BF[j], acc[i][j], 0, 0, 0); \
    __builtin_amdgcn_s_setprio(0); }

__global__ __launch_bounds__(512, 2) void k_enc_mfma(
        const unsigned short* __restrict__ Ahg, const unsigned short* __restrict__ Alg,
        const unsigned short* __restrict__ WhT, const unsigned short* __restrict__ WlT,
        const float* __restrict__ b_enc, const unsigned char* __restrict__ dead,
        float* __restrict__ acts, int* __restrict__ h1m, int* __restrict__ h1a) {
    // 2 bufs x 4 planes (Ah,Al,Bh,Bl) x [256][32] bf16 = 128 KiB
    __shared__ unsigned short smem[65536];
    const int t = threadIdx.x;
    const int lane = t & 63, w = t >> 6;
    const int wm = w >> 2, wn = w & 3;                 // 2x4 wave grid; wave out = 128x64
    // bijective XCD-chunked swizzle: 960 = 8 x 120; XCD x gets n-tiles [x*15, x*15+15)
    const int flat = blockIdx.x;
    const int wg = (flat & 7) * 120 + (flat >> 3);
    const int n0 = (wg >> 3) * 256;
    const int m0 = (wg & 7) * 256;
    const int ln15 = lane & 15, q = lane >> 4;
    // physical chunk offset (shorts) for fragment reads: (q ^ ((row>>1)&3)) * 8
    const int cph8 = ((q ^ ((lane >> 1) & 3)) << 3);

    // staging: wave w covers rows [r*128 + w*16, +16); lane l -> row +(l>>2), phys chunk l&3
    const int srow = w * 16 + (lane >> 2);
    const int sq8 = (((lane & 3) ^ ((lane >> 3) & 3)) << 3);   // logical chunk for this phys slot
    const unsigned short* gA  = Ahg + (size_t)(m0 + srow) * ND + sq8;
    const unsigned short* gAl = Alg + (size_t)(m0 + srow) * ND + sq8;
    const unsigned short* gB  = WhT + (size_t)(n0 + srow) * ND + sq8;
    const unsigned short* gBl = WlT + (size_t)(n0 + srow) * ND + sq8;
    const int ldsw = w * 512;                                  // wave slot in half-plane (shorts)

    f32x4 acc[8][4];
    #pragma unroll
    for (int i = 0; i < 8; i++)
        #pragma unroll
        for (int j = 0; j < 4; j++) acc[i][j] = (f32x4){0.f, 0.f, 0.f, 0.f};

    const int arb = wm * 128 + ln15;       // A frag row base (+ i*16)
    const int brb = wn * 64 + ln15;        // B frag row base (+ j*16)

    // prologue: issue AhBh(0) then BlAl(0) into buf 0 (issue ORDER = wait order)
    ENC_STAGE(0, 0, gA, 0, 0);  ENC_STAGE(0, 0, gA, 1, 0);
    ENC_STAGE(0, 2, gB, 0, 0);  ENC_STAGE(0, 2, gB, 1, 0);
    ENC_STAGE(0, 3, gBl, 0, 0); ENC_STAGE(0, 3, gBl, 1, 0);
    ENC_STAGE(0, 1, gAl, 0, 0); ENC_STAGE(0, 1, gAl, 1, 0);

    for (int kt = 0; kt < 31; ++kt) {
        const int cboff = (kt & 1) * 32768;
        const int nboff = cboff ^ 32768;
        const int kn = kt + 1;
        bf16x8 ah[8], bh[4], bl[4], al[8];

        // ---- phase 0: issue AhBh(kt+1); wait AhBh(kt); MFMA Ah*Bh ----
        ENC_STAGE(nboff, 0, gA, 0, kn);  ENC_STAGE(nboff, 0, gA, 1, kn);
        ENC_STAGE(nboff, 2, gB, 0, kn);  ENC_STAGE(nboff, 2, gB, 1, kn);
        asm volatile("s_waitcnt vmcnt(8)" ::: "memory");   // oldest 4 = AhBh(kt)
        __builtin_amdgcn_s_barrier();
        ENC_RD_AH(cboff) ENC_RD_BH(cboff)
        ENC_MFMA(ah, bh)

        // ---- phase 1: issue BlAl(kt+1); wait BlAl(kt); MFMA Ah*Bl ----
        ENC_STAGE(nboff, 3, gBl, 0, kn); ENC_STAGE(nboff, 3, gBl, 1, kn);
        ENC_STAGE(nboff, 1, gAl, 0, kn); ENC_STAGE(nboff, 1, gAl, 1, kn);
        asm volatile("s_waitcnt vmcnt(8)" ::: "memory");   // oldest 4 = BlAl(kt)
        __builtin_amdgcn_s_barrier();
        ENC_RD_BL(cboff)
        ENC_MFMA(ah, bl)

        // ---- phase 2: MFMA Al*Bh (Al visibility established at P1 barrier) ----
        ENC_RD_AL(cboff)
        ENC_MFMA(al, bh)
    }

    // ---- peeled tail kt=31 (no prefetch; counted waits drain naturally) ----
    {
        const int cboff = 32768;
        bf16x8 ah[8], bh[4], bl[4], al[8];
        asm volatile("s_waitcnt vmcnt(4)" ::: "memory");   // AhBh(31) landed
        __builtin_amdgcn_s_barrier();
        ENC_RD_AH(cboff) ENC_RD_BH(cboff)
        ENC_MFMA(ah, bh)
        asm volatile("s_waitcnt vmcnt(0)" ::: "memory");   // BlAl(31) landed
        __builtin_amdgcn_s_barrier();
        ENC_RD_BL(cboff)
        ENC_MFMA(ah, bl)
        ENC_RD_AL(cboff)
        ENC_MFMA(al, bh)
    }

    // ---- fused hist1 epilogue (4-way lane-spread, main|aux packed 16+16) ----
    // buf0 idle (tail reads buf1; buf0's tile-30 reads done before tail barriers).
    __syncthreads();
    int* hh = (int*)smem;            // 16384 ints = 64 KiB: bin b copies at hh[b*4 + 0..3]
    for (int i2 = t; i2 < 16384; i2 += 512) hh[i2] = 0;
    __syncthreads();

    const int ln3 = lane & 3;
    int zc = 0, zca = 0;
    #pragma unroll
    for (int j = 0; j < 4; j++) {
        int n = n0 + wn * 64 + j * 16 + ln15;
        float be = b_enc[n];
        int dd = dead[n] ? 1 : 0;
        #pragma unroll
        for (int i = 0; i < 8; i++) {
            int mrow = m0 + wm * 128 + i * 16 + q * 4;
            #pragma unroll
            for (int rg = 0; rg < 4; rg++) {
                float v = fmaxf(acc[i][j][rg] + be, 0.f);
                acts[(size_t)(mrow + rg) * NS + n] = v;
                unsigned bits = __float_as_uint(v);
                if (bits == 0u) { zc++; zca += dd; }
                else atomicAdd(&hh[((bits >> 20) << 2) | ln3], 1 + (dd << 16));
            }
        }
    }
    #pragma unroll
    for (int o = 32; o > 0; o >>= 1) { zc += __shfl_down(zc, o, 64); zca += __shfl_down(zca, o, 64); }
    if ((t & 63) == 0 && (zc | zca)) atomicAdd(&hh[w & 3], zc + (zca << 16));
    __syncthreads();
    for (int b2 = t; b2 < 4096; b2 += 512) {
        unsigned w0 = (unsigned)hh[b2 * 4 + 0], w1 = (unsigned)hh[b2 * 4 + 1];
        unsigned w2 = (unsigned)hh[b2 * 4 + 2], w3 = (unsigned)hh[b2 * 4 + 3];
        int m = (int)((w0 & 0xFFFFu) + (w1 & 0xFFFFu) + (w2 & 0xFFFFu) + (w3 & 0xFFFFu));
        int a = (int)((w0 >> 16) + (w1 >> 16) + (w2 >> 16) + (w3 >> 16));
        if (m) atomicAdd(&h1m[b2], m);
        if (a) atomicAdd(&h1a[b2], a);
    }
}

// fallback fp32 encoder GEMM (used when ws too small for bf16 planes)
#define GBM 128
#define GBN 128
#define GBK 8
__global__ __launch_bounds__(256) void k_enc_gemm(const float* __restrict__ x,
        const float* __restrict__ b_dec, const float* __restrict__ b_enc,
        const float* __restrict__ W, float* __restrict__ acts) {
    __shared__ float As[GBK][GBM];
    __shared__ float Bs[GBK][GBN];
    const int t = threadIdx.x;
    const int tx = t & 15, ty = t >> 4;
    const int m0 = blockIdx.y * GBM, n0 = blockIdx.x * GBN;
    const int am = t >> 1, ak = (t & 1) * 4;
    const int bk = t >> 5, bnq = (t & 31) * 4;
    float acc[8][8];
    #pragma unroll
    for (int i = 0; i < 8; i++)
        #pragma unroll
        for (int j = 0; j < 8; j++) acc[i][j] = 0.f;
    for (int k0 = 0; k0 < ND; k0 += GBK) {
        float4 av = *(const float4*)(x + (size_t)(m0 + am) * ND + k0 + ak);
        float4 bd = *(const float4*)(b_dec + k0 + ak);
        As[ak + 0][am] = av.x - bd.x;
        As[ak + 1][am] = av.y - bd.y;
        As[ak + 2][am] = av.z - bd.z;
        As[ak + 3][am] = av.w - bd.w;
        *(float4*)&Bs[bk][bnq] = *(const float4*)(W + (size_t)(k0 + bk) * NS + n0 + bnq);
        __syncthreads();
        #pragma unroll
        for (int kk = 0; kk < GBK; kk++) {
            float a[8], b[8];
            *(float4*)&a[0] = *(const float4*)&As[kk][ty * 4];
            *(float4*)&a[4] = *(const float4*)&As[kk][64 + ty * 4];
            *(float4*)&b[0] = *(const float4*)&Bs[kk][tx * 4];
            *(float4*)&b[4] = *(const float4*)&Bs[kk][64 + tx * 4];
            #pragma unroll
            for (int i = 0; i < 8; i++)
                #pragma unroll
                for (int j = 0; j < 8; j++)
                    acc[i][j] = fmaf(a[i], b[j], acc[i][j]);
        }
        __syncthreads();
    }
    float be[8];
    #pragma unroll
    for (int j = 0; j < 4; j++) {
        be[j]     = b_enc[n0 + tx * 4 + j];
        be[4 + j] = b_enc[n0 + 64 + tx * 4 + j];
    }
    #pragma unroll
    for (int i = 0; i < 8; i++) {
        int row = m0 + ((i < 4) ? (ty * 4 + i) : (64 + ty * 4 + i - 4));
        float* orow = acts + (size_t)row * NS + n0;
        #pragma unroll
        for (int j = 0; j < 4; j++) {
            orow[tx * 4 + j]      = fmaxf(acc[i][j] + be[j], 0.f);
            orow[64 + tx * 4 + j] = fmaxf(acc[i][4 + j] + be[4 + j], 0.f);
        }
    }
}

// standalone coarse histogram (fallback path only; fused into enc otherwise)
__global__ __launch_bounds__(256) void k_hist1(const float* __restrict__ acts,
        const unsigned char* __restrict__ dead, int* h1m, int* h1a) {
    __shared__ int hm[4096], ha[4096];
    int t = threadIdx.x;
    for (int i = t; i < 4096; i += 256) { hm[i] = 0; ha[i] = 0; }
    __syncthreads();
    for (int row = blockIdx.x; row < NB; row += gridDim.x) {
        const float* pr = acts + (size_t)row * NS;
        for (int c = t; c < NS; c += 256) {
            unsigned bits = __float_as_uint(pr[c]);
            bool isz = (bits == 0u);
            bool dd = dead[c] != 0;
            unsigned long long mz = __ballot(isz);
            unsigned long long mza = __ballot(isz && dd);
            if ((t & 63) == 0) {
                int nz = __popcll(mz);
                if (nz) atomicAdd(&hm[0], nz);
                int nza = __popcll(mza);
                if (nza) atomicAdd(&ha[0], nza);
            }
            if (!isz) {
                atomicAdd(&hm[bits >> 20], 1);
                if (dd) atomicAdd(&ha[bits >> 20], 1);
            }
        }
    }
    __syncthreads();
    for (int i = t; i < 4096; i += 256) {
        if (hm[i]) atomicAdd(&h1m[i], hm[i]);
        if (ha[i]) atomicAdd(&h1a[i], ha[i]);
    }
}

// suffix-scan over a 4096-bin histogram; finds bin containing rank k (from top)
__global__ void k_scan(const int* __restrict__ hist, int* scal, int mode) {
    __shared__ long long csum[256];
    __shared__ long long totsh;
    int t = threadIdx.x;
    int base = t * 16;
    int h[16];
    long long loc = 0;
    #pragma unroll
    for (int i = 0; i < 16; i++) { h[i] = hist[base + i]; loc += h[i]; }
    csum[t] = loc;
    __syncthreads();
    if (t == 0) {
        long long run = 0;
        for (int c = 255; c >= 0; c--) { long long tmp = csum[c]; csum[c] = run; run += tmp; }
        totsh = run;
    }
    __syncthreads();
    long long k;
    if (mode == 0) k = K_MAIN;
    else if (mode == 1) k = K_AUX;
    else if (mode == 2) k = (long long)scal[S_REM1M];
    else {
        if (scal[S_B1A] < 0) { if (t == 0) { scal[S_T24A] = -1; scal[S_MINBITS] = 0; } return; }
        k = (long long)scal[S_REM1A];
    }
    if (mode == 1 && k > totsh) { if (t == 0) scal[S_B1A] = -1; return; }
    long long cum = csum[t];
    int fb = -1; long long rem = 0;
    for (int i = 15; i >= 0; i--) {
        long long ca = cum;
        cum += h[i];
        if (ca < k && k <= cum) { fb = base + i; rem = k - ca; }
    }
    if (fb >= 0) {
        if (mode == 0)      { scal[S_B1M] = fb; scal[S_REM1M] = (int)rem; }
        else if (mode == 1) { scal[S_B1A] = fb; scal[S_REM1A] = (int)rem; }
        else if (mode == 2) {
            int t24 = (scal[S_B1M] << 12) | fb;
            scal[S_T24M] = t24;
            float center = __uint_as_float((((unsigned)t24) << 8) | 128u);
            float lo = center - EPS_BAND;
            if (lo < 0.f) lo = 0.f;
            scal[S_BLO] = (int)__float_as_uint(lo);
            scal[S_BHI] = (int)__float_as_uint(center + EPS_BAND);
        }
        else { scal[S_T24A] = (scal[S_B1A] << 12) | fb; scal[S_JA] = (int)rem; }
    }
}

// fine histograms inside the selected coarse bins
__global__ __launch_bounds__(256) void k_hist2(const float* __restrict__ acts,
        const unsigned char* __restrict__ dead, const int* scal, int* h2m, int* h2a) {
    int b1m = scal[S_B1M], b1a = scal[S_B1A];
    int row = blockIdx.x, t = threadIdx.x;
    const float* pr = acts + (size_t)row * NS;
    for (int c = t; c < NS; c += 256) {
        unsigned bits = __float_as_uint(pr[c]);
        int hi = (int)(bits >> 20);
        if (hi == b1m) atomicAdd(&h2m[(bits >> 8) & 0xFFF], 1);
        if (b1a >= 0 && hi == b1a && dead[c]) atomicAdd(&h2a[(bits >> 8) & 0xFFF], 1);
    }
}

// single pass: exact count above band (n_hi), band-member collection, aux candidates
__global__ __launch_bounds__(256) void k_collect(const float* __restrict__ acts,
        const unsigned char* __restrict__ dead, int* scal,
        int* bandi, unsigned* cab) {
    int row = blockIdx.x, t = threadIdx.x;
    unsigned blo = (unsigned)scal[S_BLO], bhi = (unsigned)scal[S_BHI];
    int t24a = scal[S_T24A];
    const float* pr = acts + (size_t)row * NS;
    int cnt = 0;
    for (int c = t; c < NS; c += 256) {
        unsigned bits = __float_as_uint(pr[c]);
        if (bits > bhi) cnt++;
        else if (bits >= blo) {
            int p = atomicAdd(&scal[S_BANDC], 1);
            if (p < BAND_CAP) bandi[p] = row * NS + c;
        }
        if (t24a >= 0 && (bits >> 8) == (unsigned)t24a && dead[c]) {
            int p = atomicAdd(&scal[S_CCA], 1);
            if (p < CANDA_CAP) cab[p] = bits;
        }
    }
    #pragma unroll
    for (int o = 32; o > 0; o >>= 1) cnt += __shfl_down(cnt, o, 64);
    __shared__ int s2[4];
    if ((t & 63) == 0) s2[t >> 6] = cnt;
    __syncthreads();
    if (t == 0) {
        int tot = s2[0] + s2[1] + s2[2] + s2[3];
        if (tot) atomicAdd(&scal[S_NHI], tot);
    }
}

// aux threshold value from boundary-fine-bin candidates
__global__ __launch_bounds__(256) void k_resolve(const unsigned* __restrict__ cab, int* scal) {
    __shared__ int h[256];
    int t = threadIdx.x;
    h[t] = 0;
    __syncthreads();
    int t24a = scal[S_T24A];
    if (t24a < 0) { if (t == 0) scal[S_MINBITS] = 0; return; }
    int cnt = min(scal[S_CCA], CANDA_CAP);
    int ja = scal[S_JA];
    for (int e = t; e < cnt; e += 256) atomicAdd(&h[cab[e] & 0xFF], 1);
    __syncthreads();
    if (t == 0) {
        long long cum = 0; int L = 0;
        for (int b = 255; b >= 0; b--) {
            long long ca = cum; cum += h[b];
            if (ca < ja && ja <= cum) { L = b; break; }
        }
        scal[S_MINBITS] = (int)((((unsigned)t24a) << 8) | (unsigned)L);
    }
}

// fp64 recompute of band elements (exact vs reference)
__global__ __launch_bounds__(256) void k_band_re(const float* __restrict__ x,
        const float* __restrict__ b_dec, const float* __restrict__ b_enc,
        const float* __restrict__ W, const int* scal,
        const int* __restrict__ bandi, double* __restrict__ bandv) {
    int n = min(scal[S_BANDC], BAND_CAP);
    int t = threadIdx.x;
    __shared__ double sd[4];
    for (int e = blockIdx.x; e < n; e += gridDim.x) {
        int idx = bandi[e];
        int r = idx / NS, c = idx - r * NS;
        double s = 0.0;
        #pragma unroll
        for (int j = 0; j < 4; j++) {
            int d = t + j * 256;
            s += ((double)x[(size_t)r * ND + d] - (double)b_dec[d]) * (double)W[(size_t)d * NS + c];
        }
        #pragma unroll
        for (int o = 32; o > 0; o >>= 1) s += __shfl_down(s, o, 64);
        if ((t & 63) == 0) sd[t >> 6] = s;
        __syncthreads();
        if (t == 0) {
            double v = sd[0] + sd[1] + sd[2] + sd[3] + (double)b_enc[c];
            bandv[e] = fmax(v, 0.0);
        }
        __syncthreads();
    }
}

// exact selection within band: rank by (v64 desc, idx asc); keep rank < need = K - n_hi
__global__ __launch_bounds__(256) void k_band_sel(int* scal,
        const int* __restrict__ bandi, const double* __restrict__ bandv,
        int* sel_idx, unsigned* sel_bits) {
    int n = min(scal[S_BANDC], BAND_CAP);
    int need = (int)(K_MAIN - (long long)scal[S_NHI]);
    if (need < 0) need = 0;
    if (need > n) need = n;
    int t = threadIdx.x;
    for (int e = t; e < n; e += 256) {
        double v = bandv[e];
        int idx = bandi[e];
        int rank = 0;
        for (int j = 0; j < n; j++) {
            double vj = bandv[j];
            rank += (vj > v || (vj == v && bandi[j] < idx)) ? 1 : 0;
        }
        if (rank < need) {
            int p = atomicAdd(&scal[S_SELCNT], 1);
            if (p < SEL_CAP) { sel_idx[p] = idx; sel_bits[p] = __float_as_uint((float)v); }
        }
    }
}

// hierarchical sparse decode; when fuse==1 additionally:
//  - writes masked acts in-place (v if bits>bhi else 0; band restored by selwrite)
//  - writes bf16 aux plane axb = relu(v - minval) * dead   (was k_aux_pack)
//  - accumulates L1/L0 of strict members                    (was k_topk_write)
// Row-private per block; each element read before written. Raw acts consumers
// (hist2/collect) run BEFORE this kernel.
__global__ __launch_bounds__(256) void k_decode(float* __restrict__ acts,
        const float* __restrict__ x, const float* __restrict__ b_dec, const float* __restrict__ Wd,
        float* __restrict__ recon, const unsigned char* __restrict__ dead,
        const int* __restrict__ sel_idx, unsigned short* __restrict__ axb,
        int* scal, double* acc, int fuse) {
    int row = blockIdx.x, t = threadIdx.x;
    unsigned blo = (unsigned)scal[S_BLO], bhi = (unsigned)scal[S_BHI];
    float minval = __uint_as_float((unsigned)scal[S_MINBITS]);
    int selcnt = min(scal[S_SELCNT], SEL_CAP);
    __shared__ int lj[2048];
    __shared__ float lv[2048];
    __shared__ int lcnt;
    __shared__ float sred[4];
    const int d0 = t * 4;
    float4 r;
    r.x = b_dec[d0]; r.y = b_dec[d0 + 1]; r.z = b_dec[d0 + 2]; r.w = b_dec[d0 + 3];
    float4 xv = *(const float4*)(x + (size_t)row * ND + d0);
    float* arow = acts + (size_t)row * NS;
    unsigned short* xrow = axb + (size_t)row * NS;
    float l1 = 0.f; int kcnt = 0;
    const int bnds[5] = {0, 2048, 6144, 14336, NS};
    for (int g = 0; g < 4; g++) {
        for (int c0 = bnds[g]; c0 < bnds[g + 1]; c0 += 2048) {
            __syncthreads();
            if (t == 0) lcnt = 0;
            __syncthreads();
            #pragma unroll
            for (int u = 0; u < 8; u++) {
                int c = c0 + u * 256 + t;
                float v = arow[c];
                unsigned bits = __float_as_uint(v);
                bool strict = bits > bhi;
                bool keep = strict;
                if (!keep && bits >= blo) {
                    int flat = row * NS + c;
                    for (int e = 0; e < selcnt; e++)
                        if (sel_idx[e] == flat) { keep = true; break; }
                }
                if (keep) { int p = atomicAdd(&lcnt, 1); lj[p] = c; lv[p] = v; }
                if (fuse) {
                    if (strict) { l1 += v; kcnt++; }
                    arow[c] = strict ? v : 0.f;
                    float o = (dead[c] && v > minval) ? (v - minval) : 0.f;
                    xrow[c] = f2bf(o);
                }
            }
            __syncthreads();
            int n = lcnt;
            for (int e = 0; e < n; e++) {
                float a_ = lv[e];
                float4 w = *(const float4*)(Wd + (size_t)lj[e] * ND + d0);
                r.x = fmaf(a_, w.x, r.x);
                r.y = fmaf(a_, w.y, r.y);
                r.z = fmaf(a_, w.z, r.z);
                r.w = fmaf(a_, w.w, r.w);
            }
        }
        float dx = r.x - xv.x, dy = r.y - xv.y, dz = r.z - xv.z, dw = r.w - xv.w;
        float ss = dx * dx + dy * dy + dz * dz + dw * dw;
        float tot = blk_reduce(ss, sred);
        if (t == 0) atomicAdd(&acc[A_L2_0 + g], (double)tot);
    }
    float* orow = recon + (size_t)row * ND + d0;   // region misaligned -> scalar stores
    orow[0] = r.x; orow[1] = r.y; orow[2] = r.z; orow[3] = r.w;
    if (fuse) {
        #pragma unroll
        for (int o = 32; o > 0; o >>= 1) { l1 += __shfl_down(l1, o, 64); kcnt += __shfl_down(kcnt, o, 64); }
        __shared__ float s1[4];
        __shared__ int s2[4];
        if ((t & 63) == 0) { s1[t >> 6] = l1; s2[t >> 6] = kcnt; }
        __syncthreads();
        if (t == 0) {
            atomicAdd(&acc[A_L1], (double)(s1[0] + s1[1] + s1[2] + s1[3]));
            atomicAdd(&scal[S_L0], s2[0] + s2[1] + s2[2] + s2[3]);
        }
    }
}

// ---- aux via dense masked GEMM ----
// pack acts_aux = relu(acts - minval) * dead into bf16 plane [NB][NS]
// (fallback path only; fused into k_decode otherwise)
__global__ __launch_bounds__(256) void k_aux_pack(const float* __restrict__ acts,
        const unsigned char* __restrict__ dead, const int* scal,
        unsigned short* __restrict__ axb) {
    int row = blockIdx.x, t = threadIdx.x;
    float minval = __uint_as_float((unsigned)scal[S_MINBITS]);
    const float* arow = acts + (size_t)row * NS;
    unsigned short* orow = axb + (size_t)row * NS;
    for (int c = t; c < NS; c += 256) {
        float v = arow[c];
        float o = (dead[c] && v > minval) ? (v - minval) : 0.f;
        orow[c] = f2bf(o);
    }
}

// transpose W_dec [S][D] fp32 -> WdT [D][S] bf16
__global__ __launch_bounds__(256) void k_prep_wd(const float* __restrict__ Wd,
        unsigned short* __restrict__ WdT) {
    __shared__ float tile[32][33];
    int s0 = blockIdx.x * 32, d0 = blockIdx.y * 32;
    int t = threadIdx.x;
    int c = t & 31, r = t >> 5;
    #pragma unroll
    for (int it = 0; it < 4; it++)
        tile[r + it * 8][c] = Wd[(size_t)(s0 + r + it * 8) * ND + d0 + c];
    __syncthreads();
    int sl = t & 31, dl = t >> 5;
    #pragma unroll
    for (int it = 0; it < 4; it++)
        WdT[(size_t)(d0 + dl + it * 8) * NS + s0 + sl] = f2bf(tile[sl][dl + it * 8]);
}

// bf16 MFMA aux GEMM: raux[z] = acts_aux @ W_dec (K-split over z), per-split fp32 planes.
// R7: double-buffered (32 KiB LDS -> 2 blocks/CU), race-free single-barrier
// schedule (vmcnt(0) BEFORE s_barrier -> cross-wave LDS visibility; stage
// issue after the barrier -> prev-tile readers provably done), and the
// verified 16B-chunk XOR swizzle (pre-swizzled global source sq8 + swizzled
// read cph8, linear gload_lds dest) -> kills the 8-way ds_read bank conflict.
// Per-acc MFMA order unchanged (k ascending, j-outer/i-inner) -> bit-identical.
__global__ __launch_bounds__(256) void k_aux_mfma(
        const unsigned short* __restrict__ axb, const unsigned short* __restrict__ WdT,
        float* __restrict__ raux) {
    __shared__ unsigned short smem[16384];   // 2 bufs x (As[128x32] + Bs[128x32]) = 32 KiB
    const int t = threadIdx.x;
    const int lane = t & 63, w = t >> 6;
    const int wm = w >> 1, wn = w & 1;
    const int m0 = blockIdx.y * 128, n0 = blockIdx.x * 128;
    const int kbase = blockIdx.z * (NS / KSPLIT);
    const int ln15 = lane & 15, q = lane >> 4;
    const int cph8 = ((q ^ ((lane >> 1) & 3)) << 3);
    const int sq8 = (((lane & 3) ^ ((lane >> 3) & 3)) << 3);

    f32x4 acc[4][4];
    #pragma unroll
    for (int i = 0; i < 4; i++)
        #pragma unroll
        for (int j = 0; j < 4; j++) acc[i][j] = (f32x4){0.f, 0.f, 0.f, 0.f};

    // waves 0,1 stage A halves; waves 2,3 stage B halves (64 rows x 32 cols each)
    const unsigned short* gbase;
    int ldst;
    if (w < 2) { gbase = axb + (size_t)(m0 + w * 64) * NS; ldst = w * 64 * 32; }
    else       { gbase = WdT + (size_t)(n0 + (w - 2) * 64) * NS; ldst = 4096 + (w - 2) * 64 * 32; }
    const unsigned short* glane = gbase + (size_t)(lane >> 2) * NS + sq8 + kbase;
    ldst += (lane >> 2) * 32 + (lane & 3) * 8;

    // prologue: stage kt=0 into buf0
    #pragma unroll
    for (int ch = 0; ch < 4; ch++)
        GLD16(glane + (size_t)ch * 16 * NS, smem + ldst + ch * 512);

    const int NKT = (NS / KSPLIT) / 32;   // 240
    for (int kt = 0; kt < NKT; ++kt) {
        const int cb = (kt & 1) * 8192;
        const int nb = cb ^ 8192;
        asm volatile("s_waitcnt vmcnt(0)" ::: "memory");   // own stage(kt) landed
        __builtin_amdgcn_s_barrier();                      // all stage(kt) visible; buf nb readers done
        __builtin_amdgcn_sched_barrier(0);
        if (kt < NKT - 1) {
            #pragma unroll
            for (int ch = 0; ch < 4; ch++)
                GLD16(glane + (size_t)ch * 16 * NS + (size_t)(kt + 1) * 32, smem + nb + ldst + ch * 512);
        }
        bf16x8 af[4], bf[4];
        #pragma unroll
        for (int i = 0; i < 4; i++)
            af[i] = *(const bf16x8*)&smem[cb + (wm * 64 + i * 16 + ln15) * 32 + cph8];
        #pragma unroll
        for (int j = 0; j < 4; j++)
            bf[j] = *(const bf16x8*)&smem[cb + 4096 + (wn * 64 + j * 16 + ln15) * 32 + cph8];
        asm volatile("s_waitcnt lgkmcnt(0)" ::: "memory");
        __builtin_amdgcn_sched_barrier(0);
        __builtin_amdgcn_s_setprio(1);
        #pragma unroll
        for (int j = 0; j < 4; j++)
            #pragma unroll
            for (int i = 0; i < 4; i++)
                acc[i][j] = __builtin_amdgcn_mfma_f32_16x16x32_bf16(af[i], bf[j], acc[i][j], 0, 0, 0);
        __builtin_amdgcn_s_setprio(0);
    }
    float* rz = raux + (size_t)blockIdx.z * NB * ND;
    #pragma unroll
    for (int j = 0; j < 4; j++) {
        int n = n0 + wn * 64 + j * 16 + ln15;
        #pragma unroll
        for (int i = 0; i < 4; i++) {
            int mrow = m0 + wm * 64 + i * 16 + q * 4;
            #pragma unroll
            for (int rg = 0; rg < 4; rg++)
                rz[(size_t)(mrow + rg) * ND + n] = acc[i][j][rg];
        }
    }
}

// aux loss: sum over B*D of (sum_z raux[z] - (x - recon))^2
__global__ __launch_bounds__(256) void k_aux_diff(const float* __restrict__ raux,
        const float* __restrict__ x, const float* __restrict__ recon, double* acc) {
    __shared__ float sred[4];
    float ss = 0.f;
    int stride = gridDim.x * blockDim.x;
    for (int i = blockIdx.x * blockDim.x + threadIdx.x; i < NB * ND; i += stride) {
        float ra = raux[i];
        #pragma unroll
        for (int z = 1; z < KSPLIT; z++) ra += raux[(size_t)z * NB * ND + i];
        float d = ra - (x[i] - recon[i]);
        ss += d * d;
    }
    float tot = blk_reduce(ss, sred);
    if (threadIdx.x == 0) atomicAdd(&acc[A_AUX], (double)tot);
}

// fallback aux: sparse gather per row
__global__ __launch_bounds__(256) void k_aux(const float* __restrict__ acts,
        const unsigned char* __restrict__ dead, const float* __restrict__ x,
        const float* __restrict__ recon, const float* __restrict__ Wd,
        const int* scal, double* acc) {
    int row = blockIdx.x, t = threadIdx.x;
    float minval = __uint_as_float((unsigned)scal[S_MINBITS]);
    __shared__ int lj[2048];
    __shared__ float lv[2048];
    __shared__ int lcnt;
    __shared__ float sred[4];
    float4 r = {0.f, 0.f, 0.f, 0.f};
    const float* arow = acts + (size_t)row * NS;
    const int d0 = t * 4;
    for (int c0 = 0; c0 < NS; c0 += 2048) {
        __syncthreads();
        if (t == 0) lcnt = 0;
        __syncthreads();
        #pragma unroll
        for (int u = 0; u < 8; u++) {
            int c = c0 + u * 256 + t;
            float v = arow[c];
            if (dead[c] && v > minval) {
                int p = atomicAdd(&lcnt, 1);
                lj[p] = c; lv[p] = v - minval;
            }
        }
        __syncthreads();
        int n = lcnt;
        for (int e = 0; e < n; e++) {
            float a_ = lv[e];
            float4 w = *(const float4*)(Wd + (size_t)lj[e] * ND + d0);
            r.x = fmaf(a_, w.x, r.x);
            r.y = fmaf(a_, w.y, r.y);
            r.z = fmaf(a_, w.z, r.z);
            r.w = fmaf(a_, w.w, r.w);
        }
    }
    const float* xr = x + (size_t)row * ND + d0;
    const float* rr = recon + (size_t)row * ND + d0;
    float dx = r.x - (xr[0] - rr[0]);
    float dy = r.y - (xr[1] - rr[1]);
    float dz = r.z - (xr[2] - rr[2]);
    float dw = r.w - (xr[3] - rr[3]);
    float ss = dx * dx + dy * dy + dz * dz + dw * dw;
    float tot = blk_reduce(ss, sred);
    if (t == 0) atomicAdd(&acc[A_AUX], (double)tot);
}

// in-place top-k zeroing over d_out acts region (fallback path only; fused into k_decode otherwise)
__global__ __launch_bounds__(256) void k_topk_write(float* __restrict__ out, const int* scal, double* acc, int* scalw) {
    unsigned bhi = (unsigned)scal[S_BHI];
    float l1 = 0.f;
    int cnt = 0;
    const long long vstart = 8, nvec = 15728639;   // [8, 62914564) as float4
    long long stride = (long long)gridDim.x * blockDim.x;
    for (long long i = (long long)blockIdx.x * blockDim.x + threadIdx.x; i < nvec; i += stride) {
        float4* p = (float4*)(out + vstart) + i;
        float4 v = *p;
        #define PROC(F) { unsigned b = __float_as_uint(v.F); if (b > bhi) { l1 += v.F; cnt++; } else v.F = 0.f; }
        PROC(x) PROC(y) PROC(z) PROC(w)
        #undef PROC
        *p = v;
    }
    if (blockIdx.x == 0 && threadIdx.x == 0) {
        const long long head[4] = {5, 6, 7, 62914564LL};
        for (int q = 0; q < 4; q++) {
            float v = out[head[q]];
            unsigned b = __float_as_uint(v);
            if (b > bhi) { l1 += v; cnt++; } else out[head[q]] = 0.f;
        }
    }
    int t = threadIdx.x;
    #pragma unroll
    for (int o = 32; o > 0; o >>= 1) { l1 += __shfl_down(l1, o, 64); cnt += __shfl_down(cnt, o, 64); }
    __shared__ float s1[4];
    __shared__ int s2[4];
    if ((t & 63) == 0) { s1[t >> 6] = l1; s2[t >> 6] = cnt; }
    __syncthreads();
    if (t == 0) {
        atomicAdd(&acc[A_L1], (double)(s1[0] + s1[1] + s1[2] + s1[3]));
        atomicAdd(&scalw[S_L0], s2[0] + s2[1] + s2[2] + s2[3]);
    }
}

// rewrite the selected band entries (zeroed by the masking pass) + their L1/L0 contribution
__global__ __launch_bounds__(256) void k_selwrite(float* __restrict__ acts, const int* __restrict__ sel_idx,
        const unsigned* __restrict__ sel_bits, int* scal, double* acc) {
    int t = threadIdx.x;
    int n = min(scal[S_SELCNT], SEL_CAP);
    float l1 = 0.f;
    for (int e = t; e < n; e += 256) {
        float v = __uint_as_float(sel_bits[e]);
        acts[sel_idx[e]] = v;
        l1 += v;
    }
    #pragma unroll
    for (int o = 32; o > 0; o >>= 1) l1 += __shfl_down(l1, o, 64);
    __shared__ float s1[4];
    if ((t & 63) == 0) s1[t >> 6] = l1;
    __syncthreads();
    if (t == 0) {
        atomicAdd(&acc[A_L1], (double)(s1[0] + s1[1] + s1[2] + s1[3]));
        atomicAdd(&scal[S_L0], n);
    }
}

__global__ void k_final(float* out, const int* scal, const double* acc) {
    if (threadIdx.x == 0 && blockIdx.x == 0) {
        double ml2 = (acc[0] + acc[1] + acc[2] + acc[3]) * 0.25 / ((double)NB * ND);
        double l1 = 1e-3 * acc[A_L1] / (double)NB;
        double aux = (scal[S_NDEAD] > 0) ? (1e-2 * acc[A_AUX] / ((double)NB * ND)) : 0.0;
        out[0] = (float)(ml2 + l1 + aux);
        out[1] = (float)ml2;
        out[2] = (float)l1;
        out[3] = (float)aux;
        out[4] = (float)scal[S_L0] / (float)NB;
    }
}

// ---------------- launch ----------------
extern "C" void kernel_launch(void* const* d_in, const int* in_sizes, int n_in,
                              void* d_out, int out_size, void* d_ws, size_t ws_size,
                              hipStream_t stream) {
    const float* x     = (const float*)d_in[0];
    const float* b_dec = (const float*)d_in[1];
    const float* b_enc = (const float*)d_in[2];
    const float* W_enc = (const float*)d_in[3];
    const float* W_dec = (const float*)d_in[4];
    const int*   nbna  = (const int*)d_in[5];

    float* out = (float*)d_out;
    float* acts  = out + 5;                         // [NB, NS] (misaligned region)
    float* recon = out + 5 + (size_t)NB * NS;       // [NB, ND]

    char* ws = (char*)d_ws;
    int*    scal = (int*)(ws + OFF_SCAL);
    double* acc  = (double*)(ws + OFF_ACC);
    int*    h1m  = (int*)(ws + OFF_H1M);
    int*    h1a  = (int*)(ws + OFF_H1A);
    int*    h2m  = (int*)(ws + OFF_H2M);
    int*    h2a  = (int*)(ws + OFF_H2A);
    unsigned char* dead = (unsigned char*)(ws + OFF_DEAD);
    int*      sel_idx  = (int*)(ws + OFF_SEL_IDX);
    unsigned* sel_bits = (unsigned*)(ws + OFF_SEL_BITS);
    int*      bandi = (int*)(ws + OFF_BANDI);
    double*   bandv = (double*)(ws + OFF_BANDV);
    unsigned* cab   = (unsigned*)(ws + OFF_CAB);
    float*    raux  = (float*)(ws + OFF_RAUX);
    unsigned short* Ahg = (unsigned short*)(ws + OFF_AH);
    unsigned short* Alg = (unsigned short*)(ws + OFF_AL);
    unsigned short* WhT = (unsigned short*)(ws + OFF_WHT);
    unsigned short* WlT = (unsigned short*)(ws + OFF_WLT);
    unsigned short* axb = (unsigned short*)(ws + OFF_AXB);
    unsigned short* WdT = (unsigned short*)(ws + OFF_WDT);

    const bool use_mfma     = (ws_size >= WS_NEED_ENC);   // constant per process -> graph-stable
    const bool use_aux_gemm = (ws_size >= WS_NEED_AUX);   // implies use_mfma (AUX > ENC)

    k_init<<<64, 256, 0, stream>>>((int*)d_ws);
    k_dead<<<60, 256, 0, stream>>>(nbna, dead, scal);
    if (use_mfma) {
        k_prep_a<<<512, 256, 0, stream>>>(x, b_dec, Ahg, Alg);
        k_prep_w<<<dim3(NS / 32, ND / 32), 256, 0, stream>>>(W_enc, WhT, WlT);
        // hist1 fused into enc epilogue
        k_enc_mfma<<<(NB / 256) * (NS / 256), 512, 0, stream>>>(Ahg, Alg, WhT, WlT, b_enc, dead, acts, h1m, h1a);
    } else {
        k_enc_gemm<<<dim3(NS / GBN, NB / GBM), 256, 0, stream>>>(x, b_dec, b_enc, W_enc, acts);
        k_hist1<<<1024, 256, 0, stream>>>(acts, dead, h1m, h1a);
    }
    k_scan<<<1, 256, 0, stream>>>(h1m, scal, 0);
    k_scan<<<1, 256, 0, stream>>>(h1a, scal, 1);
    k_hist2<<<NB, 256, 0, stream>>>(acts, dead, scal, h2m, h2a);
    k_scan<<<1, 256, 0, stream>>>(h2m, scal, 2);
    k_scan<<<1, 256, 0, stream>>>(h2a, scal, 3);
    k_collect<<<NB, 256, 0, stream>>>(acts, dead, scal, bandi, cab);
    k_resolve<<<1, 256, 0, stream>>>(cab, scal);
    k_band_re<<<512, 256, 0, stream>>>(x, b_dec, b_enc, W_enc, scal, bandi, bandv);
    k_band_sel<<<1, 256, 0, stream>>>(scal, bandi, bandv, sel_idx, sel_bits);
    if (use_aux_gemm) {
        // fused decode: recon/L2 + masked-acts write + axb pack + L1/L0
        k_decode<<<NB, 256, 0, stream>>>(acts, x, b_dec, W_dec, recon, dead, sel_idx, axb, scal, acc, 1);
        k_prep_wd<<<dim3(NS / 32, ND / 32), 256, 0, stream>>>(W_dec, WdT);
        k_aux_mfma<<<dim3(ND / 128, NB / 128, KSPLIT), 256, 0, stream>>>(axb, WdT, raux);
        k_aux_diff<<<512, 256, 0, stream>>>(raux, x, recon, acc);
    } else {
        // legacy path: decode leaves acts raw; k_aux reads raw acts; topk masks after
        k_decode<<<NB, 256, 0, stream>>>(acts, x, b_dec, W_dec, recon, dead, sel_idx, axb, scal, acc, 0);
        k_aux<<<NB, 256, 0, stream>>>(acts, dead, x, recon, W_dec, scal, acc);
        k_topk_write<<<4096, 256, 0, stream>>>(out, scal, acc, scal);
    }
    k_selwrite<<<1, 256, 0, stream>>>(acts, sel_idx, sel_bits, scal, acc);
    k_final<<<1, 64, 0, stream>>>(out, scal, acc);
}

// Round 8
// 1676.807 us; speedup vs baseline: 1.2555x; 1.1238x over previous
//
#include <hip/hip_runtime.h>

// ---------------- problem constants ----------------
#define NB 2048
#define ND 1024
#define NS 30720
#define K_MAIN 131072LL           // TOP_K * B
#define K_AUX  2097152LL          // TOP_K * AUX_K_MULT * B
#define BAND_CAP 16384
#define SEL_CAP  8192
#define CANDA_CAP 65536
#define EPS_BAND 1e-3f            // covers worst-case |approx - fp64| per element with big margin
#define KSPLIT 4

// ---------------- ws layout (bytes) ----------------
#define OFF_SCAL 0                // int[64]
#define OFF_ACC  256              // double[8]
#define OFF_H1M  512              // int[4096]
#define OFF_H1A  16896
#define OFF_H2M  33280
#define OFF_H2A  49664
#define OFF_ZERO_END 66048        // zeroed every launch
#define OFF_DEAD 66048            // 30720 bytes
#define OFF_SEL_IDX 98304         // int[SEL_CAP]
#define OFF_SEL_BITS 131072       // uint[SEL_CAP]
#define OFF_BANDI 163840          // int[BAND_CAP]
#define OFF_BANDV 229376          // double[BAND_CAP]
#define OFF_CAB  360448           // uint[CANDA_CAP]  (ends 622592)
// aux GEMM per-split output planes: fp32 [KSPLIT][NB][ND] = 32 MB
#define OFF_RAUX 1048576ULL
// split-bf16 planes for the encoder MFMA GEMM
#define OFF_AH   (OFF_RAUX + (unsigned long long)KSPLIT * NB * ND * 4)   // 34603008
#define OFF_AL   (OFF_AH + 2048ULL*1024*2)
#define OFF_WHT  (OFF_AL + 2048ULL*1024*2)          // [30720][1024] bf16 = 60 MB (transposed)
#define OFF_WLT  (OFF_WHT + 30720ULL*1024*2)
#define WS_NEED_ENC (OFF_WLT + 30720ULL*1024*2)     // ~161 MB
// aux planes reuse the encoder-plane region (encoder GEMM is complete before aux pack)
#define OFF_AXB  OFF_AH                              // bf16 [NB][NS] = 126 MB
#define OFF_WDT  (OFF_AXB + 2048ULL*30720*2)         // bf16 [ND][NS] = 63 MB
#define WS_NEED_AUX (OFF_WDT + 1024ULL*30720*2)      // ~213 MB

// scal indices
#define S_NDEAD 0
#define S_B1M 1
#define S_REM1M 2
#define S_B1A 3
#define S_REM1A 4
#define S_T24M 5
#define S_BLO 6
#define S_BHI 7
#define S_T24A 8
#define S_JA 9
#define S_NHI 10
#define S_BANDC 11
#define S_CCA 12
#define S_SELCNT 13
#define S_L0 14
#define S_MINBITS 15

// acc indices
#define A_L2_0 0
#define A_L1 4
#define A_AUX 5

typedef __attribute__((ext_vector_type(8))) short bf16x8;
typedef __attribute__((ext_vector_type(4))) float f32x4;
// 4-byte-aligned float4 for the misaligned d_out regions (acts = out+5 is
// 4-mod-16). Compiler emits dwordx4 (gfx950 handles dword-aligned vectors)
// or legally splits — correct either way.
typedef float f32x4u __attribute__((ext_vector_type(4), aligned(4)));

// ---------------- helpers ----------------
__device__ __forceinline__ float blk_reduce(float v, float* sred) {
    int t = threadIdx.x;
    #pragma unroll
    for (int o = 32; o > 0; o >>= 1) v += __shfl_down(v, o, 64);
    __syncthreads();
    if ((t & 63) == 0) sred[t >> 6] = v;
    __syncthreads();
    return sred[0] + sred[1] + sred[2] + sred[3];
}

__device__ __forceinline__ unsigned short f2bf(float f) {
    unsigned u = __float_as_uint(f);
    unsigned r = (u + 0x7FFFu + ((u >> 16) & 1u)) >> 16;   // RNE
    return (unsigned short)r;
}
__device__ __forceinline__ float bf2f(unsigned short h) {
    return __uint_as_float(((unsigned)h) << 16);
}

#define GLD16(gp, lp) __builtin_amdgcn_global_load_lds( \
    (const __attribute__((address_space(1))) unsigned int*)(gp), \
    (__attribute__((address_space(3))) unsigned int*)(lp), 16, 0, 0)

// ---------------- kernels ----------------
__global__ void k_init(int* w) {
    int n = OFF_ZERO_END / 4;
    for (int i = blockIdx.x * blockDim.x + threadIdx.x; i < n; i += gridDim.x * blockDim.x)
        w[i] = 0;
}

__global__ void k_dead(const int* __restrict__ nbna, unsigned char* __restrict__ dead, int* scal) {
    int stride = gridDim.x * blockDim.x;
    int cnt = 0;
    for (int i = blockIdx.x * blockDim.x + threadIdx.x; i < NS; i += stride) {
        bool d = nbna[i] >= 20;
        dead[i] = d ? 1 : 0;
        cnt += d ? 1 : 0;
    }
    #pragma unroll
    for (int o = 32; o > 0; o >>= 1) cnt += __shfl_down(cnt, o, 64);
    if ((threadIdx.x & 63) == 0 && cnt) atomicAdd(&scal[S_NDEAD], cnt);
}

// split (x - b_dec) into bf16 hi/lo planes, [M][K]
__global__ void k_prep_a(const float* __restrict__ x, const float* __restrict__ b_dec,
                         unsigned short* __restrict__ Ahg, unsigned short* __restrict__ Alg) {
    int stride = gridDim.x * blockDim.x;
    for (int i = blockIdx.x * blockDim.x + threadIdx.x; i < NB * ND; i += stride) {
        float v = x[i] - b_dec[i & (ND - 1)];
        unsigned short h = f2bf(v);
        unsigned short l = f2bf(v - bf2f(h));
        Ahg[i] = h; Alg[i] = l;
    }
}

// transpose + split W_enc [K][N] fp32 -> WhT/WlT [N][K] bf16 (32x32 tiles via LDS)
__global__ __launch_bounds__(256) void k_prep_w(const float* __restrict__ W,
        unsigned short* __restrict__ WhT, unsigned short* __restrict__ WlT) {
    __shared__ float tile[32][33];
    int n0 = blockIdx.x * 32, k0 = blockIdx.y * 32;
    int t = threadIdx.x;
    int c = t & 31, r = t >> 5;          // r in 0..7
    #pragma unroll
    for (int it = 0; it < 4; it++)
        tile[r + it * 8][c] = W[(size_t)(k0 + r + it * 8) * NS + n0 + c];
    __syncthreads();
    int kl = t & 31, nl = t >> 5;
    #pragma unroll
    for (int it = 0; it < 4; it++) {
        float v = tile[kl][nl + it * 8];
        unsigned short h = f2bf(v);
        unsigned short l = f2bf(v - bf2f(h));
        size_t o = (size_t)(n0 + nl + it * 8) * ND + k0 + kl;
        WhT[o] = h; WlT[o] = l;
    }
}

// ============================================================================
// split-bf16 MFMA encoder GEMM (R2 schedule) + fused hist1 epilogue
// (4-way lane-spread sub-bins, main|aux packed 16+16; see R7 notes).
// ============================================================================
#define ENC_STAGE(bufoff, p, gptr, r, ktn) GLD16((gptr) + (size_t)(r) * 128 * ND + (size_t)(ktn) * 32, \
    smem + (bufoff) + (p) * 8192 + (r) * 4096 + ldsw)

#define ENC_RD_AH(boff) { _Pragma("unroll") \
    for (int i = 0; i < 8; i++) ah[i] = *(const bf16x8*)&smem[(boff) + (arb + i * 16) * 32 + cph8]; }
#define ENC_RD_AL(boff) { _Pragma("unroll") \
    for (int i = 0; i < 8; i++) al[i] = *(const bf16x8*)&smem[(boff) + 8192 + (arb + i * 16) * 32 + cph8]; }
#define ENC_RD_BH(boff) { _Pragma("unroll") \
    for (int j = 0; j < 4; j++) bh[j] = *(const bf16x8*)&smem[(boff) + 2 * 8192 + (brb + j * 16) * 32 + cph8]; }
#define ENC_RD_BL(boff) { _Pragma("unroll") \
    for (int j = 0; j < 4; j++) bl[j] = *(const bf16x8*)&smem[(boff) + 3 * 8192 + (brb + j * 16) * 32 + cph8]; }

#define ENC_MFMA(AF, BF) { \
    asm volatile("s_waitcnt lgkmcnt(0)" ::: "memory"); \
    __builtin_amdgcn_sched_barrier(0); \
    __builtin_amdgcn_s_setprio(1); \
    _Pragma("unroll") for (int i = 0; i < 8; i++) \
        _Pragma("unroll") for (int j = 0; j < 4; j++) \
            acc[i][j] = __builtin_amdgcn_mfma_f32_16x16x32_bf16(AF[i], BF[j], acc[i][j], 0, 0, 0); \
    __builtin_amdgcn_s_setprio(0); }

__global__ __launch_bounds__(512, 2) void k_enc_mfma(
        const unsigned short* __restrict__ Ahg, const unsigned short* __restrict__ Alg,
        const unsigned short* __restrict__ WhT, const unsigned short* __restrict__ WlT,
        const float* __restrict__ b_enc, const unsigned char* __restrict__ dead,
        float* __restrict__ acts, int* __restrict__ h1m, int* __restrict__ h1a) {
    // 2 bufs x 4 planes (Ah,Al,Bh,Bl) x [256][32] bf16 = 128 KiB
    __shared__ unsigned short smem[65536];
    const int t = threadIdx.x;
    const int lane = t & 63, w = t >> 6;
    const int wm = w >> 2, wn = w & 3;                 // 2x4 wave grid; wave out = 128x64
    // bijective XCD-chunked swizzle: 960 = 8 x 120; XCD x gets n-tiles [x*15, x*15+15)
    const int flat = blockIdx.x;
    const int wg = (flat & 7) * 120 + (flat >> 3);
    const int n0 = (wg >> 3) * 256;
    const int m0 = (wg & 7) * 256;
    const int ln15 = lane & 15, q = lane >> 4;
    // physical chunk offset (shorts) for fragment reads: (q ^ ((row>>1)&3)) * 8
    const int cph8 = ((q ^ ((lane >> 1) & 3)) << 3);

    // staging: wave w covers rows [r*128 + w*16, +16); lane l -> row +(l>>2), phys chunk l&3
    const int srow = w * 16 + (lane >> 2);
    const int sq8 = (((lane & 3) ^ ((lane >> 3) & 3)) << 3);   // logical chunk for this phys slot
    const unsigned short* gA  = Ahg + (size_t)(m0 + srow) * ND + sq8;
    const unsigned short* gAl = Alg + (size_t)(m0 + srow) * ND + sq8;
    const unsigned short* gB  = WhT + (size_t)(n0 + srow) * ND + sq8;
    const unsigned short* gBl = WlT + (size_t)(n0 + srow) * ND + sq8;
    const int ldsw = w * 512;                                  // wave slot in half-plane (shorts)

    f32x4 acc[8][4];
    #pragma unroll
    for (int i = 0; i < 8; i++)
        #pragma unroll
        for (int j = 0; j < 4; j++) acc[i][j] = (f32x4){0.f, 0.f, 0.f, 0.f};

    const int arb = wm * 128 + ln15;       // A frag row base (+ i*16)
    const int brb = wn * 64 + ln15;        // B frag row base (+ j*16)

    // prologue: issue AhBh(0) then BlAl(0) into buf 0 (issue ORDER = wait order)
    ENC_STAGE(0, 0, gA, 0, 0);  ENC_STAGE(0, 0, gA, 1, 0);
    ENC_STAGE(0, 2, gB, 0, 0);  ENC_STAGE(0, 2, gB, 1, 0);
    ENC_STAGE(0, 3, gBl, 0, 0); ENC_STAGE(0, 3, gBl, 1, 0);
    ENC_STAGE(0, 1, gAl, 0, 0); ENC_STAGE(0, 1, gAl, 1, 0);

    for (int kt = 0; kt < 31; ++kt) {
        const int cboff = (kt & 1) * 32768;
        const int nboff = cboff ^ 32768;
        const int kn = kt + 1;
        bf16x8 ah[8], bh[4], bl[4], al[8];

        // ---- phase 0: issue AhBh(kt+1); wait AhBh(kt); MFMA Ah*Bh ----
        ENC_STAGE(nboff, 0, gA, 0, kn);  ENC_STAGE(nboff, 0, gA, 1, kn);
        ENC_STAGE(nboff, 2, gB, 0, kn);  ENC_STAGE(nboff, 2, gB, 1, kn);
        asm volatile("s_waitcnt vmcnt(8)" ::: "memory");   // oldest 4 = AhBh(kt)
        __builtin_amdgcn_s_barrier();
        ENC_RD_AH(cboff) ENC_RD_BH(cboff)
        ENC_MFMA(ah, bh)

        // ---- phase 1: issue BlAl(kt+1); wait BlAl(kt); MFMA Ah*Bl ----
        ENC_STAGE(nboff, 3, gBl, 0, kn); ENC_STAGE(nboff, 3, gBl, 1, kn);
        ENC_STAGE(nboff, 1, gAl, 0, kn); ENC_STAGE(nboff, 1, gAl, 1, kn);
        asm volatile("s_waitcnt vmcnt(8)" ::: "memory");   // oldest 4 = BlAl(kt)
        __builtin_amdgcn_s_barrier();
        ENC_RD_BL(cboff)
        ENC_MFMA(ah, bl)

        // ---- phase 2: MFMA Al*Bh (Al visibility established at P1 barrier) ----
        ENC_RD_AL(cboff)
        ENC_MFMA(al, bh)
    }

    // ---- peeled tail kt=31 (no prefetch; counted waits drain naturally) ----
    {
        const int cboff = 32768;
        bf16x8 ah[8], bh[4], bl[4], al[8];
        asm volatile("s_waitcnt vmcnt(4)" ::: "memory");   // AhBh(31) landed
        __builtin_amdgcn_s_barrier();
        ENC_RD_AH(cboff) ENC_RD_BH(cboff)
        ENC_MFMA(ah, bh)
        asm volatile("s_waitcnt vmcnt(0)" ::: "memory");   // BlAl(31) landed
        __builtin_amdgcn_s_barrier();
        ENC_RD_BL(cboff)
        ENC_MFMA(ah, bl)
        ENC_RD_AL(cboff)
        ENC_MFMA(al, bh)
    }

    // ---- fused hist1 epilogue (4-way lane-spread, main|aux packed 16+16) ----
    // buf0 idle (tail reads buf1; buf0's tile-30 reads done before tail barriers).
    __syncthreads();
    int* hh = (int*)smem;            // 16384 ints = 64 KiB: bin b copies at hh[b*4 + 0..3]
    for (int i2 = t; i2 < 16384; i2 += 512) hh[i2] = 0;
    __syncthreads();

    const int ln3 = lane & 3;
    int zc = 0, zca = 0;
    #pragma unroll
    for (int j = 0; j < 4; j++) {
        int n = n0 + wn * 64 + j * 16 + ln15;
        float be = b_enc[n];
        int dd = dead[n] ? 1 : 0;
        #pragma unroll
        for (int i = 0; i < 8; i++) {
            int mrow = m0 + wm * 128 + i * 16 + q * 4;
            #pragma unroll
            for (int rg = 0; rg < 4; rg++) {
                float v = fmaxf(acc[i][j][rg] + be, 0.f);
                acts[(size_t)(mrow + rg) * NS + n] = v;
                unsigned bits = __float_as_uint(v);
                if (bits == 0u) { zc++; zca += dd; }
                else atomicAdd(&hh[((bits >> 20) << 2) | ln3], 1 + (dd << 16));
            }
        }
    }
    #pragma unroll
    for (int o = 32; o > 0; o >>= 1) { zc += __shfl_down(zc, o, 64); zca += __shfl_down(zca, o, 64); }
    if ((t & 63) == 0 && (zc | zca)) atomicAdd(&hh[w & 3], zc + (zca << 16));
    __syncthreads();
    for (int b2 = t; b2 < 4096; b2 += 512) {
        unsigned w0 = (unsigned)hh[b2 * 4 + 0], w1 = (unsigned)hh[b2 * 4 + 1];
        unsigned w2 = (unsigned)hh[b2 * 4 + 2], w3 = (unsigned)hh[b2 * 4 + 3];
        int m = (int)((w0 & 0xFFFFu) + (w1 & 0xFFFFu) + (w2 & 0xFFFFu) + (w3 & 0xFFFFu));
        int a = (int)((w0 >> 16) + (w1 >> 16) + (w2 >> 16) + (w3 >> 16));
        if (m) atomicAdd(&h1m[b2], m);
        if (a) atomicAdd(&h1a[b2], a);
    }
}

// fallback fp32 encoder GEMM (used when ws too small for bf16 planes)
#define GBM 128
#define GBN 128
#define GBK 8
__global__ __launch_bounds__(256) void k_enc_gemm(const float* __restrict__ x,
        const float* __restrict__ b_dec, const float* __restrict__ b_enc,
        const float* __restrict__ W, float* __restrict__ acts) {
    __shared__ float As[GBK][GBM];
    __shared__ float Bs[GBK][GBN];
    const int t = threadIdx.x;
    const int tx = t & 15, ty = t >> 4;
    const int m0 = blockIdx.y * GBM, n0 = blockIdx.x * GBN;
    const int am = t >> 1, ak = (t & 1) * 4;
    const int bk = t >> 5, bnq = (t & 31) * 4;
    float acc[8][8];
    #pragma unroll
    for (int i = 0; i < 8; i++)
        #pragma unroll
        for (int j = 0; j < 8; j++) acc[i][j] = 0.f;
    for (int k0 = 0; k0 < ND; k0 += GBK) {
        float4 av = *(const float4*)(x + (size_t)(m0 + am) * ND + k0 + ak);
        float4 bd = *(const float4*)(b_dec + k0 + ak);
        As[ak + 0][am] = av.x - bd.x;
        As[ak + 1][am] = av.y - bd.y;
        As[ak + 2][am] = av.z - bd.z;
        As[ak + 3][am] = av.w - bd.w;
        *(float4*)&Bs[bk][bnq] = *(const float4*)(W + (size_t)(k0 + bk) * NS + n0 + bnq);
        __syncthreads();
        #pragma unroll
        for (int kk = 0; kk < GBK; kk++) {
            float a[8], b[8];
            *(float4*)&a[0] = *(const float4*)&As[kk][ty * 4];
            *(float4*)&a[4] = *(const float4*)&As[kk][64 + ty * 4];
            *(float4*)&b[0] = *(const float4*)&Bs[kk][tx * 4];
            *(float4*)&b[4] = *(const float4*)&Bs[kk][64 + tx * 4];
            #pragma unroll
            for (int i = 0; i < 8; i++)
                #pragma unroll
                for (int j = 0; j < 8; j++)
                    acc[i][j] = fmaf(a[i], b[j], acc[i][j]);
        }
        __syncthreads();
    }
    float be[8];
    #pragma unroll
    for (int j = 0; j < 4; j++) {
        be[j]     = b_enc[n0 + tx * 4 + j];
        be[4 + j] = b_enc[n0 + 64 + tx * 4 + j];
    }
    #pragma unroll
    for (int i = 0; i < 8; i++) {
        int row = m0 + ((i < 4) ? (ty * 4 + i) : (64 + ty * 4 + i - 4));
        float* orow = acts + (size_t)row * NS + n0;
        #pragma unroll
        for (int j = 0; j < 4; j++) {
            orow[tx * 4 + j]      = fmaxf(acc[i][j] + be[j], 0.f);
            orow[64 + tx * 4 + j] = fmaxf(acc[i][4 + j] + be[4 + j], 0.f);
        }
    }
}

// standalone coarse histogram (fallback path only; fused into enc otherwise)
__global__ __launch_bounds__(256) void k_hist1(const float* __restrict__ acts,
        const unsigned char* __restrict__ dead, int* h1m, int* h1a) {
    __shared__ int hm[4096], ha[4096];
    int t = threadIdx.x;
    for (int i = t; i < 4096; i += 256) { hm[i] = 0; ha[i] = 0; }
    __syncthreads();
    for (int row = blockIdx.x; row < NB; row += gridDim.x) {
        const float* pr = acts + (size_t)row * NS;
        for (int c = t; c < NS; c += 256) {
            unsigned bits = __float_as_uint(pr[c]);
            bool isz = (bits == 0u);
            bool dd = dead[c] != 0;
            unsigned long long mz = __ballot(isz);
            unsigned long long mza = __ballot(isz && dd);
            if ((t & 63) == 0) {
                int nz = __popcll(mz);
                if (nz) atomicAdd(&hm[0], nz);
                int nza = __popcll(mza);
                if (nza) atomicAdd(&ha[0], nza);
            }
            if (!isz) {
                atomicAdd(&hm[bits >> 20], 1);
                if (dd) atomicAdd(&ha[bits >> 20], 1);
            }
        }
    }
    __syncthreads();
    for (int i = t; i < 4096; i += 256) {
        if (hm[i]) atomicAdd(&h1m[i], hm[i]);
        if (ha[i]) atomicAdd(&h1a[i], ha[i]);
    }
}

// suffix-scan over a 4096-bin histogram; finds bin containing rank k (from top)
__global__ void k_scan(const int* __restrict__ hist, int* scal, int mode) {
    __shared__ long long csum[256];
    __shared__ long long totsh;
    int t = threadIdx.x;
    int base = t * 16;
    int h[16];
    long long loc = 0;
    #pragma unroll
    for (int i = 0; i < 16; i++) { h[i] = hist[base + i]; loc += h[i]; }
    csum[t] = loc;
    __syncthreads();
    if (t == 0) {
        long long run = 0;
        for (int c = 255; c >= 0; c--) { long long tmp = csum[c]; csum[c] = run; run += tmp; }
        totsh = run;
    }
    __syncthreads();
    long long k;
    if (mode == 0) k = K_MAIN;
    else if (mode == 1) k = K_AUX;
    else if (mode == 2) k = (long long)scal[S_REM1M];
    else {
        if (scal[S_B1A] < 0) { if (t == 0) { scal[S_T24A] = -1; scal[S_MINBITS] = 0; } return; }
        k = (long long)scal[S_REM1A];
    }
    if (mode == 1 && k > totsh) { if (t == 0) scal[S_B1A] = -1; return; }
    long long cum = csum[t];
    int fb = -1; long long rem = 0;
    for (int i = 15; i >= 0; i--) {
        long long ca = cum;
        cum += h[i];
        if (ca < k && k <= cum) { fb = base + i; rem = k - ca; }
    }
    if (fb >= 0) {
        if (mode == 0)      { scal[S_B1M] = fb; scal[S_REM1M] = (int)rem; }
        else if (mode == 1) { scal[S_B1A] = fb; scal[S_REM1A] = (int)rem; }
        else if (mode == 2) {
            int t24 = (scal[S_B1M] << 12) | fb;
            scal[S_T24M] = t24;
            float center = __uint_as_float((((unsigned)t24) << 8) | 128u);
            float lo = center - EPS_BAND;
            if (lo < 0.f) lo = 0.f;
            scal[S_BLO] = (int)__float_as_uint(lo);
            scal[S_BHI] = (int)__float_as_uint(center + EPS_BAND);
        }
        else { scal[S_T24A] = (scal[S_B1A] << 12) | fb; scal[S_JA] = (int)rem; }
    }
}

// fine histograms inside the selected coarse bins — vectorized f32x4u reads +
// LDS-buffered bins (was: scalar reads + direct global atomics)
__global__ __launch_bounds__(256) void k_hist2(const float* __restrict__ acts,
        const unsigned char* __restrict__ dead, const int* scal, int* h2m, int* h2a) {
    __shared__ int hm[4096], ha[4096];
    int t = threadIdx.x;
    for (int i = t; i < 4096; i += 256) { hm[i] = 0; ha[i] = 0; }
    __syncthreads();
    int b1m = scal[S_B1M], b1a = scal[S_B1A];
    int row = blockIdx.x;
    const float* pr = acts + (size_t)row * NS;
    for (int c4 = t; c4 < NS / 4; c4 += 256) {
        int c = c4 * 4;
        f32x4u v4 = *(const f32x4u*)&pr[c];
        uchar4 dd4 = *(const uchar4*)(dead + c);
        unsigned char dda[4] = {dd4.x, dd4.y, dd4.z, dd4.w};
        #pragma unroll
        for (int k2 = 0; k2 < 4; k2++) {
            unsigned bits = __float_as_uint(v4[k2]);
            int hi = (int)(bits >> 20);
            if (hi == b1m) atomicAdd(&hm[(bits >> 8) & 0xFFF], 1);
            if (b1a >= 0 && hi == b1a && dda[k2]) atomicAdd(&ha[(bits >> 8) & 0xFFF], 1);
        }
    }
    __syncthreads();
    for (int i = t; i < 4096; i += 256) {
        if (hm[i]) atomicAdd(&h2m[i], hm[i]);
        if (ha[i]) atomicAdd(&h2a[i], ha[i]);
    }
}

// single pass: exact count above band (n_hi), band-member collection, aux candidates.
// Vectorized f32x4u reads + wave-aggregated pushes (ballot/prefix, one atomic
// per wave per predicate) — kills the hot-counter serialization.
__global__ __launch_bounds__(256) void k_collect(const float* __restrict__ acts,
        const unsigned char* __restrict__ dead, int* scal,
        int* bandi, unsigned* cab) {
    int row = blockIdx.x, t = threadIdx.x;
    int lane = t & 63;
    unsigned blo = (unsigned)scal[S_BLO], bhi = (unsigned)scal[S_BHI];
    int t24a = scal[S_T24A];
    const float* pr = acts + (size_t)row * NS;
    int cnt = 0;
    for (int c4 = t; c4 < NS / 4; c4 += 256) {   // 7680/256 = 30 uniform iters
        int c = c4 * 4;
        f32x4u v4 = *(const f32x4u*)&pr[c];
        uchar4 dd4 = *(const uchar4*)(dead + c);
        unsigned char dda[4] = {dd4.x, dd4.y, dd4.z, dd4.w};
        #pragma unroll
        for (int k2 = 0; k2 < 4; k2++) {
            unsigned bits = __float_as_uint(v4[k2]);
            bool hi2 = bits > bhi;
            cnt += hi2 ? 1 : 0;
            bool band = !hi2 && bits >= blo;
            unsigned long long mb = __ballot(band);
            if (mb) {
                int ldr = __ffsll(mb) - 1;
                int nb = __popcll(mb);
                int base = 0;
                if (lane == ldr) base = atomicAdd(&scal[S_BANDC], nb);
                base = __shfl(base, ldr, 64);
                if (band) {
                    int p = base + __popcll(mb & ((1ull << lane) - 1ull));
                    if (p < BAND_CAP) bandi[p] = row * NS + c + k2;
                }
            }
            bool ax = (t24a >= 0) && ((bits >> 8) == (unsigned)t24a) && dda[k2];
            unsigned long long ma = __ballot(ax);
            if (ma) {
                int ldr = __ffsll(ma) - 1;
                int na = __popcll(ma);
                int base = 0;
                if (lane == ldr) base = atomicAdd(&scal[S_CCA], na);
                base = __shfl(base, ldr, 64);
                if (ax) {
                    int p = base + __popcll(ma & ((1ull << lane) - 1ull));
                    if (p < CANDA_CAP) cab[p] = bits;
                }
            }
        }
    }
    #pragma unroll
    for (int o = 32; o > 0; o >>= 1) cnt += __shfl_down(cnt, o, 64);
    __shared__ int s2[4];
    if ((t & 63) == 0) s2[t >> 6] = cnt;
    __syncthreads();
    if (t == 0) {
        int tot = s2[0] + s2[1] + s2[2] + s2[3];
        if (tot) atomicAdd(&scal[S_NHI], tot);
    }
}

// aux threshold value from boundary-fine-bin candidates
__global__ __launch_bounds__(256) void k_resolve(const unsigned* __restrict__ cab, int* scal) {
    __shared__ int h[256];
    int t = threadIdx.x;
    h[t] = 0;
    __syncthreads();
    int t24a = scal[S_T24A];
    if (t24a < 0) { if (t == 0) scal[S_MINBITS] = 0; return; }
    int cnt = min(scal[S_CCA], CANDA_CAP);
    int ja = scal[S_JA];
    for (int e = t; e < cnt; e += 256) atomicAdd(&h[cab[e] & 0xFF], 1);
    __syncthreads();
    if (t == 0) {
        long long cum = 0; int L = 0;
        for (int b = 255; b >= 0; b--) {
            long long ca = cum; cum += h[b];
            if (ca < ja && ja <= cum) { L = b; break; }
        }
        scal[S_MINBITS] = (int)((((unsigned)t24a) << 8) | (unsigned)L);
    }
}

// fp64 recompute of band elements (exact vs reference)
__global__ __launch_bounds__(256) void k_band_re(const float* __restrict__ x,
        const float* __restrict__ b_dec, const float* __restrict__ b_enc,
        const float* __restrict__ W, const int* scal,
        const int* __restrict__ bandi, double* __restrict__ bandv) {
    int n = min(scal[S_BANDC], BAND_CAP);
    int t = threadIdx.x;
    __shared__ double sd[4];
    for (int e = blockIdx.x; e < n; e += gridDim.x) {
        int idx = bandi[e];
        int r = idx / NS, c = idx - r * NS;
        double s = 0.0;
        #pragma unroll
        for (int j = 0; j < 4; j++) {
            int d = t + j * 256;
            s += ((double)x[(size_t)r * ND + d] - (double)b_dec[d]) * (double)W[(size_t)d * NS + c];
        }
        #pragma unroll
        for (int o = 32; o > 0; o >>= 1) s += __shfl_down(s, o, 64);
        if ((t & 63) == 0) sd[t >> 6] = s;
        __syncthreads();
        if (t == 0) {
            double v = sd[0] + sd[1] + sd[2] + sd[3] + (double)b_enc[c];
            bandv[e] = fmax(v, 0.0);
        }
        __syncthreads();
    }
}

// exact selection within band: rank by (v64 desc, idx asc); keep rank < need = K - n_hi
__global__ __launch_bounds__(256) void k_band_sel(int* scal,
        const int* __restrict__ bandi, const double* __restrict__ bandv,
        int* sel_idx, unsigned* sel_bits) {
    int n = min(scal[S_BANDC], BAND_CAP);
    int need = (int)(K_MAIN - (long long)scal[S_NHI]);
    if (need < 0) need = 0;
    if (need > n) need = n;
    int t = threadIdx.x;
    for (int e = t; e < n; e += 256) {
        double v = bandv[e];
        int idx = bandi[e];
        int rank = 0;
        for (int j = 0; j < n; j++) {
            double vj = bandv[j];
            rank += (vj > v || (vj == v && bandi[j] < idx)) ? 1 : 0;
        }
        if (rank < need) {
            int p = atomicAdd(&scal[S_SELCNT], 1);
            if (p < SEL_CAP) { sel_idx[p] = idx; sel_bits[p] = __float_as_uint((float)v); }
        }
    }
}

// hierarchical sparse decode; when fuse==1 additionally:
//  - writes masked acts in-place (v if bits>bhi else 0; band restored by selwrite)
//  - writes bf16 aux plane axb = relu(v - minval) * dead   (was k_aux_pack)
//  - accumulates L1/L0 of strict members                    (was k_topk_write)
// R8: scan phase vectorized (f32x4u loads/stores on the 4-mod-16 acts region,
// ushort4 axb stores, uchar4 dead loads) — 4x fewer memory instructions.
__global__ __launch_bounds__(256) void k_decode(float* __restrict__ acts,
        const float* __restrict__ x, const float* __restrict__ b_dec, const float* __restrict__ Wd,
        float* __restrict__ recon, const unsigned char* __restrict__ dead,
        const int* __restrict__ sel_idx, unsigned short* __restrict__ axb,
        int* scal, double* acc, int fuse) {
    int row = blockIdx.x, t = threadIdx.x;
    unsigned blo = (unsigned)scal[S_BLO], bhi = (unsigned)scal[S_BHI];
    float minval = __uint_as_float((unsigned)scal[S_MINBITS]);
    int selcnt = min(scal[S_SELCNT], SEL_CAP);
    __shared__ int lj[2048];
    __shared__ float lv[2048];
    __shared__ int lcnt;
    __shared__ float sred[4];
    const int d0 = t * 4;
    float4 r;
    r.x = b_dec[d0]; r.y = b_dec[d0 + 1]; r.z = b_dec[d0 + 2]; r.w = b_dec[d0 + 3];
    float4 xv = *(const float4*)(x + (size_t)row * ND + d0);
    float* arow = acts + (size_t)row * NS;
    unsigned short* xrow = axb + (size_t)row * NS;
    float l1 = 0.f; int kcnt = 0;
    const int bnds[5] = {0, 2048, 6144, 14336, NS};
    for (int g = 0; g < 4; g++) {
        for (int c0 = bnds[g]; c0 < bnds[g + 1]; c0 += 2048) {
            __syncthreads();
            if (t == 0) lcnt = 0;
            __syncthreads();
            #pragma unroll
            for (int u = 0; u < 2; u++) {
                int c = c0 + (u * 256 + t) * 4;
                f32x4u v4 = *(const f32x4u*)&arow[c];
                uchar4 dd4 = *(const uchar4*)(dead + c);
                unsigned char dda[4] = {dd4.x, dd4.y, dd4.z, dd4.w};
                f32x4u m4;
                unsigned short ov[4];
                #pragma unroll
                for (int k2 = 0; k2 < 4; k2++) {
                    float v = v4[k2];
                    unsigned bits = __float_as_uint(v);
                    bool strict = bits > bhi;
                    bool keep = strict;
                    if (!keep && bits >= blo) {
                        int flat = row * NS + c + k2;
                        for (int e = 0; e < selcnt; e++)
                            if (sel_idx[e] == flat) { keep = true; break; }
                    }
                    if (keep) { int p = atomicAdd(&lcnt, 1); lj[p] = c + k2; lv[p] = v; }
                    if (strict) { l1 += v; kcnt++; }
                    m4[k2] = strict ? v : 0.f;
                    float o = (dda[k2] && v > minval) ? (v - minval) : 0.f;
                    ov[k2] = f2bf(o);
                }
                if (fuse) {
                    *(f32x4u*)&arow[c] = m4;
                    *(ushort4*)&xrow[c] = make_ushort4(ov[0], ov[1], ov[2], ov[3]);
                }
            }
            __syncthreads();
            int n = lcnt;
            for (int e = 0; e < n; e++) {
                float a_ = lv[e];
                float4 w = *(const float4*)(Wd + (size_t)lj[e] * ND + d0);
                r.x = fmaf(a_, w.x, r.x);
                r.y = fmaf(a_, w.y, r.y);
                r.z = fmaf(a_, w.z, r.z);
                r.w = fmaf(a_, w.w, r.w);
            }
        }
        float dx = r.x - xv.x, dy = r.y - xv.y, dz = r.z - xv.z, dw = r.w - xv.w;
        float ss = dx * dx + dy * dy + dz * dz + dw * dw;
        float tot = blk_reduce(ss, sred);
        if (t == 0) atomicAdd(&acc[A_L2_0 + g], (double)tot);
    }
    {
        f32x4u rr;
        rr[0] = r.x; rr[1] = r.y; rr[2] = r.z; rr[3] = r.w;
        *(f32x4u*)(recon + (size_t)row * ND + d0) = rr;   // 4-mod-16 region: f32x4u
    }
    if (fuse) {
        #pragma unroll
        for (int o = 32; o > 0; o >>= 1) { l1 += __shfl_down(l1, o, 64); kcnt += __shfl_down(kcnt, o, 64); }
        __shared__ float s1[4];
        __shared__ int s2[4];
        if ((t & 63) == 0) { s1[t >> 6] = l1; s2[t >> 6] = kcnt; }
        __syncthreads();
        if (t == 0) {
            atomicAdd(&acc[A_L1], (double)(s1[0] + s1[1] + s1[2] + s1[3]));
            atomicAdd(&scal[S_L0], s2[0] + s2[1] + s2[2] + s2[3]);
        }
    }
}

// ---- aux via dense masked GEMM ----
// pack acts_aux = relu(acts - minval) * dead into bf16 plane [NB][NS]
// (fallback path only; fused into k_decode otherwise)
__global__ __launch_bounds__(256) void k_aux_pack(const float* __restrict__ acts,
        const unsigned char* __restrict__ dead, const int* scal,
        unsigned short* __restrict__ axb) {
    int row = blockIdx.x, t = threadIdx.x;
    float minval = __uint_as_float((unsigned)scal[S_MINBITS]);
    const float* arow = acts + (size_t)row * NS;
    unsigned short* orow = axb + (size_t)row * NS;
    for (int c = t; c < NS; c += 256) {
        float v = arow[c];
        float o = (dead[c] && v > minval) ? (v - minval) : 0.f;
        orow[c] = f2bf(o);
    }
}

// transpose W_dec [S][D] fp32 -> WdT [D][S] bf16
__global__ __launch_bounds__(256) void k_prep_wd(const float* __restrict__ Wd,
        unsigned short* __restrict__ WdT) {
    __shared__ float tile[32][33];
    int s0 = blockIdx.x * 32, d0 = blockIdx.y * 32;
    int t = threadIdx.x;
    int c = t & 31, r = t >> 5;
    #pragma unroll
    for (int it = 0; it < 4; it++)
        tile[r + it * 8][c] = Wd[(size_t)(s0 + r + it * 8) * ND + d0 + c];
    __syncthreads();
    int sl = t & 31, dl = t >> 5;
    #pragma unroll
    for (int it = 0; it < 4; it++)
        WdT[(size_t)(d0 + dl + it * 8) * NS + s0 + sl] = f2bf(tile[sl][dl + it * 8]);
}

// bf16 MFMA aux GEMM: raux[z] = acts_aux @ W_dec (K-split over z), per-split fp32 planes.
// Double-buffered (32 KiB LDS -> 2 blocks/CU), race-free single-barrier
// schedule, 16B-chunk XOR swizzle (verified). Per-acc MFMA order unchanged.
__global__ __launch_bounds__(256) void k_aux_mfma(
        const unsigned short* __restrict__ axb, const unsigned short* __restrict__ WdT,
        float* __restrict__ raux) {
    __shared__ unsigned short smem[16384];   // 2 bufs x (As[128x32] + Bs[128x32]) = 32 KiB
    const int t = threadIdx.x;
    const int lane = t & 63, w = t >> 6;
    const int wm = w >> 1, wn = w & 1;
    const int m0 = blockIdx.y * 128, n0 = blockIdx.x * 128;
    const int kbase = blockIdx.z * (NS / KSPLIT);
    const int ln15 = lane & 15, q = lane >> 4;
    const int cph8 = ((q ^ ((lane >> 1) & 3)) << 3);
    const int sq8 = (((lane & 3) ^ ((lane >> 3) & 3)) << 3);

    f32x4 acc[4][4];
    #pragma unroll
    for (int i = 0; i < 4; i++)
        #pragma unroll
        for (int j = 0; j < 4; j++) acc[i][j] = (f32x4){0.f, 0.f, 0.f, 0.f};

    // waves 0,1 stage A halves; waves 2,3 stage B halves (64 rows x 32 cols each)
    const unsigned short* gbase;
    int ldst;
    if (w < 2) { gbase = axb + (size_t)(m0 + w * 64) * NS; ldst = w * 64 * 32; }
    else       { gbase = WdT + (size_t)(n0 + (w - 2) * 64) * NS; ldst = 4096 + (w - 2) * 64 * 32; }
    const unsigned short* glane = gbase + (size_t)(lane >> 2) * NS + sq8 + kbase;
    ldst += (lane >> 2) * 32 + (lane & 3) * 8;

    // prologue: stage kt=0 into buf0
    #pragma unroll
    for (int ch = 0; ch < 4; ch++)
        GLD16(glane + (size_t)ch * 16 * NS, smem + ldst + ch * 512);

    const int NKT = (NS / KSPLIT) / 32;   // 240
    for (int kt = 0; kt < NKT; ++kt) {
        const int cb = (kt & 1) * 8192;
        const int nb = cb ^ 8192;
        asm volatile("s_waitcnt vmcnt(0)" ::: "memory");   // own stage(kt) landed
        __builtin_amdgcn_s_barrier();                      // all stage(kt) visible; buf nb readers done
        __builtin_amdgcn_sched_barrier(0);
        if (kt < NKT - 1) {
            #pragma unroll
            for (int ch = 0; ch < 4; ch++)
                GLD16(glane + (size_t)ch * 16 * NS + (size_t)(kt + 1) * 32, smem + nb + ldst + ch * 512);
        }
        bf16x8 af[4], bf[4];
        #pragma unroll
        for (int i = 0; i < 4; i++)
            af[i] = *(const bf16x8*)&smem[cb + (wm * 64 + i * 16 + ln15) * 32 + cph8];
        #pragma unroll
        for (int j = 0; j < 4; j++)
            bf[j] = *(const bf16x8*)&smem[cb + 4096 + (wn * 64 + j * 16 + ln15) * 32 + cph8];
        asm volatile("s_waitcnt lgkmcnt(0)" ::: "memory");
        __builtin_amdgcn_sched_barrier(0);
        __builtin_amdgcn_s_setprio(1);
        #pragma unroll
        for (int j = 0; j < 4; j++)
            #pragma unroll
            for (int i = 0; i < 4; i++)
                acc[i][j] = __builtin_amdgcn_mfma_f32_16x16x32_bf16(af[i], bf[j], acc[i][j], 0, 0, 0);
        __builtin_amdgcn_s_setprio(0);
    }
    float* rz = raux + (size_t)blockIdx.z * NB * ND;
    #pragma unroll
    for (int j = 0; j < 4; j++) {
        int n = n0 + wn * 64 + j * 16 + ln15;
        #pragma unroll
        for (int i = 0; i < 4; i++) {
            int mrow = m0 + wm * 64 + i * 16 + q * 4;
            #pragma unroll
            for (int rg = 0; rg < 4; rg++)
                rz[(size_t)(mrow + rg) * ND + n] = acc[i][j][rg];
        }
    }
}

// aux loss: sum over B*D of (sum_z raux[z] - (x - recon))^2 — vectorized
__global__ __launch_bounds__(256) void k_aux_diff(const float* __restrict__ raux,
        const float* __restrict__ x, const float* __restrict__ recon, double* acc) {
    __shared__ float sred[4];
    float ss = 0.f;
    int stride = gridDim.x * blockDim.x;
    for (int i4 = blockIdx.x * blockDim.x + threadIdx.x; i4 < NB * ND / 4; i4 += stride) {
        int i = i4 * 4;
        float4 ra = *(const float4*)&raux[i];
        #pragma unroll
        for (int z = 1; z < KSPLIT; z++) {
            float4 rz = *(const float4*)&raux[(size_t)z * NB * ND + i];
            ra.x += rz.x; ra.y += rz.y; ra.z += rz.z; ra.w += rz.w;
        }
        float4 xd = *(const float4*)&x[i];
        f32x4u rc = *(const f32x4u*)&recon[i];   // recon region is 4-mod-16
        float d0 = ra.x - (xd.x - rc[0]);
        float d1 = ra.y - (xd.y - rc[1]);
        float d2 = ra.z - (xd.z - rc[2]);
        float d3 = ra.w - (xd.w - rc[3]);
        ss += d0 * d0 + d1 * d1 + d2 * d2 + d3 * d3;
    }
    float tot = blk_reduce(ss, sred);
    if (threadIdx.x == 0) atomicAdd(&acc[A_AUX], (double)tot);
}

// fallback aux: sparse gather per row
__global__ __launch_bounds__(256) void k_aux(const float* __restrict__ acts,
        const unsigned char* __restrict__ dead, const float* __restrict__ x,
        const float* __restrict__ recon, const float* __restrict__ Wd,
        const int* scal, double* acc) {
    int row = blockIdx.x, t = threadIdx.x;
    float minval = __uint_as_float((unsigned)scal[S_MINBITS]);
    __shared__ int lj[2048];
    __shared__ float lv[2048];
    __shared__ int lcnt;
    __shared__ float sred[4];
    float4 r = {0.f, 0.f, 0.f, 0.f};
    const float* arow = acts + (size_t)row * NS;
    const int d0 = t * 4;
    for (int c0 = 0; c0 < NS; c0 += 2048) {
        __syncthreads();
        if (t == 0) lcnt = 0;
        __syncthreads();
        #pragma unroll
        for (int u = 0; u < 8; u++) {
            int c = c0 + u * 256 + t;
            float v = arow[c];
            if (dead[c] && v > minval) {
                int p = atomicAdd(&lcnt, 1);
                lj[p] = c; lv[p] = v - minval;
            }
        }
        __syncthreads();
        int n = lcnt;
        for (int e = 0; e < n; e++) {
            float a_ = lv[e];
            float4 w = *(const float4*)(Wd + (size_t)lj[e] * ND + d0);
            r.x = fmaf(a_, w.x, r.x);
            r.y = fmaf(a_, w.y, r.y);
            r.z = fmaf(a_, w.z, r.z);
            r.w = fmaf(a_, w.w, r.w);
        }
    }
    const float* xr = x + (size_t)row * ND + d0;
    const float* rr = recon + (size_t)row * ND + d0;
    float dx = r.x - (xr[0] - rr[0]);
    float dy = r.y - (xr[1] - rr[1]);
    float dz = r.z - (xr[2] - rr[2]);
    float dw = r.w - (xr[3] - rr[3]);
    float ss = dx * dx + dy * dy + dz * dz + dw * dw;
    float tot = blk_reduce(ss, sred);
    if (t == 0) atomicAdd(&acc[A_AUX], (double)tot);
}

// in-place top-k zeroing over d_out acts region (fallback path only; fused into k_decode otherwise)
__global__ __launch_bounds__(256) void k_topk_write(float* __restrict__ out, const int* scal, double* acc, int* scalw) {
    unsigned bhi = (unsigned)scal[S_BHI];
    float l1 = 0.f;
    int cnt = 0;
    const long long vstart = 8, nvec = 15728639;   // [8, 62914564) as float4
    long long stride = (long long)gridDim.x * blockDim.x;
    for (long long i = (long long)blockIdx.x * blockDim.x + threadIdx.x; i < nvec; i += stride) {
        float4* p = (float4*)(out + vstart) + i;
        float4 v = *p;
        #define PROC(F) { unsigned b = __float_as_uint(v.F); if (b > bhi) { l1 += v.F; cnt++; } else v.F = 0.f; }
        PROC(x) PROC(y) PROC(z) PROC(w)
        #undef PROC
        *p = v;
    }
    if (blockIdx.x == 0 && threadIdx.x == 0) {
        const long long head[4] = {5, 6, 7, 62914564LL};
        for (int q = 0; q < 4; q++) {
            float v = out[head[q]];
            unsigned b = __float_as_uint(v);
            if (b > bhi) { l1 += v; cnt++; } else out[head[q]] = 0.f;
        }
    }
    int t = threadIdx.x;
    #pragma unroll
    for (int o = 32; o > 0; o >>= 1) { l1 += __shfl_down(l1, o, 64); cnt += __shfl_down(cnt, o, 64); }
    __shared__ float s1[4];
    __shared__ int s2[4];
    if ((t & 63) == 0) { s1[t >> 6] = l1; s2[t >> 6] = cnt; }
    __syncthreads();
    if (t == 0) {
        atomicAdd(&acc[A_L1], (double)(s1[0] + s1[1] + s1[2] + s1[3]));
        atomicAdd(&scalw[S_L0], s2[0] + s2[1] + s2[2] + s2[3]);
    }
}

// rewrite the selected band entries (zeroed by the masking pass) + their L1/L0 contribution
__global__ __launch_bounds__(256) void k_selwrite(float* __restrict__ acts, const int* __restrict__ sel_idx,
        const unsigned* __restrict__ sel_bits, int* scal, double* acc) {
    int t = threadIdx.x;
    int n = min(scal[S_SELCNT], SEL_CAP);
    float l1 = 0.f;
    for (int e = t; e < n; e += 256) {
        float v = __uint_as_float(sel_bits[e]);
        acts[sel_idx[e]] = v;
        l1 += v;
    }
    #pragma unroll
    for (int o = 32; o > 0; o >>= 1) l1 += __shfl_down(l1, o, 64);
    __shared__ float s1[4];
    if ((t & 63) == 0) s1[t >> 6] = l1;
    __syncthreads();
    if (t == 0) {
        atomicAdd(&acc[A_L1], (double)(s1[0] + s1[1] + s1[2] + s1[3]));
        atomicAdd(&scal[S_L0], n);
    }
}

__global__ void k_final(float* out, const int* scal, const double* acc) {
    if (threadIdx.x == 0 && blockIdx.x == 0) {
        double ml2 = (acc[0] + acc[1] + acc[2] + acc[3]) * 0.25 / ((double)NB * ND);
        double l1 = 1e-3 * acc[A_L1] / (double)NB;
        double aux = (scal[S_NDEAD] > 0) ? (1e-2 * acc[A_AUX] / ((double)NB * ND)) : 0.0;
        out[0] = (float)(ml2 + l1 + aux);
        out[1] = (float)ml2;
        out[2] = (float)l1;
        out[3] = (float)aux;
        out[4] = (float)scal[S_L0] / (float)NB;
    }
}

// ---------------- launch ----------------
extern "C" void kernel_launch(void* const* d_in, const int* in_sizes, int n_in,
                              void* d_out, int out_size, void* d_ws, size_t ws_size,
                              hipStream_t stream) {
    const float* x     = (const float*)d_in[0];
    const float* b_dec = (const float*)d_in[1];
    const float* b_enc = (const float*)d_in[2];
    const float* W_enc = (const float*)d_in[3];
    const float* W_dec = (const float*)d_in[4];
    const int*   nbna  = (const int*)d_in[5];

    float* out = (float*)d_out;
    float* acts  = out + 5;                         // [NB, NS] (misaligned region)
    float* recon = out + 5 + (size_t)NB * NS;       // [NB, ND]

    char* ws = (char*)d_ws;
    int*    scal = (int*)(ws + OFF_SCAL);
    double* acc  = (double*)(ws + OFF_ACC);
    int*    h1m  = (int*)(ws + OFF_H1M);
    int*    h1a  = (int*)(ws + OFF_H1A);
    int*    h2m  = (int*)(ws + OFF_H2M);
    int*    h2a  = (int*)(ws + OFF_H2A);
    unsigned char* dead = (unsigned char*)(ws + OFF_DEAD);
    int*      sel_idx  = (int*)(ws + OFF_SEL_IDX);
    unsigned* sel_bits = (unsigned*)(ws + OFF_SEL_BITS);
    int*      bandi = (int*)(ws + OFF_BANDI);
    double*   bandv = (double*)(ws + OFF_BANDV);
    unsigned* cab   = (unsigned*)(ws + OFF_CAB);
    float*    raux  = (float*)(ws + OFF_RAUX);
    unsigned short* Ahg = (unsigned short*)(ws + OFF_AH);
    unsigned short* Alg = (unsigned short*)(ws + OFF_AL);
    unsigned short* WhT = (unsigned short*)(ws + OFF_WHT);
    unsigned short* WlT = (unsigned short*)(ws + OFF_WLT);
    unsigned short* axb = (unsigned short*)(ws + OFF_AXB);
    unsigned short* WdT = (unsigned short*)(ws + OFF_WDT);

    const bool use_mfma     = (ws_size >= WS_NEED_ENC);   // constant per process -> graph-stable
    const bool use_aux_gemm = (ws_size >= WS_NEED_AUX);   // implies use_mfma (AUX > ENC)

    k_init<<<64, 256, 0, stream>>>((int*)d_ws);
    k_dead<<<60, 256, 0, stream>>>(nbna, dead, scal);
    if (use_mfma) {
        k_prep_a<<<512, 256, 0, stream>>>(x, b_dec, Ahg, Alg);
        k_prep_w<<<dim3(NS / 32, ND / 32), 256, 0, stream>>>(W_enc, WhT, WlT);
        // hist1 fused into enc epilogue
        k_enc_mfma<<<(NB / 256) * (NS / 256), 512, 0, stream>>>(Ahg, Alg, WhT, WlT, b_enc, dead, acts, h1m, h1a);
    } else {
        k_enc_gemm<<<dim3(NS / GBN, NB / GBM), 256, 0, stream>>>(x, b_dec, b_enc, W_enc, acts);
        k_hist1<<<1024, 256, 0, stream>>>(acts, dead, h1m, h1a);
    }
    k_scan<<<1, 256, 0, stream>>>(h1m, scal, 0);
    k_scan<<<1, 256, 0, stream>>>(h1a, scal, 1);
    k_hist2<<<NB, 256, 0, stream>>>(acts, dead, scal, h2m, h2a);
    k_scan<<<1, 256, 0, stream>>>(h2m, scal, 2);
    k_scan<<<1, 256, 0, stream>>>(h2a, scal, 3);
    k_collect<<<NB, 256, 0, stream>>>(acts, dead, scal, bandi, cab);
    k_resolve<<<1, 256, 0, stream>>>(cab, scal);
    k_band_re<<<512, 256, 0, stream>>>(x, b_dec, b_enc, W_enc, scal, bandi, bandv);
    k_band_sel<<<1, 256, 0, stream>>>(scal, bandi, bandv, sel_idx, sel_bits);
    if (use_aux_gemm) {
        // fused decode: recon/L2 + masked-acts write + axb pack + L1/L0
        k_decode<<<NB, 256, 0, stream>>>(acts, x, b_dec, W_dec, recon, dead, sel_idx, axb, scal, acc, 1);
        k_prep_wd<<<dim3(NS / 32, ND / 32), 256, 0, stream>>>(W_dec, WdT);
        k_aux_mfma<<<dim3(ND / 128, NB / 128, KSPLIT), 256, 0, stream>>>(axb, WdT, raux);
        k_aux_diff<<<512, 256, 0, stream>>>(raux, x, recon, acc);
    } else {
        // legacy path: decode leaves acts raw; k_aux reads raw acts; topk masks after
        k_decode<<<NB, 256, 0, stream>>>(acts, x, b_dec, W_dec, recon, dead, sel_idx, axb, scal, acc, 0);
        k_aux<<<NB, 256, 0, stream>>>(acts, dead, x, recon, W_dec, scal, acc);
        k_topk_write<<<4096, 256, 0, stream>>>(out, scal, acc, scal);
    }
    k_selwrite<<<1, 256, 0, stream>>>(acts, sel_idx, sel_bits, scal, acc);
    k_final<<<1, 64, 0, stream>>>(out, scal, acc);
}